// Round 1
// baseline (8088.405 us; speedup 1.0000x reference)
//
#include <hip/hip_runtime.h>
#include <math.h>

#define GAIN 1.6778523489932886f     // 1/0.596
#define MPS  1.3130643285972254f     // 1/sqrt(0.7^2+0.3^2)

__device__ __forceinline__ float silu_g(float x){
  float s = 1.0f/(1.0f + __expf(-x));
  return x*s*GAIN;
}

// ---------------- weight row-norm reciprocals ----------------
struct NormEnt { const float* w; int O, K, off; };
struct NormArgs { NormEnt e[16]; };

__global__ __launch_bounds__(64) void rownorm_kernel(NormArgs na, float* invw){
  int row = blockIdx.x;
  int base = 0; int i;
  for (i = 0; i < 16; i++){
    if (row < base + na.e[i].O) break;
    base += na.e[i].O;
  }
  if (i >= 16) return;
  int r = row - base; int K = na.e[i].K;
  const float* w = na.e[i].w + (long)r*K;
  float s = 0.f;
  for (int k = threadIdx.x; k < K; k += 64){ float v = w[k]; s += v*v; }
  for (int off = 32; off; off >>= 1) s += __shfl_down(s, off);
  if (threadIdx.x == 0) invw[na.e[i].off + r] = rsqrtf(s + 1e-8f);
}

// ---------------- pixel_norm (per-position inverse rms) ----------------
__global__ __launch_bounds__(256) void invn_x_kernel(const float* __restrict__ X, float* __restrict__ invn, int C, int F){
  int pos = blockIdx.x*256 + threadIdx.x;
  int total = 2*F*2048;
  if (pos >= total) return;
  int bf = pos >> 11; int l = pos & 2047;
  int b = bf / F; int f = bf - b*F;
  const float* p = X + ((b*C)*F + f)*2048 + l;
  int stride = F*2048;
  float s = 0.f;
  for (int c = 0; c < C; c++){ float v = p[c*stride]; s += v*v; }
  invn[pos] = rsqrtf(s/(float)C + 1e-4f);
}

__global__ __launch_bounds__(256) void invn_audio_kernel(const float* __restrict__ audio, const float* __restrict__ pw,
                                                         const float* __restrict__ pb, float* __restrict__ invn){
  int pos = blockIdx.x*256 + threadIdx.x;
  if (pos >= 2*128*2048) return;
  float a = audio[pos];
  float s = 0.f;
  for (int o = 0; o < 64; o++){ float v = a*pw[o] + pb[o]; s += v*v; }
  invn[pos] = rsqrtf(s/64.f + 1e-4f);
}

// ---------------- generic fused GEMM ----------------
// out[b,n,f,l] = invwA[n] * sum_k A[n,k] * Bacc(k; b,f,l)   (+ epilogue)
// M-space column m -> (b, f, l = lq0 + il), il in [0,Lw)
// BMODE: 0 plain, 1 X*invn->silu, 2 (audio*pw[k]+pb[k])*invn->silu, 3 freq-pooled mean, 4 X*invn
// EMODE: 0 store, 1 silu, 2 mp_add with auxX*invn, 3 mp_add with (audio*pw[n]+pb[n])*invn
struct GemmArgs {
  const float* A; const float* invwA;
  const float* Bsrc; const float* invn; const float* audio;
  const float* pw; const float* pb; const float* auxX;
  float* Cout;
  int N, K, Fdim, Lw, lq0, BLw, Bl0, CLw, Cl0, Nsto, Fsrc, pool_s;
};

template<int BMODE, int EMODE>
__global__ __launch_bounds__(256) void gemm_kernel(GemmArgs g){
  __shared__ float As[16][64];
  __shared__ float Bs[16][64];
  int t = threadIdx.x;
  int m0 = blockIdx.x*64, n0 = blockIdx.y*64;
  int FL = g.Fdim * g.Lw;

  // B-load column (fixed per thread)
  int colm = m0 + (t & 63);
  int bcol = colm / FL; int rr = colm - bcol*FL;
  int fcol = rr / g.Lw; int labs = g.lq0 + (rr - fcol*g.Lw);
  bool cv = (bcol < 2) && (labs >= 0) && (labs < 2048);
  float invn_c = 0.f, audio_c = 0.f;
  if (cv && (BMODE==1 || BMODE==2 || BMODE==4)) invn_c = g.invn[(bcol*g.Fdim + fcol)*2048 + labs];
  if (cv && BMODE==2) audio_c = g.audio[(bcol*128 + fcol)*2048 + labs];
  const float* bbase = g.Bsrc;
  if (cv && BMODE != 2) bbase = g.Bsrc + ((bcol*g.K)*g.Fsrc + fcol*g.pool_s)*g.BLw + (labs - g.Bl0);
  int kstep = g.Fsrc * g.BLw;
  float pinv = 1.f/(float)g.pool_s;

  int kb = t >> 6;
  int ka = t & 15, na = t >> 4;
  int tx = t & 15, ty = t >> 4;
  float acc[4][4] = {};

  for (int k0 = 0; k0 < g.K; k0 += 16){
    #pragma unroll
    for (int i = 0; i < 4; i++)
      As[ka][na + 16*i] = g.A[(n0 + na + 16*i)*g.K + k0 + ka];
    #pragma unroll
    for (int u = 0; u < 4; u++){
      int kk = kb + 4*u;
      int k = k0 + kk;
      float v = 0.f;
      if (cv){
        if (BMODE == 2){
          float x = (audio_c*g.pw[k] + g.pb[k])*invn_c; v = silu_g(x);
        } else if (BMODE == 3){
          float s = 0.f;
          for (int j = 0; j < g.pool_s; j++) s += bbase[k*kstep + j*g.BLw];
          v = s*pinv;
        } else {
          float x = bbase[k*kstep];
          if (BMODE == 1) v = silu_g(x*invn_c);
          else if (BMODE == 4) v = x*invn_c;
          else v = x;
        }
      }
      Bs[kk][t & 63] = v;
    }
    __syncthreads();
    #pragma unroll
    for (int kk = 0; kk < 16; kk++){
      float4 av = *(const float4*)&As[kk][ty*4];
      float4 bv = *(const float4*)&Bs[kk][tx*4];
      float a[4] = {av.x, av.y, av.z, av.w};
      float b[4] = {bv.x, bv.y, bv.z, bv.w};
      #pragma unroll
      for (int i = 0; i < 4; i++)
        #pragma unroll
        for (int j = 0; j < 4; j++)
          acc[i][j] = fmaf(a[i], b[j], acc[i][j]);
    }
    __syncthreads();
  }

  float invw4[4];
  #pragma unroll
  for (int i = 0; i < 4; i++) invw4[i] = g.invwA[n0 + ty*4 + i];

  #pragma unroll
  for (int j = 0; j < 4; j++){
    int m = m0 + tx*4 + j;
    int b2 = m / FL; int r2 = m - b2*FL;
    int f2 = r2 / g.Lw; int l2 = g.lq0 + (r2 - f2*g.Lw);
    if (b2 >= 2 || l2 < 0 || l2 >= 2048) continue;
    float invn_p = 0.f, audio_p = 0.f;
    if (EMODE == 2 || EMODE == 3) invn_p = g.invn[(b2*g.Fdim + f2)*2048 + l2];
    if (EMODE == 3) audio_p = g.audio[(b2*128 + f2)*2048 + l2];
    #pragma unroll
    for (int i = 0; i < 4; i++){
      int n = n0 + ty*4 + i;
      float v = acc[i][j] * invw4[i];
      if (EMODE == 1) v = silu_g(v);
      else if (EMODE == 2){
        float xn = g.auxX[((b2*g.N + n)*g.Fdim + f2)*2048 + l2] * invn_p;
        v = (xn*0.7f + v*0.3f)*MPS;
      } else if (EMODE == 3){
        float xn = (audio_p*g.pw[n] + g.pb[n])*invn_p;
        v = (xn*0.7f + v*0.3f)*MPS;
      }
      g.Cout[((b2*g.Nsto + n)*g.Fdim + f2)*g.CLw + (l2 - g.Cl0)] = v;
    }
  }
}

// ---------------- depthwise 5x3 conv (+ silu) ----------------
struct DwArgs { const float* R1; const float* wd; const float* invw; float* R2; int C, F, Lc, l0; };
__global__ __launch_bounds__(256) void dw2d_kernel(DwArgs a){
  int idx = blockIdx.x*256 + threadIdx.x;
  int total = 2*a.C*a.F*a.Lc;
  if (idx >= total) return;
  int li = idx % a.Lc; int r = idx / a.Lc;
  int f = r % a.F; r /= a.F;
  int c = r % a.C; int b = r / a.C;
  int labs = a.l0 + li;
  const float* w = a.wd + c*15;
  const float* base = a.R1 + (long)((b*a.C + c)*a.F)*(a.Lc + 2);
  float s = 0.f;
  #pragma unroll
  for (int df = -2; df <= 2; df++){
    int ff = f + df; if (ff < 0 || ff >= a.F) continue;
    #pragma unroll
    for (int dl = -1; dl <= 1; dl++){
      int ll = labs + dl; if (ll < 0 || ll >= 2048) continue;
      s += base[ff*(a.Lc + 2) + (ll - (a.l0 - 1))] * w[(df + 2)*3 + (dl + 1)];
    }
  }
  a.R2[((b*a.C + c)*a.F + f)*a.Lc + li] = silu_g(s * a.invw[c]);
}

// ---------------- seq depthwise 3-tap (+ silu) ----------------
__global__ __launch_bounds__(256) void dwseq_kernel(const float* __restrict__ HS, const float* __restrict__ w,
                                                    const float* __restrict__ invw, float* __restrict__ H2){
  int idx = blockIdx.x*256 + threadIdx.x;
  if (idx >= 2*1024*2048) return;
  int tt = idx & 2047; int bc = idx >> 11; int c = bc & 1023;
  const float* base = HS + (long)bc*2048;
  const float* ww = w + c*3;
  float s = 0.f;
  if (tt > 0)    s += base[tt-1]*ww[0];
  s += base[tt]*ww[1];
  if (tt < 2047) s += base[tt+1]*ww[2];
  H2[idx] = silu_g(s * invw[c]);
}

// ---------------- minGRU scan + gate ----------------
__global__ __launch_bounds__(256) void scan_kernel(const float* __restrict__ ZC, const float* __restrict__ G,
                                                   float* __restrict__ SC){
  int bc = blockIdx.x;            // 0..2047 = b*1024+c
  int b = bc >> 10, c = bc & 1023;
  const float* zrow = ZC + ((long)(b*2048 + c))*2048;
  const float* crow = ZC + ((long)(b*2048 + 1024 + c))*2048;
  const float* grow = G + (long)bc*2048;
  float* orow = SC + (long)bc*2048;
  int tid = threadIdx.x;
  int t0 = tid*8;
  float av[8], bv[8];
  float A = 1.f, Bv = 0.f;
  #pragma unroll
  for (int j = 0; j < 8; j++){
    float z = zrow[t0+j]; float cval = crow[t0+j];
    float zs = 1.f/(1.f + __expf(-z));
    float a = 1.f - zs; float bb = zs*cval;
    av[j] = a; bv[j] = bb;
    Bv = a*Bv + bb;
    A = a*A;
  }
  __shared__ float sA[256], sB[256];
  sA[tid] = A; sB[tid] = Bv;
  __syncthreads();
  for (int off = 1; off < 256; off <<= 1){
    float pA = 1.f, pB = 0.f;
    if (tid >= off){ pA = sA[tid-off]; pB = sB[tid-off]; }
    __syncthreads();
    float nA = A*pA; float nB = A*pB + Bv;
    A = nA; Bv = nB;
    sA[tid] = A; sB[tid] = Bv;
    __syncthreads();
  }
  float h = (tid > 0) ? sB[tid-1] : 0.f;
  #pragma unroll
  for (int j = 0; j < 8; j++){
    h = av[j]*h + bv[j];
    orow[t0+j] = h * silu_g(grow[t0+j]);
  }
}

// ---------------- final mp_silu ----------------
__global__ __launch_bounds__(256) void final_kernel(const float* __restrict__ SEQ, float* __restrict__ out){
  int i = blockIdx.x*256 + threadIdx.x;
  if (i < 2*512*2048) out[i] = silu_g(SEQ[i]);
}

extern "C" void kernel_launch(void* const* d_in, const int* in_sizes, int n_in,
                              void* d_out, int out_size, void* d_ws, size_t ws_size,
                              hipStream_t stream) {
  const float* audio = (const float*)d_in[0];
  const float* pw = (const float*)d_in[1];
  const float* pb = (const float*)d_in[2];
  const float* cw1[3] = {(const float*)d_in[3], (const float*)d_in[7], (const float*)d_in[11]};
  const float* cwd[3] = {(const float*)d_in[4], (const float*)d_in[8], (const float*)d_in[12]};
  const float* cw2[3] = {(const float*)d_in[5], (const float*)d_in[9], (const float*)d_in[13]};
  const float* cdn[3] = {(const float*)d_in[6], (const float*)d_in[10], (const float*)d_in[14]};
  const float* hgw  = (const float*)d_in[15];
  const float* dww  = (const float*)d_in[16];
  const float* gruw = (const float*)d_in[17];
  const float* outw = (const float*)d_in[18];
  float* out = (float*)d_out;

  float* W = (float*)d_ws;
  float* INVW    = W;                      // 32768
  float* INVN    = W + 32768;              // 524288
  float* INVNSEQ = INVN + 524288;          // 4096
  float* SEQ     = INVNSEQ + 4096;         // 2097152
  float* IN1     = SEQ + 2097152;          // 16777216
  float* IN2     = IN1 + 16777216;         // 8388608
  float* ARENA   = IN2 + 8388608;

  long wf = (long)(ws_size / 4);
  auto need = [](long ncq){
    long Lcq = 2048/ncq;
    long conv = 32768L*(Lcq+2) + 32768L*Lcq + 16384L*Lcq;
    long ar = conv > 25165824L ? conv : 25165824L;
    return 27824128L + ar;
  };
  int nc = 8;
  if (wf >= need(2)) nc = 2; else if (wf >= need(4)) nc = 4;
  int Lc = 2048/nc;

  // ---- weight norms (one kernel for all 16 tensors) ----
  {
    NormArgs na;
    const float* wp[16] = {cw1[0],cwd[0],cw2[0],cdn[0], cw1[1],cwd[1],cw2[1],cdn[1],
                           cw1[2],cwd[2],cw2[2],cdn[2], hgw, dww, gruw, outw};
    int Os[16] = {128,128,64,128, 256,256,128,256, 512,512,256,512, 8192,4096,8192,2048};
    int Ks[16] = {64,15,128,64, 128,15,256,128, 256,15,512,256, 512,3,1024,1024};
    int off = 0, rows = 0;
    for (int i = 0; i < 16; i++){ na.e[i].w = wp[i]; na.e[i].O = Os[i]; na.e[i].K = Ks[i]; na.e[i].off = off; off += Os[i]; rows += Os[i]; }
    rownorm_kernel<<<rows, 64, 0, stream>>>(na, INVW);
  }

  // ---- conv blocks ----
  int Cin_[3]  = {64,128,256};
  int Cmid_[3] = {128,256,512};
  int F_[3]    = {128,32,8};
  int s_[3]    = {4,4,8};
  const float* Xin[3] = {nullptr, IN1, IN2};
  float* Xout[3] = {IN1, IN2, SEQ};
  int w1o[3] = {0,448,1344}, wdo[3] = {128,704,1856}, w2o[3] = {256,960,2368}, dno[3] = {320,1088,2624};

  float* R1 = ARENA;
  float* R2 = ARENA + 32768L*(Lc+2);
  float* Hb = R2 + 32768L*Lc;

  for (int b = 0; b < 3; b++){
    int Cin = Cin_[b], Cmid = Cmid_[b], F = F_[b], s = s_[b];
    if (b == 0)
      invn_audio_kernel<<<(2*128*2048)/256, 256, 0, stream>>>(audio, pw, pb, INVN);
    else {
      int total = 2*F*2048;
      invn_x_kernel<<<(total+255)/256, 256, 0, stream>>>(Xin[b], INVN, Cin, F);
    }
    for (int ci = 0; ci < nc; ci++){
      int l0 = ci*Lc;
      // conv1: Cin -> Cmid on l-window [l0-1, l0+Lc+1)
      GemmArgs ga{};
      ga.A = cw1[b]; ga.invwA = INVW + w1o[b];
      ga.Bsrc = Xin[b]; ga.invn = INVN; ga.audio = audio; ga.pw = pw; ga.pb = pb;
      ga.Cout = R1; ga.N = Cmid; ga.K = Cin; ga.Fdim = F; ga.Lw = Lc+2; ga.lq0 = l0-1;
      ga.BLw = 2048; ga.Bl0 = 0; ga.CLw = Lc+2; ga.Cl0 = l0-1; ga.Nsto = Cmid; ga.Fsrc = F; ga.pool_s = 1;
      int M1 = 2*F*(Lc+2);
      dim3 g1((M1+63)/64, Cmid/64);
      if (b == 0) gemm_kernel<2,0><<<g1,256,0,stream>>>(ga);
      else        gemm_kernel<1,0><<<g1,256,0,stream>>>(ga);
      // depthwise 5x3 + silu
      DwArgs da{R1, cwd[b], INVW + wdo[b], R2, Cmid, F, Lc, l0};
      int tdw = 2*Cmid*F*Lc;
      dw2d_kernel<<<(tdw+255)/256, 256, 0, stream>>>(da);
      // conv2 + mp_add -> Hb
      GemmArgs gb{};
      gb.A = cw2[b]; gb.invwA = INVW + w2o[b];
      gb.Bsrc = R2; gb.invn = INVN; gb.audio = audio; gb.pw = pw; gb.pb = pb; gb.auxX = Xin[b];
      gb.Cout = Hb; gb.N = Cin; gb.K = Cmid; gb.Fdim = F; gb.Lw = Lc; gb.lq0 = l0;
      gb.BLw = Lc; gb.Bl0 = l0; gb.CLw = Lc; gb.Cl0 = l0; gb.Nsto = Cin; gb.Fsrc = F; gb.pool_s = 1;
      int M2 = 2*F*Lc;
      dim3 g2((M2+63)/64, Cin/64);
      if (b == 0) gemm_kernel<0,3><<<g2,256,0,stream>>>(gb);
      else        gemm_kernel<0,2><<<g2,256,0,stream>>>(gb);
      // avgpool_freq + dn conv -> next block input
      GemmArgs gc{};
      gc.A = cdn[b]; gc.invwA = INVW + dno[b];
      gc.Bsrc = Hb; gc.Cout = Xout[b];
      gc.N = Cmid; gc.K = Cin; gc.Fdim = F/s; gc.Lw = Lc; gc.lq0 = l0;
      gc.BLw = Lc; gc.Bl0 = l0; gc.CLw = 2048; gc.Cl0 = 0; gc.Nsto = Cmid; gc.Fsrc = F; gc.pool_s = s;
      int M3 = 2*(F/s)*Lc;
      dim3 g3((M3+63)/64, Cmid/64);
      gemm_kernel<3,0><<<g3,256,0,stream>>>(gc);
    }
  }

  // ---- seq blocks ----
  float* HS = ARENA;
  float* G  = ARENA + 4194304;
  float* H2 = G + 4194304;
  float* ZC = H2 + 4194304;
  float* SC = ZC + 8388608;

  for (int i = 0; i < 4; i++){
    invn_x_kernel<<<(4096+255)/256, 256, 0, stream>>>(SEQ, INVNSEQ, 512, 1);
    const float* hgi  = hgw  + (long)i*2048*512;
    const float* dwi  = dww  + (long)i*1024*3;
    const float* grui = gruw + (long)i*2048*1024;
    const float* outi = outw + (long)i*512*1024;
    // hg conv, h-half (with silu epilogue)
    GemmArgs gh{};
    gh.A = hgi; gh.invwA = INVW + 3136 + i*2048;
    gh.Bsrc = SEQ; gh.invn = INVNSEQ;
    gh.Cout = HS; gh.N = 1024; gh.K = 512; gh.Fdim = 1; gh.Lw = 2048; gh.lq0 = 0;
    gh.BLw = 2048; gh.Bl0 = 0; gh.CLw = 2048; gh.Cl0 = 0; gh.Nsto = 1024; gh.Fsrc = 1; gh.pool_s = 1;
    gemm_kernel<4,1><<<dim3(64,16),256,0,stream>>>(gh);
    // hg conv, g-half (raw)
    GemmArgs gg = gh; gg.A = hgi + 1024*512; gg.invwA = INVW + 3136 + i*2048 + 1024; gg.Cout = G;
    gemm_kernel<4,0><<<dim3(64,16),256,0,stream>>>(gg);
    // depthwise 3-tap + silu
    dwseq_kernel<<<(2*1024*2048)/256, 256, 0, stream>>>(HS, dwi, INVW + 11328 + i*1024, H2);
    // gru conv 1024 -> 2048 (z|c)
    GemmArgs gz{};
    gz.A = grui; gz.invwA = INVW + 15424 + i*2048;
    gz.Bsrc = H2; gz.Cout = ZC; gz.N = 2048; gz.K = 1024; gz.Fdim = 1; gz.Lw = 2048; gz.lq0 = 0;
    gz.BLw = 2048; gz.Bl0 = 0; gz.CLw = 2048; gz.Cl0 = 0; gz.Nsto = 2048; gz.Fsrc = 1; gz.pool_s = 1;
    gemm_kernel<0,0><<<dim3(64,32),256,0,stream>>>(gz);
    // scan + gate
    scan_kernel<<<2048,256,0,stream>>>(ZC, G, SC);
    // out conv + mp_add -> SEQ (in place)
    GemmArgs go{};
    go.A = outi; go.invwA = INVW + 23616 + i*512;
    go.Bsrc = SC; go.auxX = SEQ; go.invn = INVNSEQ;
    go.Cout = SEQ; go.N = 512; go.K = 1024; go.Fdim = 1; go.Lw = 2048; go.lq0 = 0;
    go.BLw = 2048; go.Bl0 = 0; go.CLw = 2048; go.Cl0 = 0; go.Nsto = 512; go.Fsrc = 1; go.pool_s = 1;
    gemm_kernel<0,2><<<dim3(64,8),256,0,stream>>>(go);
  }

  final_kernel<<<(2*512*2048)/256, 256, 0, stream>>>(SEQ, out);

  (void)in_sizes; (void)n_in; (void)out_size;
}

// Round 2
// 4631.126 us; speedup vs baseline: 1.7465x; 1.7465x over previous
//
#include <hip/hip_runtime.h>
#include <math.h>

#define GAIN 1.6778523489932886f     // 1/0.596
#define MPS  1.3130643285972254f     // 1/sqrt(0.7^2+0.3^2)

typedef __attribute__((ext_vector_type(8))) short short8;
typedef __attribute__((ext_vector_type(4))) short short4v;
typedef __attribute__((ext_vector_type(4))) float float4v;

__device__ __forceinline__ float silu_g(float x){
  float s = 1.0f/(1.0f + __expf(-x));
  return x*s*GAIN;
}

__device__ __forceinline__ short f2bf(float f){
  unsigned u = __builtin_bit_cast(unsigned, f);
  u += 0x7fffu + ((u >> 16) & 1u);
  return (short)(u >> 16);
}

// ---------------- weight row-norm reciprocals ----------------
struct NormEnt { const float* w; int O, K, off; };
struct NormArgs { NormEnt e[16]; };

__global__ __launch_bounds__(64) void rownorm_kernel(NormArgs na, float* invw){
  int row = blockIdx.x;
  int base = 0; int i;
  for (i = 0; i < 16; i++){
    if (row < base + na.e[i].O) break;
    base += na.e[i].O;
  }
  if (i >= 16) return;
  int r = row - base; int K = na.e[i].K;
  const float* w = na.e[i].w + (long)r*K;
  float s = 0.f;
  for (int k = threadIdx.x; k < K; k += 64){ float v = w[k]; s += v*v; }
  for (int off = 32; off; off >>= 1) s += __shfl_down(s, off);
  if (threadIdx.x == 0) invw[na.e[i].off + r] = rsqrtf(s + 1e-8f);
}

// ---------------- pixel_norm (per-position inverse rms) ----------------
__global__ __launch_bounds__(256) void invn_x_kernel(const float* __restrict__ X, float* __restrict__ invn, int C, int F){
  int pos = blockIdx.x*256 + threadIdx.x;
  int total = 2*F*2048;
  if (pos >= total) return;
  int bf = pos >> 11; int l = pos & 2047;
  int b = bf / F; int f = bf - b*F;
  const float* p = X + ((b*C)*F + f)*2048 + l;
  int stride = F*2048;
  float s = 0.f;
  for (int c = 0; c < C; c++){ float v = p[c*stride]; s += v*v; }
  invn[pos] = rsqrtf(s/(float)C + 1e-4f);
}

__global__ __launch_bounds__(256) void invn_audio_kernel(const float* __restrict__ audio, const float* __restrict__ pw,
                                                         const float* __restrict__ pb, float* __restrict__ invn){
  int pos = blockIdx.x*256 + threadIdx.x;
  if (pos >= 2*128*2048) return;
  float a = audio[pos];
  float s = 0.f;
  for (int o = 0; o < 64; o++){ float v = a*pw[o] + pb[o]; s += v*v; }
  invn[pos] = rsqrtf(s/64.f + 1e-4f);
}

// ---------------- bf16 MFMA fused GEMM ----------------
// D[n, m] = invwA[n] * sum_k W[n,k] * Bacc(k; m) (+ epilogue); m -> (b, f, l=lq0+il)
// BMODE: 0 plain, 1 X*invn->silu, 2 (audio*pw[k]+pb[k])*invn->silu, 3 freq-pooled mean, 4 X*invn
// EMODE: 0 store, 2 mp_add auxX*invn, 3 mp_add audio-proj, 4 split: n<Nsto -> silu->Cout else raw->Cout2
struct GemmArgs {
  const float* A; const float* invwA;
  const float* Bsrc; const float* invn; const float* audio;
  const float* pw; const float* pb; const float* auxX;
  float* Cout; float* Cout2;
  int N, K, Fdim, Lw, lq0, BLw, Bl0, CLw, Cl0, Nsto, Fsrc, pool_s;
};

template<int BMODE, int EMODE>
__global__ __launch_bounds__(256,2) void mgemm_kernel(GemmArgs g){
  // LDS rows padded to 72 shorts (144B, 16B-aligned, <=2-way conflicts on b128 frag reads)
  __shared__ __align__(16) short Asm[128*72];
  __shared__ __align__(16) short Bsm[128*72];
  const int t = threadIdx.x;
  const int lane = t & 63;
  const int wave = t >> 6;
  const int wc = wave >> 1, wsd = wave & 1;
  const int q = lane >> 4, r16 = lane & 15;
  const int s0 = blockIdx.x * 128;    // spatial tile base
  const int n0 = blockIdx.y * 128;    // channel tile base
  const int FL = g.Fdim * g.Lw;

  // ---- A staging mapping: thread = (row ar, half ah) ----
  const int ar = t >> 1, ah = t & 1;
  const int an = n0 + ar;
  const bool aval = an < g.N;
  const float* Aptr = g.A + (long)an * g.K + ah*16;

  // ---- B staging mapping: thread = (k-group kg 0..7, m-group mg 0..31) ----
  const int kg = t & 7, mg = t >> 3;
  const int mb = s0 + mg*4;
  int bcol = mb / FL; int rr = mb - bcol*FL;
  int fcol = (g.Fdim > 1) ? (rr / g.Lw) : 0;
  int labs = g.lq0 + (rr - fcol*g.Lw);
  const bool cv = (bcol < 2);
  bool lv[4];
  #pragma unroll
  for (int j = 0; j < 4; j++) lv[j] = cv && (labs + j >= 0) && (labs + j < 2048);
  const bool vec4 = cv && (labs >= 0) && (labs + 3 < 2048);
  float invn4[4] = {0,0,0,0}, aud4[4] = {0,0,0,0};
  if (BMODE==1 || BMODE==2 || BMODE==4){
    #pragma unroll
    for (int j = 0; j < 4; j++) if (lv[j]) invn4[j] = g.invn[(bcol*g.Fdim + fcol)*2048 + labs + j];
  }
  if (BMODE==2){
    #pragma unroll
    for (int j = 0; j < 4; j++) if (lv[j]) aud4[j] = g.audio[(bcol*128 + fcol)*2048 + labs + j];
  }
  const float* bbase = g.Bsrc;
  if (cv && BMODE != 2)
    bbase = g.Bsrc + ((long)(bcol*g.K)*g.Fsrc + fcol*g.pool_s)*g.BLw + (labs - g.Bl0);
  const long kstep = (long)g.Fsrc * g.BLw;
  const float pinv = 1.f/(float)g.pool_s;

  float4v acc[4][4];
  #pragma unroll
  for (int i = 0; i < 4; i++)
    #pragma unroll
    for (int j = 0; j < 4; j++) acc[i][j] = (float4v){0.f,0.f,0.f,0.f};

  for (int k0 = 0; k0 < g.K; k0 += 32){
    // ---- load + transform + pack (no LDS yet) ----
    short8 apk0, apk1;
    {
      float af[16];
      if (aval){
        const float4v* ap = (const float4v*)(Aptr + k0);
        float4v v0 = ap[0], v1 = ap[1], v2 = ap[2], v3 = ap[3];
        #pragma unroll
        for (int e = 0; e < 4; e++){ af[e]=v0[e]; af[4+e]=v1[e]; af[8+e]=v2[e]; af[12+e]=v3[e]; }
      } else {
        #pragma unroll
        for (int e = 0; e < 16; e++) af[e] = 0.f;
      }
      #pragma unroll
      for (int e = 0; e < 8; e++){ apk0[e] = f2bf(af[e]); apk1[e] = f2bf(af[8+e]); }
    }
    float bval[4][4];   // [i over k][j over m]
    #pragma unroll
    for (int i = 0; i < 4; i++){
      const int k = k0 + kg*4 + i;
      if (BMODE == 2){
        const float pwk = g.pw[k], pbk = g.pb[k];
        #pragma unroll
        for (int j = 0; j < 4; j++) bval[i][j] = lv[j] ? silu_g((aud4[j]*pwk + pbk)*invn4[j]) : 0.f;
      } else if (BMODE == 3){
        float a0=0,a1=0,a2=0,a3=0;
        for (int p = 0; p < g.pool_s; p++){
          const float* bp = bbase + (long)k*kstep + (long)p*g.BLw;
          if (vec4){ float4v v = *(const float4v*)bp; a0+=v[0]; a1+=v[1]; a2+=v[2]; a3+=v[3]; }
          else { if(lv[0]) a0+=bp[0]; if(lv[1]) a1+=bp[1]; if(lv[2]) a2+=bp[2]; if(lv[3]) a3+=bp[3]; }
        }
        bval[i][0]=a0*pinv; bval[i][1]=a1*pinv; bval[i][2]=a2*pinv; bval[i][3]=a3*pinv;
      } else {
        const float* bp = bbase + (long)k*kstep;
        float v0=0,v1=0,v2=0,v3=0;
        if (vec4){ float4v v = *(const float4v*)bp; v0=v[0]; v1=v[1]; v2=v[2]; v3=v[3]; }
        else { if(lv[0]) v0=bp[0]; if(lv[1]) v1=bp[1]; if(lv[2]) v2=bp[2]; if(lv[3]) v3=bp[3]; }
        if (BMODE == 1){ v0=silu_g(v0*invn4[0]); v1=silu_g(v1*invn4[1]); v2=silu_g(v2*invn4[2]); v3=silu_g(v3*invn4[3]); }
        else if (BMODE == 4){ v0*=invn4[0]; v1*=invn4[1]; v2*=invn4[2]; v3*=invn4[3]; }
        bval[i][0]=v0; bval[i][1]=v1; bval[i][2]=v2; bval[i][3]=v3;
      }
    }
    short4v bpk[4];
    #pragma unroll
    for (int j = 0; j < 4; j++){
      short4v p;
      #pragma unroll
      for (int i = 0; i < 4; i++) p[i] = f2bf(bval[i][j]);
      bpk[j] = p;
    }

    __syncthreads();   // previous iteration's frag reads done
    *(short8*)&Asm[ar*72 + ah*16]     = apk0;
    *(short8*)&Asm[ar*72 + ah*16 + 8] = apk1;
    #pragma unroll
    for (int j = 0; j < 4; j++)
      *(short4v*)&Bsm[(mg*4 + j)*72 + kg*4] = bpk[j];
    __syncthreads();

    short8 afr[4], bfr[4];
    #pragma unroll
    for (int i = 0; i < 4; i++) afr[i] = *(const short8*)&Asm[(wc*64 + i*16 + r16)*72 + q*8];
    #pragma unroll
    for (int j = 0; j < 4; j++) bfr[j] = *(const short8*)&Bsm[(wsd*64 + j*16 + r16)*72 + q*8];
    #pragma unroll
    for (int i = 0; i < 4; i++)
      #pragma unroll
      for (int j = 0; j < 4; j++)
        acc[i][j] = __builtin_amdgcn_mfma_f32_16x16x32_bf16(afr[i], bfr[j], acc[i][j], 0, 0, 0);
  }

  // ---- epilogue ----
  float invw16[4][4];
  #pragma unroll
  for (int i = 0; i < 4; i++)
    #pragma unroll
    for (int rg = 0; rg < 4; rg++){
      int n = n0 + wc*64 + i*16 + q*4 + rg;
      invw16[i][rg] = (n < g.N) ? g.invwA[n] : 0.f;
    }
  #pragma unroll
  for (int j = 0; j < 4; j++){
    int sg = s0 + wsd*64 + j*16 + r16;
    int b2 = sg / FL; int r2 = sg - b2*FL;
    int f2 = (g.Fdim > 1) ? (r2 / g.Lw) : 0;
    int l2 = g.lq0 + (r2 - f2*g.Lw);
    if (b2 >= 2 || l2 < 0 || l2 >= 2048) continue;
    float invn_p = 0.f, aud_p = 0.f;
    if (EMODE==2 || EMODE==3) invn_p = g.invn[(b2*g.Fdim + f2)*2048 + l2];
    if (EMODE==3) aud_p = g.audio[(b2*128 + f2)*2048 + l2];
    #pragma unroll
    for (int i = 0; i < 4; i++){
      #pragma unroll
      for (int rg = 0; rg < 4; rg++){
        int n = n0 + wc*64 + i*16 + q*4 + rg;
        if (n >= g.N) continue;
        float v = acc[i][j][rg] * invw16[i][rg];
        if (EMODE == 2){
          float xn = g.auxX[((long)(b2*g.N + n)*g.Fdim + f2)*2048 + l2] * invn_p;
          v = (xn*0.7f + v*0.3f)*MPS;
        } else if (EMODE == 3){
          float xn = (aud_p*g.pw[n] + g.pb[n])*invn_p;
          v = (xn*0.7f + v*0.3f)*MPS;
        }
        if (EMODE == 4){
          if (n < g.Nsto) g.Cout[((long)(b2*g.Nsto + n))*g.CLw + l2] = silu_g(v);
          else            g.Cout2[((long)(b2*g.Nsto + (n - g.Nsto)))*g.CLw + l2] = v;
        } else {
          g.Cout[((long)(b2*g.Nsto + n)*g.Fdim + f2)*g.CLw + (l2 - g.Cl0)] = v;
        }
      }
    }
  }
}

// ---------------- depthwise 5x3 conv (+ silu), 4 outputs/thread ----------------
struct DwArgs { const float* R1; const float* wd; const float* invw; float* R2; int C, F, Lc, l0; };
__global__ __launch_bounds__(256) void dw2d_kernel(DwArgs a){
  int idx = blockIdx.x*256 + threadIdx.x;
  int Lq = a.Lc >> 2;
  int total = 2*a.C*a.F*Lq;
  if (idx >= total) return;
  int lq = idx % Lq; int r = idx / Lq;
  int f = r % a.F; r /= a.F;
  int c = r % a.C; int b = r / a.C;
  int labs = a.l0 + lq*4;
  const float* w = a.wd + c*15;
  float iw = a.invw[c];
  int Lw = a.Lc + 8;
  const float* rowbase = a.R1 + (long)((b*a.C + c)*a.F)*Lw + (labs - (a.l0 - 4));
  float acc0=0,acc1=0,acc2=0,acc3=0;
  #pragma unroll
  for (int df = -2; df <= 2; df++){
    int ff = f + df; if (ff < 0 || ff >= a.F) continue;
    const float* p = rowbase + (long)ff*Lw;
    float w0 = w[(df+2)*3+0], w1 = w[(df+2)*3+1], w2 = w[(df+2)*3+2];
    float xm = (labs > 0) ? p[-1] : 0.f;
    float x0 = p[0], x1 = p[1], x2 = p[2], x3 = p[3];
    float x4 = (labs + 4 < 2048) ? p[4] : 0.f;
    acc0 += w0*xm + w1*x0 + w2*x1;
    acc1 += w0*x0 + w1*x1 + w2*x2;
    acc2 += w0*x1 + w1*x2 + w2*x3;
    acc3 += w0*x2 + w1*x3 + w2*x4;
  }
  float4v o = { silu_g(acc0*iw), silu_g(acc1*iw), silu_g(acc2*iw), silu_g(acc3*iw) };
  *(float4v*)&a.R2[((long)((b*a.C + c)*a.F + f))*a.Lc + (labs - a.l0)] = o;
}

// ---------------- seq depthwise 3-tap (+ silu), 4 outputs/thread ----------------
__global__ __launch_bounds__(256) void dwseq_kernel(const float* __restrict__ HS, const float* __restrict__ w,
                                                    const float* __restrict__ invw, float* __restrict__ H2){
  int idx = blockIdx.x*256 + threadIdx.x;
  if (idx >= 2*1024*512) return;
  int e = idx*4;
  int tt = e & 2047; int bc = e >> 11; int c = bc & 1023;
  const float* base = HS + (long)bc*2048 + tt;
  float iw = invw[c];
  const float* ww = w + c*3;
  float w0 = ww[0]*iw, w1 = ww[1]*iw, w2 = ww[2]*iw;
  float xm = (tt > 0) ? base[-1] : 0.f;
  float x0 = base[0], x1 = base[1], x2 = base[2], x3 = base[3];
  float x4 = (tt < 2044) ? base[4] : 0.f;
  float4v o = { silu_g(w0*xm + w1*x0 + w2*x1),
                silu_g(w0*x0 + w1*x1 + w2*x2),
                silu_g(w0*x1 + w1*x2 + w2*x3),
                silu_g(w0*x2 + w1*x3 + w2*x4) };
  *(float4v*)&H2[(long)bc*2048 + tt] = o;
}

// ---------------- minGRU scan + gate ----------------
__global__ __launch_bounds__(256) void scan_kernel(const float* __restrict__ ZC, const float* __restrict__ G,
                                                   float* __restrict__ SC){
  int bc = blockIdx.x;            // 0..2047 = b*1024+c
  int b = bc >> 10, c = bc & 1023;
  const float* zrow = ZC + ((long)(b*2048 + c))*2048;
  const float* crow = ZC + ((long)(b*2048 + 1024 + c))*2048;
  const float* grow = G + (long)bc*2048;
  float* orow = SC + (long)bc*2048;
  int tid = threadIdx.x;
  int t0 = tid*8;
  float av[8], bv[8];
  float A = 1.f, Bv = 0.f;
  #pragma unroll
  for (int j = 0; j < 8; j++){
    float z = zrow[t0+j]; float cval = crow[t0+j];
    float zs = 1.f/(1.f + __expf(-z));
    float a = 1.f - zs; float bb = zs*cval;
    av[j] = a; bv[j] = bb;
    Bv = a*Bv + bb;
    A = a*A;
  }
  __shared__ float sA[256], sB[256];
  sA[tid] = A; sB[tid] = Bv;
  __syncthreads();
  for (int off = 1; off < 256; off <<= 1){
    float pA = 1.f, pB = 0.f;
    if (tid >= off){ pA = sA[tid-off]; pB = sB[tid-off]; }
    __syncthreads();
    float nA = A*pA; float nB = A*pB + Bv;
    A = nA; Bv = nB;
    sA[tid] = A; sB[tid] = Bv;
    __syncthreads();
  }
  float h = (tid > 0) ? sB[tid-1] : 0.f;
  #pragma unroll
  for (int j = 0; j < 8; j++){
    h = av[j]*h + bv[j];
    orow[t0+j] = h * silu_g(grow[t0+j]);
  }
}

// ---------------- final mp_silu ----------------
__global__ __launch_bounds__(256) void final_kernel(const float* __restrict__ SEQ, float* __restrict__ out){
  int i = blockIdx.x*256 + threadIdx.x;
  if (i < 2*512*2048) out[i] = silu_g(SEQ[i]);
}

extern "C" void kernel_launch(void* const* d_in, const int* in_sizes, int n_in,
                              void* d_out, int out_size, void* d_ws, size_t ws_size,
                              hipStream_t stream) {
  const float* audio = (const float*)d_in[0];
  const float* pw = (const float*)d_in[1];
  const float* pb = (const float*)d_in[2];
  const float* cw1[3] = {(const float*)d_in[3], (const float*)d_in[7], (const float*)d_in[11]};
  const float* cwd[3] = {(const float*)d_in[4], (const float*)d_in[8], (const float*)d_in[12]};
  const float* cw2[3] = {(const float*)d_in[5], (const float*)d_in[9], (const float*)d_in[13]};
  const float* cdn[3] = {(const float*)d_in[6], (const float*)d_in[10], (const float*)d_in[14]};
  const float* hgw  = (const float*)d_in[15];
  const float* dww  = (const float*)d_in[16];
  const float* gruw = (const float*)d_in[17];
  const float* outw = (const float*)d_in[18];
  float* out = (float*)d_out;

  float* W = (float*)d_ws;
  float* INVW    = W;                      // 32768
  float* INVN    = W + 32768;              // 524288
  float* INVNSEQ = INVN + 524288;          // 4096
  float* SEQ     = INVNSEQ + 4096;         // 2097152
  float* IN1     = SEQ + 2097152;          // 16777216
  float* IN2     = IN1 + 16777216;         // 8388608
  float* ARENA   = IN2 + 8388608;

  long wf = (long)(ws_size / 4);
  auto need = [](long ncq){
    long Lcq = 2048/ncq;
    long conv = 32768L*(Lcq+8) + 32768L*Lcq + 16384L*Lcq;
    long ar = conv > 25165824L ? conv : 25165824L;
    return 27824128L + ar;
  };
  int nc = 8;
  if (wf >= need(2)) nc = 2; else if (wf >= need(4)) nc = 4;
  int Lc = 2048/nc;

  // ---- weight norms ----
  {
    NormArgs na;
    const float* wp[16] = {cw1[0],cwd[0],cw2[0],cdn[0], cw1[1],cwd[1],cw2[1],cdn[1],
                           cw1[2],cwd[2],cw2[2],cdn[2], hgw, dww, gruw, outw};
    int Os[16] = {128,128,64,128, 256,256,128,256, 512,512,256,512, 8192,4096,8192,2048};
    int Ks[16] = {64,15,128,64, 128,15,256,128, 256,15,512,256, 512,3,1024,1024};
    int off = 0, rows = 0;
    for (int i = 0; i < 16; i++){ na.e[i].w = wp[i]; na.e[i].O = Os[i]; na.e[i].K = Ks[i]; na.e[i].off = off; off += Os[i]; rows += Os[i]; }
    rownorm_kernel<<<rows, 64, 0, stream>>>(na, INVW);
  }

  // ---- conv blocks ----
  int Cin_[3]  = {64,128,256};
  int Cmid_[3] = {128,256,512};
  int F_[3]    = {128,32,8};
  int s_[3]    = {4,4,8};
  const float* Xin[3] = {nullptr, IN1, IN2};
  float* Xout[3] = {IN1, IN2, SEQ};
  int w1o[3] = {0,448,1344}, wdo[3] = {128,704,1856}, w2o[3] = {256,960,2368}, dno[3] = {320,1088,2624};

  float* R1 = ARENA;
  float* R2 = ARENA + 32768L*(Lc+8);
  float* Hb = R2 + 32768L*Lc;

  for (int b = 0; b < 3; b++){
    int Cin = Cin_[b], Cmid = Cmid_[b], F = F_[b], s = s_[b];
    if (b == 0)
      invn_audio_kernel<<<(2*128*2048)/256, 256, 0, stream>>>(audio, pw, pb, INVN);
    else {
      int total = 2*F*2048;
      invn_x_kernel<<<(total+255)/256, 256, 0, stream>>>(Xin[b], INVN, Cin, F);
    }
    for (int ci = 0; ci < nc; ci++){
      int l0 = ci*Lc;
      // conv1: Cin -> Cmid on aligned window [l0-4, l0+Lc+4)
      GemmArgs ga{};
      ga.A = cw1[b]; ga.invwA = INVW + w1o[b];
      ga.Bsrc = Xin[b]; ga.invn = INVN; ga.audio = audio; ga.pw = pw; ga.pb = pb;
      ga.Cout = R1; ga.N = Cmid; ga.K = Cin; ga.Fdim = F; ga.Lw = Lc+8; ga.lq0 = l0-4;
      ga.BLw = 2048; ga.Bl0 = 0; ga.CLw = Lc+8; ga.Cl0 = l0-4; ga.Nsto = Cmid; ga.Fsrc = F; ga.pool_s = 1;
      int M1 = 2*F*(Lc+8);
      dim3 g1((M1+127)/128, (Cmid+127)/128);
      if (b == 0) mgemm_kernel<2,0><<<g1,256,0,stream>>>(ga);
      else        mgemm_kernel<1,0><<<g1,256,0,stream>>>(ga);
      // depthwise 5x3 + silu
      DwArgs da{R1, cwd[b], INVW + wdo[b], R2, Cmid, F, Lc, l0};
      int tdw = 2*Cmid*F*(Lc/4);
      dw2d_kernel<<<(tdw+255)/256, 256, 0, stream>>>(da);
      // conv2 + mp_add -> Hb
      GemmArgs gb{};
      gb.A = cw2[b]; gb.invwA = INVW + w2o[b];
      gb.Bsrc = R2; gb.invn = INVN; gb.audio = audio; gb.pw = pw; gb.pb = pb; gb.auxX = Xin[b];
      gb.Cout = Hb; gb.N = Cin; gb.K = Cmid; gb.Fdim = F; gb.Lw = Lc; gb.lq0 = l0;
      gb.BLw = Lc; gb.Bl0 = l0; gb.CLw = Lc; gb.Cl0 = l0; gb.Nsto = Cin; gb.Fsrc = F; gb.pool_s = 1;
      int M2 = 2*F*Lc;
      dim3 g2((M2+127)/128, (Cin+127)/128);
      if (b == 0) mgemm_kernel<0,3><<<g2,256,0,stream>>>(gb);
      else        mgemm_kernel<0,2><<<g2,256,0,stream>>>(gb);
      // avgpool_freq + dn conv -> next block input
      GemmArgs gc{};
      gc.A = cdn[b]; gc.invwA = INVW + dno[b];
      gc.Bsrc = Hb; gc.Cout = Xout[b];
      gc.N = Cmid; gc.K = Cin; gc.Fdim = F/s; gc.Lw = Lc; gc.lq0 = l0;
      gc.BLw = Lc; gc.Bl0 = l0; gc.CLw = 2048; gc.Cl0 = 0; gc.Nsto = Cmid; gc.Fsrc = F; gc.pool_s = s;
      int M3 = 2*(F/s)*Lc;
      dim3 g3((M3+127)/128, (Cmid+127)/128);
      mgemm_kernel<3,0><<<g3,256,0,stream>>>(gc);
    }
  }

  // ---- seq blocks ----
  float* HS = ARENA;
  float* G  = ARENA + 4194304;
  float* H2 = G + 4194304;
  float* ZC = H2 + 4194304;
  float* SC = ZC + 8388608;

  for (int i = 0; i < 4; i++){
    invn_x_kernel<<<(4096+255)/256, 256, 0, stream>>>(SEQ, INVNSEQ, 512, 1);
    const float* hgi  = hgw  + (long)i*2048*512;
    const float* dwi  = dww  + (long)i*1024*3;
    const float* grui = gruw + (long)i*2048*1024;
    const float* outi = outw + (long)i*512*1024;
    // hg conv (both halves): n<1024 -> silu -> HS, else raw -> G
    GemmArgs gh{};
    gh.A = hgi; gh.invwA = INVW + 3136 + i*2048;
    gh.Bsrc = SEQ; gh.invn = INVNSEQ;
    gh.Cout = HS; gh.Cout2 = G;
    gh.N = 2048; gh.K = 512; gh.Fdim = 1; gh.Lw = 2048; gh.lq0 = 0;
    gh.BLw = 2048; gh.Bl0 = 0; gh.CLw = 2048; gh.Cl0 = 0; gh.Nsto = 1024; gh.Fsrc = 1; gh.pool_s = 1;
    mgemm_kernel<4,4><<<dim3(32,16),256,0,stream>>>(gh);
    // depthwise 3-tap + silu
    dwseq_kernel<<<(2*1024*512)/256, 256, 0, stream>>>(HS, dwi, INVW + 11328 + i*1024, H2);
    // gru conv 1024 -> 2048 (z|c)
    GemmArgs gz{};
    gz.A = grui; gz.invwA = INVW + 15424 + i*2048;
    gz.Bsrc = H2; gz.Cout = ZC; gz.N = 2048; gz.K = 1024; gz.Fdim = 1; gz.Lw = 2048; gz.lq0 = 0;
    gz.BLw = 2048; gz.Bl0 = 0; gz.CLw = 2048; gz.Cl0 = 0; gz.Nsto = 2048; gz.Fsrc = 1; gz.pool_s = 1;
    mgemm_kernel<0,0><<<dim3(32,16),256,0,stream>>>(gz);
    // scan + gate
    scan_kernel<<<2048,256,0,stream>>>(ZC, G, SC);
    // out conv + mp_add -> SEQ (in place)
    GemmArgs go{};
    go.A = outi; go.invwA = INVW + 23616 + i*512;
    go.Bsrc = SC; go.auxX = SEQ; go.invn = INVNSEQ;
    go.Cout = SEQ; go.N = 512; go.K = 1024; go.Fdim = 1; go.Lw = 2048; go.lq0 = 0;
    go.BLw = 2048; go.Bl0 = 0; go.CLw = 2048; go.Cl0 = 0; go.Nsto = 512; go.Fsrc = 1; go.pool_s = 1;
    mgemm_kernel<0,2><<<dim3(32,4),256,0,stream>>>(go);
  }

  final_kernel<<<(2*512*2048)/256, 256, 0, stream>>>(SEQ, out);

  (void)in_sizes; (void)n_in; (void)out_size;
}

// Round 3
// 2329.438 us; speedup vs baseline: 3.4723x; 1.9881x over previous
//
#include <hip/hip_runtime.h>
#include <math.h>

#define GAIN 1.6778523489932886f     // 1/0.596
#define MPS  1.3130643285972254f     // 1/sqrt(0.7^2+0.3^2)

typedef __attribute__((ext_vector_type(8))) short short8;
typedef __attribute__((ext_vector_type(4))) short short4v;
typedef __attribute__((ext_vector_type(4))) float float4v;

__device__ __forceinline__ float silu_g(float x){
  float s = 1.0f/(1.0f + __expf(-x));
  return x*s*GAIN;
}
__device__ __forceinline__ short f2bf(float f){
  unsigned u = __builtin_bit_cast(unsigned, f);
  u += 0x7fffu + ((u >> 16) & 1u);
  return (short)(u >> 16);
}
__device__ __forceinline__ float bf2f(unsigned short h){
  return __builtin_bit_cast(float, ((unsigned)h) << 16);
}

// ---------------- weight row-norm reciprocals ----------------
struct NormEnt { const float* w; int O, K, off; };
struct NormArgs { NormEnt e[16]; };

__global__ __launch_bounds__(64) void rownorm_kernel(NormArgs na, float* invw){
  int row = blockIdx.x;
  int base = 0; int i;
  for (i = 0; i < 16; i++){
    if (row < base + na.e[i].O) break;
    base += na.e[i].O;
  }
  if (i >= 16) return;
  int r = row - base; int K = na.e[i].K;
  const float* w = na.e[i].w + (long)r*K;
  float s = 0.f;
  for (int k = threadIdx.x; k < K; k += 64){ float v = w[k]; s += v*v; }
  for (int off = 32; off; off >>= 1) s += __shfl_down(s, off);
  if (threadIdx.x == 0) invw[na.e[i].off + r] = rsqrtf(s + 1e-8f);
}

// ---------------- weight cast: bf16(w * invw[row]) ----------------
struct WcEnt { const float* src; int dstOff, K, invwOff, base; };
struct WcArgs { WcEnt e[16]; int total; };

__global__ __launch_bounds__(256) void wcast_kernel(WcArgs a, const float* __restrict__ invw,
                                                    unsigned short* __restrict__ wbf){
  int gid = blockIdx.x*256 + threadIdx.x;
  if (gid >= a.total) return;
  int i = 0;
  #pragma unroll
  for (int t = 1; t < 16; t++) if (gid >= a.e[t].base) i = t;
  int e = gid - a.e[i].base;
  int row = e / a.e[i].K;
  wbf[a.e[i].dstOff + e] = (unsigned short)f2bf(a.e[i].src[e] * invw[a.e[i].invwOff + row]);
}

// ---------------- b0 inverse pixel-norm (closed form over audio projection) ----------------
__global__ __launch_bounds__(256) void invn_audio_kernel(const float* __restrict__ audio, const float* __restrict__ pw,
                                                         const float* __restrict__ pb, float* __restrict__ invn){
  int pos = blockIdx.x*256 + threadIdx.x;
  if (pos >= 2*128*2048) return;
  float a = audio[pos];
  float S1=0.f, S2=0.f, S3=0.f;
  for (int o = 0; o < 64; o++){ float p = pw[o], q = pb[o]; S1 += p*p; S2 += p*q; S3 += q*q; }
  invn[pos] = rsqrtf((a*a*S1 + 2.f*a*S2 + S3)/64.f + 1e-4f);
}

// ---------------- conv-block pixel-norm prep: invn + bf16 silu(x*invn) ----------------
__global__ __launch_bounds__(256) void pixelprep_kernel(const float* __restrict__ X, unsigned short* __restrict__ XB,
                                                        float* __restrict__ invn, int C, int F){
  int blk = blockIdx.x;
  int lt = blk & 7; int bf = blk >> 3; int b = bf / F; int f = bf - b*F;
  int l = lt*256 + threadIdx.x;
  const float* base = X + ((long)(b*C)*F + f)*2048 + l;
  long stride = (long)F*2048;
  float s = 0.f;
  for (int c = 0; c < C; c++){ float v = base[c*stride]; s += v*v; }
  float iv = rsqrtf(s/(float)C + 1e-4f);
  invn[((long)b*F + f)*2048 + l] = iv;
  unsigned short* ob = XB + ((long)(b*C)*F + f)*2048 + l;
  for (int c = 0; c < C; c++){ float v = base[c*stride]; ob[c*stride] = (unsigned short)f2bf(silu_g(v*iv)); }
}

// ---------------- seq pixel-norm prep: invn + bf16 (x*invn) ----------------
__global__ __launch_bounds__(256) void seqprep_kernel(const float* __restrict__ SEQ, unsigned short* __restrict__ XS,
                                                      float* __restrict__ invn){
  int t = threadIdx.x; int cs = t >> 5; int li = t & 31;
  int pos0 = blockIdx.x*32;
  int b = pos0 >> 11; int l = (pos0 & 2047) + li;
  const float* base = SEQ + ((long)b*512)*2048 + l;
  float s = 0.f;
  for (int c = cs; c < 512; c += 8){ float v = base[(long)c*2048]; s += v*v; }
  __shared__ float red[256];
  red[t] = s; __syncthreads();
  if (cs < 4) red[t] += red[t+128]; __syncthreads();
  if (cs < 2) red[t] += red[t+64];  __syncthreads();
  if (cs < 1) red[t] += red[t+32];  __syncthreads();
  float iv = rsqrtf(red[li]/512.f + 1e-4f);
  if (cs == 0) invn[b*2048 + l] = iv;
  unsigned short* ob = XS + ((long)b*512)*2048 + l;
  for (int c = cs; c < 512; c += 8) ob[(long)c*2048] = (unsigned short)f2bf(base[(long)c*2048]*iv);
}

// ---------------- bf16 MFMA fused GEMM ----------------
// BMODE: 0 = bf16 copy (windowed/zero-padded), 1 = freq-pool mean of bf16, 2 = audio closed-form (b0 conv1)
// EMODE: 0 f32 store, 1 bf16 store, 2 mp_add auxX->bf16, 3 mp_add audio->bf16,
//        4 split n<Nsto: silu->CoutH else raw->Cout2H, 5 mp_add auxX->f32, 6 mp_add auxX + silu -> f32
struct GemmArgs {
  const unsigned short* A;       // pre-normalized bf16 weights, row-major K
  const unsigned short* Bh;      // bf16 B source
  const float* invn; const float* audio;
  const float* pw; const float* pb; const float* auxX;
  float* Cout; unsigned short* CoutH; unsigned short* Cout2H;
  int N, K, Fdim, Lw, lq0, BLw, Bl0, CLw, Cl0, Nsto, Fsrc, pool_s;
};

template<int BMODE, int EMODE>
__global__ __launch_bounds__(256,2) void mgemm_kernel(GemmArgs g){
  __shared__ __align__(16) unsigned short Asm[128*40];
  __shared__ __align__(16) unsigned short Bsm[128*40];
  const int t = threadIdx.x;
  const int lane = t & 63;
  const int wave = t >> 6;
  const int wc = wave >> 1, wsd = wave & 1;
  const int q = lane >> 4, r16 = lane & 15;
  const int s0 = blockIdx.x * 128;
  const int n0 = blockIdx.y * 128;
  const int FL = g.Fdim * g.Lw;

  // A staging mapping
  const int ar = t >> 1, ah = t & 1;
  const int an = n0 + ar;
  const bool aval = an < g.N;
  const unsigned short* Aptr = g.A + (long)an*g.K + ah*16;

  // B staging mapping: (k-group kg 0..7 of 4k, m-group mg 0..31 of 4m)
  const int kg = t & 7, mg = t >> 3;
  const int mb = s0 + mg*4;
  int bcol = mb / FL; int rr = mb - bcol*FL;
  int fcol = (g.Fdim > 1) ? (rr / g.Lw) : 0;
  int labs = g.lq0 + (rr - fcol*g.Lw);
  const bool cv = (bcol < 2);
  bool lv[4];
  #pragma unroll
  for (int j = 0; j < 4; j++) lv[j] = cv && (labs + j >= 0) && (labs + j < 2048);
  const bool vec4 = cv && (labs >= 0) && (labs + 3 < 2048);
  const unsigned short* bbase = g.Bh;
  if (cv) bbase = g.Bh + ((long)(bcol*g.K)*g.Fsrc + fcol*g.pool_s)*g.BLw + (labs - g.Bl0);
  const long kstep = (long)g.Fsrc * g.BLw;
  const float pinv = 1.f/(float)g.pool_s;

  float invn4[4] = {0,0,0,0}, aud4[4] = {0,0,0,0};
  if (BMODE == 2){
    #pragma unroll
    for (int j = 0; j < 4; j++) if (lv[j]){
      invn4[j] = g.invn[(bcol*g.Fdim + fcol)*2048 + labs + j];
      aud4[j]  = g.audio[(bcol*128 + fcol)*2048 + labs + j];
    }
  }

  float4v acc[4][4];
  #pragma unroll
  for (int i = 0; i < 4; i++)
    #pragma unroll
    for (int j = 0; j < 4; j++) acc[i][j] = (float4v){0.f,0.f,0.f,0.f};

  for (int k0 = 0; k0 < g.K; k0 += 32){
    short8 apk0 = {0,0,0,0,0,0,0,0}, apk1 = {0,0,0,0,0,0,0,0};
    if (aval){
      apk0 = *(const short8*)(Aptr + k0);
      apk1 = *(const short8*)(Aptr + k0 + 8);
    }
    short4v bpk[4];
    if (BMODE == 0){
      short4v uld[4];
      #pragma unroll
      for (int i = 0; i < 4; i++){
        const int k = k0 + kg*4 + i;
        const unsigned short* bp = bbase + (long)k*kstep;
        if (vec4) uld[i] = *(const short4v*)bp;
        else {
          short4v u = {0,0,0,0};
          #pragma unroll
          for (int j = 0; j < 4; j++) if (lv[j]) u[j] = (short)bp[j];
          uld[i] = u;
        }
      }
      #pragma unroll
      for (int j = 0; j < 4; j++){
        short4v p;
        #pragma unroll
        for (int i = 0; i < 4; i++) p[i] = uld[i][j];
        bpk[j] = p;
      }
    } else if (BMODE == 1){
      float sacc[4][4];
      #pragma unroll
      for (int i = 0; i < 4; i++){
        const int k = k0 + kg*4 + i;
        float s0v=0,s1v=0,s2v=0,s3v=0;
        for (int p = 0; p < g.pool_s; p++){
          const unsigned short* bp = bbase + (long)k*kstep + (long)p*g.BLw;
          if (vec4){ short4v u = *(const short4v*)bp;
            s0v += bf2f((unsigned short)u[0]); s1v += bf2f((unsigned short)u[1]);
            s2v += bf2f((unsigned short)u[2]); s3v += bf2f((unsigned short)u[3]); }
          else {
            if (lv[0]) s0v += bf2f(bp[0]); if (lv[1]) s1v += bf2f(bp[1]);
            if (lv[2]) s2v += bf2f(bp[2]); if (lv[3]) s3v += bf2f(bp[3]);
          }
        }
        sacc[i][0]=s0v*pinv; sacc[i][1]=s1v*pinv; sacc[i][2]=s2v*pinv; sacc[i][3]=s3v*pinv;
      }
      #pragma unroll
      for (int j = 0; j < 4; j++){
        short4v p;
        #pragma unroll
        for (int i = 0; i < 4; i++) p[i] = f2bf(sacc[i][j]);
        bpk[j] = p;
      }
    } else { // BMODE == 2
      float tv[4][4];
      #pragma unroll
      for (int i = 0; i < 4; i++){
        const int k = k0 + kg*4 + i;
        const float pwk = g.pw[k], pbk = g.pb[k];
        #pragma unroll
        for (int j = 0; j < 4; j++) tv[i][j] = lv[j] ? silu_g((aud4[j]*pwk + pbk)*invn4[j]) : 0.f;
      }
      #pragma unroll
      for (int j = 0; j < 4; j++){
        short4v p;
        #pragma unroll
        for (int i = 0; i < 4; i++) p[i] = f2bf(tv[i][j]);
        bpk[j] = p;
      }
    }

    __syncthreads();
    *(short8*)&Asm[ar*40 + ah*16]     = apk0;
    *(short8*)&Asm[ar*40 + ah*16 + 8] = apk1;
    #pragma unroll
    for (int j = 0; j < 4; j++)
      *(short4v*)&Bsm[(mg*4 + j)*40 + kg*4] = bpk[j];
    __syncthreads();

    short8 afr[4], bfr[4];
    #pragma unroll
    for (int i = 0; i < 4; i++) afr[i] = *(const short8*)&Asm[(wc*64 + i*16 + r16)*40 + q*8];
    #pragma unroll
    for (int j = 0; j < 4; j++) bfr[j] = *(const short8*)&Bsm[(wsd*64 + j*16 + r16)*40 + q*8];
    #pragma unroll
    for (int i = 0; i < 4; i++)
      #pragma unroll
      for (int j = 0; j < 4; j++)
        acc[i][j] = __builtin_amdgcn_mfma_f32_16x16x32_bf16(afr[i], bfr[j], acc[i][j], 0, 0, 0);
  }

  // ---- epilogue ----
  #pragma unroll
  for (int j = 0; j < 4; j++){
    int sg = s0 + wsd*64 + j*16 + r16;
    int b2 = sg / FL; int r2 = sg - b2*FL;
    int f2 = (g.Fdim > 1) ? (r2 / g.Lw) : 0;
    int l2 = g.lq0 + (r2 - f2*g.Lw);
    if (b2 >= 2 || l2 < 0 || l2 >= 2048) continue;
    float invn_p = 0.f, aud_p = 0.f;
    if (EMODE==2 || EMODE==3 || EMODE==5 || EMODE==6) invn_p = g.invn[(b2*g.Fdim + f2)*2048 + l2];
    if (EMODE==3) aud_p = g.audio[(b2*128 + f2)*2048 + l2];
    #pragma unroll
    for (int i = 0; i < 4; i++){
      #pragma unroll
      for (int rg = 0; rg < 4; rg++){
        int n = n0 + wc*64 + i*16 + q*4 + rg;
        if (n >= g.N) continue;
        float v = acc[i][j][rg];
        long oidx = ((long)(b2*g.Nsto + n)*g.Fdim + f2)*g.CLw + (l2 - g.Cl0);
        if (EMODE == 0){
          g.Cout[oidx] = v;
        } else if (EMODE == 1){
          g.CoutH[oidx] = (unsigned short)f2bf(v);
        } else if (EMODE == 2){
          float xn = g.auxX[((long)(b2*g.N + n)*g.Fdim + f2)*2048 + l2] * invn_p;
          g.CoutH[oidx] = (unsigned short)f2bf((xn*0.7f + v*0.3f)*MPS);
        } else if (EMODE == 3){
          float xn = (aud_p*g.pw[n] + g.pb[n])*invn_p;
          g.CoutH[oidx] = (unsigned short)f2bf((xn*0.7f + v*0.3f)*MPS);
        } else if (EMODE == 4){
          if (n < g.Nsto) g.CoutH[(long)(b2*g.Nsto + n)*g.CLw + l2] = (unsigned short)f2bf(silu_g(v));
          else            g.Cout2H[(long)(b2*g.Nsto + (n - g.Nsto))*g.CLw + l2] = (unsigned short)f2bf(v);
        } else if (EMODE == 5){
          float xn = g.auxX[((long)(b2*g.N + n))*2048 + l2] * invn_p;
          g.Cout[oidx] = (xn*0.7f + v*0.3f)*MPS;
        } else { // 6
          float xn = g.auxX[((long)(b2*g.N + n))*2048 + l2] * invn_p;
          g.Cout[oidx] = silu_g((xn*0.7f + v*0.3f)*MPS);
        }
      }
    }
  }
}

// ---------------- depthwise 5x3 conv (+ silu), bf16 in/out ----------------
struct DwArgs { const unsigned short* R1; const unsigned short* wd; unsigned short* R2; int C, F, Lc, l0; };
__global__ __launch_bounds__(256) void dw2d_kernel(DwArgs a){
  int idx = blockIdx.x*256 + threadIdx.x;
  int Lq = a.Lc >> 2;
  int total = 2*a.C*a.F*Lq;
  if (idx >= total) return;
  int lq = idx % Lq; int r = idx / Lq;
  int f = r % a.F; r /= a.F;
  int c = r % a.C; int b = r / a.C;
  int labs = a.l0 + lq*4;
  const unsigned short* w = a.wd + c*15;
  int Lw = a.Lc + 8;
  const unsigned short* rowbase = a.R1 + (long)((b*a.C + c)*a.F)*Lw + (labs - (a.l0 - 4));
  float acc0=0,acc1=0,acc2=0,acc3=0;
  #pragma unroll
  for (int df = -2; df <= 2; df++){
    int ff = f + df; if (ff < 0 || ff >= a.F) continue;
    const unsigned short* p = rowbase + (long)ff*Lw;
    float w0 = bf2f(w[(df+2)*3+0]), w1 = bf2f(w[(df+2)*3+1]), w2 = bf2f(w[(df+2)*3+2]);
    short4v u = *(const short4v*)p;
    float xm = (labs > 0) ? bf2f(p[-1]) : 0.f;
    float x0 = bf2f((unsigned short)u[0]), x1 = bf2f((unsigned short)u[1]);
    float x2 = bf2f((unsigned short)u[2]), x3 = bf2f((unsigned short)u[3]);
    float x4 = (labs + 4 < 2048) ? bf2f(p[4]) : 0.f;
    acc0 += w0*xm + w1*x0 + w2*x1;
    acc1 += w0*x0 + w1*x1 + w2*x2;
    acc2 += w0*x1 + w1*x2 + w2*x3;
    acc3 += w0*x2 + w1*x3 + w2*x4;
  }
  short4v o = { f2bf(silu_g(acc0)), f2bf(silu_g(acc1)), f2bf(silu_g(acc2)), f2bf(silu_g(acc3)) };
  *(short4v*)&a.R2[((long)((b*a.C + c)*a.F + f))*a.Lc + (labs - a.l0)] = o;
}

// ---------------- seq depthwise 3-tap (+ silu), bf16 in/out ----------------
__global__ __launch_bounds__(256) void dwseq_kernel(const unsigned short* __restrict__ HS, const unsigned short* __restrict__ w,
                                                    unsigned short* __restrict__ H2){
  int idx = blockIdx.x*256 + threadIdx.x;
  if (idx >= 2*1024*512) return;
  int e = idx*4;
  int tt = e & 2047; int bc = e >> 11; int c = bc & 1023;
  const unsigned short* base = HS + (long)bc*2048 + tt;
  float w0 = bf2f(w[c*3+0]), w1 = bf2f(w[c*3+1]), w2 = bf2f(w[c*3+2]);
  short4v u = *(const short4v*)base;
  float xm = (tt > 0) ? bf2f(base[-1]) : 0.f;
  float x0 = bf2f((unsigned short)u[0]), x1 = bf2f((unsigned short)u[1]);
  float x2 = bf2f((unsigned short)u[2]), x3 = bf2f((unsigned short)u[3]);
  float x4 = (tt < 2044) ? bf2f(base[4]) : 0.f;
  short4v o = { f2bf(silu_g(w0*xm + w1*x0 + w2*x1)),
                f2bf(silu_g(w0*x0 + w1*x1 + w2*x2)),
                f2bf(silu_g(w0*x1 + w1*x2 + w2*x3)),
                f2bf(silu_g(w0*x2 + w1*x3 + w2*x4)) };
  *(short4v*)&H2[(long)bc*2048 + tt] = o;
}

// ---------------- minGRU scan + gate ----------------
__global__ __launch_bounds__(256) void scan_kernel(const float* __restrict__ ZC, const unsigned short* __restrict__ G,
                                                   unsigned short* __restrict__ SC){
  int bc = blockIdx.x;            // 0..2047 = b*1024+c
  int b = bc >> 10, c = bc & 1023;
  const float* zrow = ZC + ((long)(b*2048 + c))*2048;
  const float* crow = ZC + ((long)(b*2048 + 1024 + c))*2048;
  const unsigned short* grow = G + (long)bc*2048;
  unsigned short* orow = SC + (long)bc*2048;
  int tid = threadIdx.x;
  int t0 = tid*8;
  float av[8], bv[8];
  float A = 1.f, Bv = 0.f;
  #pragma unroll
  for (int j = 0; j < 8; j++){
    float z = zrow[t0+j]; float cval = crow[t0+j];
    float zs = 1.f/(1.f + __expf(-z));
    float a = 1.f - zs; float bb = zs*cval;
    av[j] = a; bv[j] = bb;
    Bv = a*Bv + bb;
    A = a*A;
  }
  __shared__ float sA[256], sB[256];
  sA[tid] = A; sB[tid] = Bv;
  __syncthreads();
  for (int off = 1; off < 256; off <<= 1){
    float pA = 1.f, pB = 0.f;
    if (tid >= off){ pA = sA[tid-off]; pB = sB[tid-off]; }
    __syncthreads();
    float nA = A*pA; float nB = A*pB + Bv;
    A = nA; Bv = nB;
    sA[tid] = A; sB[tid] = Bv;
    __syncthreads();
  }
  float h = (tid > 0) ? sB[tid-1] : 0.f;
  #pragma unroll
  for (int j = 0; j < 8; j++){
    h = av[j]*h + bv[j];
    orow[t0+j] = (unsigned short)f2bf(h * silu_g(bf2f(grow[t0+j])));
  }
}

extern "C" void kernel_launch(void* const* d_in, const int* in_sizes, int n_in,
                              void* d_out, int out_size, void* d_ws, size_t ws_size,
                              hipStream_t stream) {
  const float* audio = (const float*)d_in[0];
  const float* pw = (const float*)d_in[1];
  const float* pb = (const float*)d_in[2];
  const float* cw1[3] = {(const float*)d_in[3], (const float*)d_in[7], (const float*)d_in[11]};
  const float* cwd[3] = {(const float*)d_in[4], (const float*)d_in[8], (const float*)d_in[12]};
  const float* cw2[3] = {(const float*)d_in[5], (const float*)d_in[9], (const float*)d_in[13]};
  const float* cdn[3] = {(const float*)d_in[6], (const float*)d_in[10], (const float*)d_in[14]};
  const float* hgw  = (const float*)d_in[15];
  const float* dww  = (const float*)d_in[16];
  const float* gruw = (const float*)d_in[17];
  const float* outw = (const float*)d_in[18];
  float* out = (float*)d_out;

  // ---- workspace layout (bytes) ----
  char* P = (char*)d_ws;
  float*          INVW = (float*)P;                     P += 131072;
  unsigned short* WBF  = (unsigned short*)P;            P += 30443776;   // 15,221,888 bf16
  float*          INVN = (float*)P;                     P += 2097152;
  char*           XBZC = P;                             P += 33554432;   // XB (conv b1/b2) then ZC (seq)
  float*          IN1  = (float*)P;                     P += 67108864;   // also seq bf16 scratch later
  float*          IN2  = (float*)P;                     P += 33554432;
  float*          SEQ  = (float*)P;                     P += 8388608;
  char*           ARENA = P;
  long arenaBytes = (long)ws_size - (long)(P - (char*)d_ws);

  // weight table (order: cw1/cwd/cw2/cdn x3, hg, dww, gru, out)
  const float* wsrc[16] = {cw1[0],cwd[0],cw2[0],cdn[0], cw1[1],cwd[1],cw2[1],cdn[1],
                           cw1[2],cwd[2],cw2[2],cdn[2], hgw, dww, gruw, outw};
  int Os[16] = {128,128,64,128, 256,256,128,256, 512,512,256,512, 8192,4096,8192,2048};
  int Ks[16] = {64,15,128,64, 128,15,256,128, 256,15,512,256, 512,3,1024,1024};
  int wbfOff[16], ivOff[16];
  {
    int wo = 0, io = 0;
    for (int i = 0; i < 16; i++){ wbfOff[i] = wo; ivOff[i] = io; wo += Os[i]*Ks[i]; io += Os[i]; }
  }
  // rownorm
  {
    NormArgs na;
    int rows = 0;
    for (int i = 0; i < 16; i++){ na.e[i].w = wsrc[i]; na.e[i].O = Os[i]; na.e[i].K = Ks[i]; na.e[i].off = ivOff[i]; rows += Os[i]; }
    rownorm_kernel<<<rows, 64, 0, stream>>>(na, INVW);
  }
  // wcast
  {
    WcArgs wa; int base = 0;
    for (int i = 0; i < 16; i++){
      wa.e[i].src = wsrc[i]; wa.e[i].dstOff = wbfOff[i]; wa.e[i].K = Ks[i];
      wa.e[i].invwOff = ivOff[i]; wa.e[i].base = base; base += Os[i]*Ks[i];
    }
    wa.total = base;
    wcast_kernel<<<(base+255)/256, 256, 0, stream>>>(wa, INVW, WBF);
  }

  // ---- conv blocks ----
  int Cin_[3]  = {64,128,256};
  int Cmid_[3] = {128,256,512};
  int F_[3]    = {128,32,8};
  int s_[3]    = {4,4,8};
  const float* Xin[3] = {nullptr, IN1, IN2};
  float* Xout[3] = {IN1, IN2, SEQ};
  int iW1[3]={0,4,8}, iWd[3]={1,5,9}, iW2[3]={2,6,10}, iDn[3]={3,7,11};

  for (int b = 0; b < 3; b++){
    int Cin = Cin_[b], Cmid = Cmid_[b], F = F_[b], s = s_[b];
    // pick chunk count: smallest nc with chunk buffers fitting arena
    int nc = 16;
    for (int c = 1; c <= 16; c <<= 1){
      long Lc = 2048/c;
      long bytes = 2L*(2L*Cmid*F*(Lc+8) + 2L*Cmid*F*Lc + 2L*Cin*F*Lc);
      if (bytes <= arenaBytes){ nc = c; break; }
    }
    int Lc = 2048/nc;
    unsigned short* R1 = (unsigned short*)ARENA;
    unsigned short* R2 = R1 + 2L*Cmid*F*(Lc+8);
    unsigned short* Hb = R2 + 2L*Cmid*F*Lc;
    unsigned short* XB = (unsigned short*)XBZC;

    if (b == 0)
      invn_audio_kernel<<<(2*128*2048)/256, 256, 0, stream>>>(audio, pw, pb, INVN);
    else
      pixelprep_kernel<<<2*F*8, 256, 0, stream>>>(Xin[b], XB, INVN, Cin, F);

    for (int ci = 0; ci < nc; ci++){
      int l0 = ci*Lc;
      // conv1: Cin -> Cmid on window [l0-4, l0+Lc+4) -> R1 bf16
      GemmArgs ga{};
      ga.A = WBF + wbfOff[iW1[b]];
      ga.Bh = XB; ga.invn = INVN; ga.audio = audio; ga.pw = pw; ga.pb = pb;
      ga.CoutH = R1; ga.N = Cmid; ga.K = Cin; ga.Fdim = F; ga.Lw = Lc+8; ga.lq0 = l0-4;
      ga.BLw = 2048; ga.Bl0 = 0; ga.CLw = Lc+8; ga.Cl0 = l0-4; ga.Nsto = Cmid; ga.Fsrc = F; ga.pool_s = 1;
      int M1 = 2*F*(Lc+8);
      dim3 g1((M1+127)/128, (Cmid+127)/128);
      if (b == 0) mgemm_kernel<2,1><<<g1,256,0,stream>>>(ga);
      else        mgemm_kernel<0,1><<<g1,256,0,stream>>>(ga);
      // depthwise 5x3 + silu -> R2 bf16
      DwArgs da{R1, WBF + wbfOff[iWd[b]], R2, Cmid, F, Lc, l0};
      int tdw = 2*Cmid*F*(Lc/4);
      dw2d_kernel<<<(tdw+255)/256, 256, 0, stream>>>(da);
      // conv2 + mp_add -> Hb bf16
      GemmArgs gb{};
      gb.A = WBF + wbfOff[iW2[b]];
      gb.Bh = R2; gb.invn = INVN; gb.audio = audio; gb.pw = pw; gb.pb = pb; gb.auxX = Xin[b];
      gb.CoutH = Hb; gb.N = Cin; gb.K = Cmid; gb.Fdim = F; gb.Lw = Lc; gb.lq0 = l0;
      gb.BLw = Lc; gb.Bl0 = l0; gb.CLw = Lc; gb.Cl0 = l0; gb.Nsto = Cin; gb.Fsrc = F; gb.pool_s = 1;
      int M2 = 2*F*Lc;
      dim3 g2((M2+127)/128, (Cin+127)/128);
      if (b == 0) mgemm_kernel<0,3><<<g2,256,0,stream>>>(gb);
      else        mgemm_kernel<0,2><<<g2,256,0,stream>>>(gb);
      // avgpool_freq + dn conv -> Xout fp32 (full-L layout)
      GemmArgs gc{};
      gc.A = WBF + wbfOff[iDn[b]];
      gc.Bh = Hb; gc.Cout = Xout[b];
      gc.N = Cmid; gc.K = Cin; gc.Fdim = F/s; gc.Lw = Lc; gc.lq0 = l0;
      gc.BLw = Lc; gc.Bl0 = l0; gc.CLw = 2048; gc.Cl0 = 0; gc.Nsto = Cmid; gc.Fsrc = F; gc.pool_s = s;
      int M3 = 2*(F/s)*Lc;
      dim3 g3((M3+127)/128, (Cmid+127)/128);
      mgemm_kernel<1,0><<<g3,256,0,stream>>>(gc);
    }
  }

  // ---- seq blocks (bf16 scratch lives in IN1, ZC in XBZC) ----
  unsigned short* XS = (unsigned short*)IN1;
  unsigned short* HS = XS + 2097152;
  unsigned short* G  = HS + 4194304;
  unsigned short* H2 = G  + 4194304;
  unsigned short* SC = H2 + 4194304;
  float* ZC = (float*)XBZC;

  for (int i = 0; i < 4; i++){
    seqprep_kernel<<<128, 256, 0, stream>>>(SEQ, XS, INVN);
    // hg conv (both halves): n<1024 -> silu -> HS, else raw -> G
    GemmArgs gh{};
    gh.A = WBF + wbfOff[12] + (long)i*2048*512;
    gh.Bh = XS;
    gh.CoutH = HS; gh.Cout2H = G;
    gh.N = 2048; gh.K = 512; gh.Fdim = 1; gh.Lw = 2048; gh.lq0 = 0;
    gh.BLw = 2048; gh.Bl0 = 0; gh.CLw = 2048; gh.Cl0 = 0; gh.Nsto = 1024; gh.Fsrc = 1; gh.pool_s = 1;
    mgemm_kernel<0,4><<<dim3(32,16),256,0,stream>>>(gh);
    // depthwise 3-tap + silu
    dwseq_kernel<<<(2*1024*512)/256, 256, 0, stream>>>(HS, WBF + wbfOff[13] + i*1024*3, H2);
    // gru conv 1024 -> 2048 (z|c) -> ZC fp32
    GemmArgs gz{};
    gz.A = WBF + wbfOff[14] + (long)i*2048*1024;
    gz.Bh = H2; gz.Cout = ZC; gz.N = 2048; gz.K = 1024; gz.Fdim = 1; gz.Lw = 2048; gz.lq0 = 0;
    gz.BLw = 2048; gz.Bl0 = 0; gz.CLw = 2048; gz.Cl0 = 0; gz.Nsto = 2048; gz.Fsrc = 1; gz.pool_s = 1;
    mgemm_kernel<0,0><<<dim3(32,16),256,0,stream>>>(gz);
    // scan + gate -> SC bf16
    scan_kernel<<<2048,256,0,stream>>>(ZC, G, SC);
    // out conv + mp_add -> SEQ (i<3) or mp_add+silu -> d_out (i==3)
    GemmArgs go{};
    go.A = WBF + wbfOff[15] + (long)i*512*1024;
    go.Bh = SC; go.auxX = SEQ; go.invn = INVN;
    go.N = 512; go.K = 1024; go.Fdim = 1; go.Lw = 2048; go.lq0 = 0;
    go.BLw = 2048; go.Bl0 = 0; go.CLw = 2048; go.Cl0 = 0; go.Nsto = 512; go.Fsrc = 1; go.pool_s = 1;
    if (i < 3){ go.Cout = SEQ; mgemm_kernel<0,5><<<dim3(32,4),256,0,stream>>>(go); }
    else      { go.Cout = out; mgemm_kernel<0,6><<<dim3(32,4),256,0,stream>>>(go); }
  }

  (void)in_sizes; (void)n_in; (void)out_size;
}

// Round 4
// 1891.734 us; speedup vs baseline: 4.2757x; 1.2314x over previous
//
#include <hip/hip_runtime.h>
#include <math.h>

#define GAIN 1.6778523489932886f     // 1/0.596
#define MPS  1.3130643285972254f     // 1/sqrt(0.7^2+0.3^2)

typedef __attribute__((ext_vector_type(8))) short short8;
typedef __attribute__((ext_vector_type(4))) short short4v;
typedef __attribute__((ext_vector_type(4))) float float4v;

__device__ __forceinline__ float silu_g(float x){
  float s = 1.0f/(1.0f + __expf(-x));
  return x*s*GAIN;
}
__device__ __forceinline__ short f2bf(float f){
  unsigned u = __builtin_bit_cast(unsigned, f);
  u += 0x7fffu + ((u >> 16) & 1u);
  return (short)(u >> 16);
}
__device__ __forceinline__ float bf2f(unsigned short h){
  return __builtin_bit_cast(float, ((unsigned)h) << 16);
}

// ---------------- weight row-norm reciprocals ----------------
struct NormEnt { const float* w; int O, K, off; };
struct NormArgs { NormEnt e[16]; };

__global__ __launch_bounds__(64) void rownorm_kernel(NormArgs na, float* invw){
  int row = blockIdx.x;
  int base = 0; int i;
  for (i = 0; i < 16; i++){
    if (row < base + na.e[i].O) break;
    base += na.e[i].O;
  }
  if (i >= 16) return;
  int r = row - base; int K = na.e[i].K;
  const float* w = na.e[i].w + (long)r*K;
  float s = 0.f;
  for (int k = threadIdx.x; k < K; k += 64){ float v = w[k]; s += v*v; }
  for (int off = 32; off; off >>= 1) s += __shfl_down(s, off);
  if (threadIdx.x == 0) invw[na.e[i].off + r] = rsqrtf(s + 1e-8f);
}

// ---------------- weight cast: bf16(w * invw[row]) ----------------
struct WcEnt { const float* src; int dstOff, K, invwOff, base; };
struct WcArgs { WcEnt e[16]; int total; };

__global__ __launch_bounds__(256) void wcast_kernel(WcArgs a, const float* __restrict__ invw,
                                                    unsigned short* __restrict__ wbf){
  int gid = blockIdx.x*256 + threadIdx.x;
  if (gid >= a.total) return;
  int i = 0;
  #pragma unroll
  for (int t = 1; t < 16; t++) if (gid >= a.e[t].base) i = t;
  int e = gid - a.e[i].base;
  int row = e / a.e[i].K;
  wbf[a.e[i].dstOff + e] = (unsigned short)f2bf(a.e[i].src[e] * invw[a.e[i].invwOff + row]);
}

// ---------------- audio projection stats (one wave) ----------------
__global__ __launch_bounds__(64) void projstats_kernel(const float* __restrict__ pw, const float* __restrict__ pb,
                                                       float* __restrict__ S){
  int t = threadIdx.x;
  float p = pw[t], q = pb[t];
  float s1 = p*p, s2 = p*q, s3 = q*q;
  for (int off = 32; off; off >>= 1){
    s1 += __shfl_down(s1, off); s2 += __shfl_down(s2, off); s3 += __shfl_down(s3, off);
  }
  if (t == 0){ S[0] = s1; S[1] = s2; S[2] = s3; }
}

// ---------------- b0 inverse pixel-norm (closed form, element-wise 4-wide) ----------------
__global__ __launch_bounds__(256) void invn_audio_kernel(const float* __restrict__ audio, const float* __restrict__ S,
                                                         float* __restrict__ invn){
  long i = blockIdx.x*256 + threadIdx.x;
  if (i >= (2L*128*2048)/4) return;
  long e = i*4;
  float S1 = S[0], S2 = S[1], S3 = S[2];
  float4v a = *(const float4v*)&audio[e];
  float4v o;
  #pragma unroll
  for (int j = 0; j < 4; j++) o[j] = rsqrtf((a[j]*a[j]*S1 + 2.f*a[j]*S2 + S3)/64.f + 1e-4f);
  *(float4v*)&invn[e] = o;
}

// ---------------- pixel-norm reduce: invn[(b*F+f)*2048+l] ----------------
// block = G c-groups x (256/G) coalesced lanes over l
template<int G>
__global__ __launch_bounds__(256) void invn_reduce_kernel(const float* __restrict__ X, float* __restrict__ invn,
                                                          int C, int F){
  constexpr int L = 256/G;
  int t = threadIdx.x; int cs = t / L; int li = t % L;
  long pos = (long)blockIdx.x*L + li;
  int bf = (int)(pos >> 11); int l = (int)(pos & 2047);
  int b = bf / F; int f = bf - b*F;
  const float* base = X + ((long)b*C*F + f)*2048 + l;
  long stride = (long)F*2048;
  float s = 0.f;
  for (int c = cs; c < C; c += G){ float v = base[(long)c*stride]; s += v*v; }
  __shared__ float red[256];
  red[t] = s; __syncthreads();
  #pragma unroll
  for (int off = G/2; off > 0; off >>= 1){
    if (cs < off) red[t] += red[t + off*L];
    __syncthreads();
  }
  if (cs == 0) invn[pos] = rsqrtf(red[li]/(float)C + 1e-4f);
}

// ---------------- pixel-norm apply: bf16( [silu](x*invn) ), 4-wide element-wise ----------------
template<bool SILU>
__global__ __launch_bounds__(256) void applynorm_kernel(const float* __restrict__ X, const float* __restrict__ invn,
                                                        unsigned short* __restrict__ XB, int C, int F, long total4){
  long i = blockIdx.x*256 + threadIdx.x;
  if (i >= total4) return;
  long e = i*4;
  int l = (int)(e & 2047); long r = e >> 11;      // r = (b*C + c)*F + f
  int f = (int)(r % F); long bc = r / F; int b = (int)(bc / C);
  float4v x = *(const float4v*)&X[e];
  float4v iv = *(const float4v*)&invn[((long)b*F + f)*2048 + l];
  short4v o;
  #pragma unroll
  for (int j = 0; j < 4; j++){
    float v = x[j]*iv[j];
    o[j] = f2bf(SILU ? silu_g(v) : v);
  }
  *(short4v*)&XB[e] = o;
}

// ---------------- bf16 MFMA fused GEMM ----------------
// BMODE: 0 = bf16 copy (windowed/zero-padded), 1 = freq-pool mean of bf16, 2 = audio closed-form (b0 conv1)
// EMODE: 0 f32 store, 1 bf16 store, 2 mp_add auxX->bf16, 3 mp_add audio->bf16,
//        4 split n<Nsto: silu->CoutH else raw->Cout2H, 5 mp_add auxX->f32, 6 mp_add auxX + silu -> f32
struct GemmArgs {
  const unsigned short* A;       // pre-normalized bf16 weights, row-major K
  const unsigned short* Bh;      // bf16 B source
  const float* invn; const float* audio;
  const float* pw; const float* pb; const float* auxX;
  float* Cout; unsigned short* CoutH; unsigned short* Cout2H;
  int N, K, Fdim, Lw, lq0, BLw, Bl0, CLw, Cl0, Nsto, Fsrc, pool_s;
};

template<int BMODE, int EMODE>
__global__ __launch_bounds__(256,2) void mgemm_kernel(GemmArgs g){
  __shared__ __align__(16) unsigned short Asm[128*40];
  __shared__ __align__(16) unsigned short Bsm[128*40];
  const int t = threadIdx.x;
  const int lane = t & 63;
  const int wave = t >> 6;
  const int wc = wave >> 1, wsd = wave & 1;
  const int q = lane >> 4, r16 = lane & 15;
  const int s0 = blockIdx.x * 128;
  const int n0 = blockIdx.y * 128;
  const int FL = g.Fdim * g.Lw;

  // A staging mapping
  const int ar = t >> 1, ah = t & 1;
  const int an = n0 + ar;
  const bool aval = an < g.N;
  const unsigned short* Aptr = g.A + (long)an*g.K + ah*16;

  // B staging mapping: (k-group kg 0..7 of 4k, m-group mg 0..31 of 4m)
  const int kg = t & 7, mg = t >> 3;
  const int mb = s0 + mg*4;
  int bcol = mb / FL; int rr = mb - bcol*FL;
  int fcol = (g.Fdim > 1) ? (rr / g.Lw) : 0;
  int labs = g.lq0 + (rr - fcol*g.Lw);
  const bool cv = (bcol < 2);
  bool lv[4];
  #pragma unroll
  for (int j = 0; j < 4; j++) lv[j] = cv && (labs + j >= 0) && (labs + j < 2048);
  const bool vec4 = cv && (labs >= 0) && (labs + 3 < 2048);
  const unsigned short* bbase = g.Bh;
  if (cv) bbase = g.Bh + ((long)(bcol*g.K)*g.Fsrc + fcol*g.pool_s)*g.BLw + (labs - g.Bl0);
  const long kstep = (long)g.Fsrc * g.BLw;
  const float pinv = 1.f/(float)g.pool_s;

  float invn4[4] = {0,0,0,0}, aud4[4] = {0,0,0,0};
  if (BMODE == 2){
    #pragma unroll
    for (int j = 0; j < 4; j++) if (lv[j]){
      invn4[j] = g.invn[(bcol*g.Fdim + fcol)*2048 + labs + j];
      aud4[j]  = g.audio[(bcol*128 + fcol)*2048 + labs + j];
    }
  }

  float4v acc[4][4];
  #pragma unroll
  for (int i = 0; i < 4; i++)
    #pragma unroll
    for (int j = 0; j < 4; j++) acc[i][j] = (float4v){0.f,0.f,0.f,0.f};

  for (int k0 = 0; k0 < g.K; k0 += 32){
    short8 apk0 = {0,0,0,0,0,0,0,0}, apk1 = {0,0,0,0,0,0,0,0};
    if (aval){
      apk0 = *(const short8*)(Aptr + k0);
      apk1 = *(const short8*)(Aptr + k0 + 8);
    }
    short4v bpk[4];
    if (BMODE == 0){
      short4v uld[4];
      #pragma unroll
      for (int i = 0; i < 4; i++){
        const int k = k0 + kg*4 + i;
        const unsigned short* bp = bbase + (long)k*kstep;
        if (vec4) uld[i] = *(const short4v*)bp;
        else {
          short4v u = {0,0,0,0};
          #pragma unroll
          for (int j = 0; j < 4; j++) if (lv[j]) u[j] = (short)bp[j];
          uld[i] = u;
        }
      }
      #pragma unroll
      for (int j = 0; j < 4; j++){
        short4v p;
        #pragma unroll
        for (int i = 0; i < 4; i++) p[i] = uld[i][j];
        bpk[j] = p;
      }
    } else if (BMODE == 1){
      float sacc[4][4];
      #pragma unroll
      for (int i = 0; i < 4; i++){
        const int k = k0 + kg*4 + i;
        float s0v=0,s1v=0,s2v=0,s3v=0;
        for (int p = 0; p < g.pool_s; p++){
          const unsigned short* bp = bbase + (long)k*kstep + (long)p*g.BLw;
          if (vec4){ short4v u = *(const short4v*)bp;
            s0v += bf2f((unsigned short)u[0]); s1v += bf2f((unsigned short)u[1]);
            s2v += bf2f((unsigned short)u[2]); s3v += bf2f((unsigned short)u[3]); }
          else {
            if (lv[0]) s0v += bf2f(bp[0]); if (lv[1]) s1v += bf2f(bp[1]);
            if (lv[2]) s2v += bf2f(bp[2]); if (lv[3]) s3v += bf2f(bp[3]);
          }
        }
        sacc[i][0]=s0v*pinv; sacc[i][1]=s1v*pinv; sacc[i][2]=s2v*pinv; sacc[i][3]=s3v*pinv;
      }
      #pragma unroll
      for (int j = 0; j < 4; j++){
        short4v p;
        #pragma unroll
        for (int i = 0; i < 4; i++) p[i] = f2bf(sacc[i][j]);
        bpk[j] = p;
      }
    } else { // BMODE == 2
      float tv[4][4];
      #pragma unroll
      for (int i = 0; i < 4; i++){
        const int k = k0 + kg*4 + i;
        const float pwk = g.pw[k], pbk = g.pb[k];
        #pragma unroll
        for (int j = 0; j < 4; j++) tv[i][j] = lv[j] ? silu_g((aud4[j]*pwk + pbk)*invn4[j]) : 0.f;
      }
      #pragma unroll
      for (int j = 0; j < 4; j++){
        short4v p;
        #pragma unroll
        for (int i = 0; i < 4; i++) p[i] = f2bf(tv[i][j]);
        bpk[j] = p;
      }
    }

    __syncthreads();
    *(short8*)&Asm[ar*40 + ah*16]     = apk0;
    *(short8*)&Asm[ar*40 + ah*16 + 8] = apk1;
    #pragma unroll
    for (int j = 0; j < 4; j++)
      *(short4v*)&Bsm[(mg*4 + j)*40 + kg*4] = bpk[j];
    __syncthreads();

    short8 afr[4], bfr[4];
    #pragma unroll
    for (int i = 0; i < 4; i++) afr[i] = *(const short8*)&Asm[(wc*64 + i*16 + r16)*40 + q*8];
    #pragma unroll
    for (int j = 0; j < 4; j++) bfr[j] = *(const short8*)&Bsm[(wsd*64 + j*16 + r16)*40 + q*8];
    #pragma unroll
    for (int i = 0; i < 4; i++)
      #pragma unroll
      for (int j = 0; j < 4; j++)
        acc[i][j] = __builtin_amdgcn_mfma_f32_16x16x32_bf16(afr[i], bfr[j], acc[i][j], 0, 0, 0);
  }

  // ---- epilogue ----
  #pragma unroll
  for (int j = 0; j < 4; j++){
    int sg = s0 + wsd*64 + j*16 + r16;
    int b2 = sg / FL; int r2 = sg - b2*FL;
    int f2 = (g.Fdim > 1) ? (r2 / g.Lw) : 0;
    int l2 = g.lq0 + (r2 - f2*g.Lw);
    if (b2 >= 2 || l2 < 0 || l2 >= 2048) continue;
    float invn_p = 0.f, aud_p = 0.f;
    if (EMODE==2 || EMODE==3 || EMODE==5 || EMODE==6) invn_p = g.invn[(b2*g.Fdim + f2)*2048 + l2];
    if (EMODE==3) aud_p = g.audio[(b2*128 + f2)*2048 + l2];
    #pragma unroll
    for (int i = 0; i < 4; i++){
      #pragma unroll
      for (int rg = 0; rg < 4; rg++){
        int n = n0 + wc*64 + i*16 + q*4 + rg;
        if (n >= g.N) continue;
        float v = acc[i][j][rg];
        long oidx = ((long)(b2*g.Nsto + n)*g.Fdim + f2)*g.CLw + (l2 - g.Cl0);
        if (EMODE == 0){
          g.Cout[oidx] = v;
        } else if (EMODE == 1){
          g.CoutH[oidx] = (unsigned short)f2bf(v);
        } else if (EMODE == 2){
          float xn = g.auxX[((long)(b2*g.N + n)*g.Fdim + f2)*2048 + l2] * invn_p;
          g.CoutH[oidx] = (unsigned short)f2bf((xn*0.7f + v*0.3f)*MPS);
        } else if (EMODE == 3){
          float xn = (aud_p*g.pw[n] + g.pb[n])*invn_p;
          g.CoutH[oidx] = (unsigned short)f2bf((xn*0.7f + v*0.3f)*MPS);
        } else if (EMODE == 4){
          if (n < g.Nsto) g.CoutH[(long)(b2*g.Nsto + n)*g.CLw + l2] = (unsigned short)f2bf(silu_g(v));
          else            g.Cout2H[(long)(b2*g.Nsto + (n - g.Nsto))*g.CLw + l2] = (unsigned short)f2bf(v);
        } else if (EMODE == 5){
          float xn = g.auxX[((long)(b2*g.N + n))*2048 + l2] * invn_p;
          g.Cout[oidx] = (xn*0.7f + v*0.3f)*MPS;
        } else { // 6
          float xn = g.auxX[((long)(b2*g.N + n))*2048 + l2] * invn_p;
          g.Cout[oidx] = silu_g((xn*0.7f + v*0.3f)*MPS);
        }
      }
    }
  }
}

// ---------------- depthwise 5x3 conv (+ silu), bf16 in/out ----------------
struct DwArgs { const unsigned short* R1; const unsigned short* wd; unsigned short* R2; int C, F, Lc, l0; };
__global__ __launch_bounds__(256) void dw2d_kernel(DwArgs a){
  int idx = blockIdx.x*256 + threadIdx.x;
  int Lq = a.Lc >> 2;
  int total = 2*a.C*a.F*Lq;
  if (idx >= total) return;
  int lq = idx % Lq; int r = idx / Lq;
  int f = r % a.F; r /= a.F;
  int c = r % a.C; int b = r / a.C;
  int labs = a.l0 + lq*4;
  const unsigned short* w = a.wd + c*15;
  int Lw = a.Lc + 8;
  const unsigned short* rowbase = a.R1 + (long)((b*a.C + c)*a.F)*Lw + (labs - (a.l0 - 4));
  float acc0=0,acc1=0,acc2=0,acc3=0;
  #pragma unroll
  for (int df = -2; df <= 2; df++){
    int ff = f + df; if (ff < 0 || ff >= a.F) continue;
    const unsigned short* p = rowbase + (long)ff*Lw;
    float w0 = bf2f(w[(df+2)*3+0]), w1 = bf2f(w[(df+2)*3+1]), w2 = bf2f(w[(df+2)*3+2]);
    short4v u = *(const short4v*)p;
    float xm = (labs > 0) ? bf2f(p[-1]) : 0.f;
    float x0 = bf2f((unsigned short)u[0]), x1 = bf2f((unsigned short)u[1]);
    float x2 = bf2f((unsigned short)u[2]), x3 = bf2f((unsigned short)u[3]);
    float x4 = (labs + 4 < 2048) ? bf2f(p[4]) : 0.f;
    acc0 += w0*xm + w1*x0 + w2*x1;
    acc1 += w0*x0 + w1*x1 + w2*x2;
    acc2 += w0*x1 + w1*x2 + w2*x3;
    acc3 += w0*x2 + w1*x3 + w2*x4;
  }
  short4v o = { f2bf(silu_g(acc0)), f2bf(silu_g(acc1)), f2bf(silu_g(acc2)), f2bf(silu_g(acc3)) };
  *(short4v*)&a.R2[((long)((b*a.C + c)*a.F + f))*a.Lc + (labs - a.l0)] = o;
}

// ---------------- seq depthwise 3-tap (+ silu), bf16 in/out ----------------
__global__ __launch_bounds__(256) void dwseq_kernel(const unsigned short* __restrict__ HS, const unsigned short* __restrict__ w,
                                                    unsigned short* __restrict__ H2){
  int idx = blockIdx.x*256 + threadIdx.x;
  if (idx >= 2*1024*512) return;
  int e = idx*4;
  int tt = e & 2047; int bc = e >> 11; int c = bc & 1023;
  const unsigned short* base = HS + (long)bc*2048 + tt;
  float w0 = bf2f(w[c*3+0]), w1 = bf2f(w[c*3+1]), w2 = bf2f(w[c*3+2]);
  short4v u = *(const short4v*)base;
  float xm = (tt > 0) ? bf2f(base[-1]) : 0.f;
  float x0 = bf2f((unsigned short)u[0]), x1 = bf2f((unsigned short)u[1]);
  float x2 = bf2f((unsigned short)u[2]), x3 = bf2f((unsigned short)u[3]);
  float x4 = (tt < 2044) ? bf2f(base[4]) : 0.f;
  short4v o = { f2bf(silu_g(w0*xm + w1*x0 + w2*x1)),
                f2bf(silu_g(w0*x0 + w1*x1 + w2*x2)),
                f2bf(silu_g(w0*x1 + w1*x2 + w2*x3)),
                f2bf(silu_g(w0*x2 + w1*x3 + w2*x4)) };
  *(short4v*)&H2[(long)bc*2048 + tt] = o;
}

// ---------------- minGRU scan + gate ----------------
__global__ __launch_bounds__(256) void scan_kernel(const float* __restrict__ ZC, const unsigned short* __restrict__ G,
                                                   unsigned short* __restrict__ SC){
  int bc = blockIdx.x;            // 0..2047 = b*1024+c
  int b = bc >> 10, c = bc & 1023;
  const float* zrow = ZC + ((long)(b*2048 + c))*2048;
  const float* crow = ZC + ((long)(b*2048 + 1024 + c))*2048;
  const unsigned short* grow = G + (long)bc*2048;
  unsigned short* orow = SC + (long)bc*2048;
  int tid = threadIdx.x;
  int t0 = tid*8;
  float av[8], bv[8];
  float A = 1.f, Bv = 0.f;
  #pragma unroll
  for (int j = 0; j < 8; j++){
    float z = zrow[t0+j]; float cval = crow[t0+j];
    float zs = 1.f/(1.f + __expf(-z));
    float a = 1.f - zs; float bb = zs*cval;
    av[j] = a; bv[j] = bb;
    Bv = a*Bv + bb;
    A = a*A;
  }
  __shared__ float sA[256], sB[256];
  sA[tid] = A; sB[tid] = Bv;
  __syncthreads();
  for (int off = 1; off < 256; off <<= 1){
    float pA = 1.f, pB = 0.f;
    if (tid >= off){ pA = sA[tid-off]; pB = sB[tid-off]; }
    __syncthreads();
    float nA = A*pA; float nB = A*pB + Bv;
    A = nA; Bv = nB;
    sA[tid] = A; sB[tid] = Bv;
    __syncthreads();
  }
  float h = (tid > 0) ? sB[tid-1] : 0.f;
  #pragma unroll
  for (int j = 0; j < 8; j++){
    h = av[j]*h + bv[j];
    orow[t0+j] = (unsigned short)f2bf(h * silu_g(bf2f(grow[t0+j])));
  }
}

extern "C" void kernel_launch(void* const* d_in, const int* in_sizes, int n_in,
                              void* d_out, int out_size, void* d_ws, size_t ws_size,
                              hipStream_t stream) {
  const float* audio = (const float*)d_in[0];
  const float* pw = (const float*)d_in[1];
  const float* pb = (const float*)d_in[2];
  const float* cw1[3] = {(const float*)d_in[3], (const float*)d_in[7], (const float*)d_in[11]};
  const float* cwd[3] = {(const float*)d_in[4], (const float*)d_in[8], (const float*)d_in[12]};
  const float* cw2[3] = {(const float*)d_in[5], (const float*)d_in[9], (const float*)d_in[13]};
  const float* cdn[3] = {(const float*)d_in[6], (const float*)d_in[10], (const float*)d_in[14]};
  const float* hgw  = (const float*)d_in[15];
  const float* dww  = (const float*)d_in[16];
  const float* gruw = (const float*)d_in[17];
  const float* outw = (const float*)d_in[18];
  float* out = (float*)d_out;

  // ---- workspace layout (bytes) ----
  char* P = (char*)d_ws;
  float*          INVW = (float*)P;                     P += 131072;     // 25664 used + S at [32000]
  unsigned short* WBF  = (unsigned short*)P;            P += 30443776;   // 15,221,888 bf16
  float*          INVN = (float*)P;                     P += 2097152;
  char*           XBZC = P;                             P += 33554432;   // XB (conv b1/b2) then ZC (seq)
  float*          IN1  = (float*)P;                     P += 67108864;   // also seq bf16 scratch later
  float*          IN2  = (float*)P;                     P += 33554432;
  float*          SEQ  = (float*)P;                     P += 8388608;
  char*           ARENA = P;
  long arenaBytes = (long)ws_size - (long)(P - (char*)d_ws);
  float* S = INVW + 32000;

  // weight table (order: cw1/cwd/cw2/cdn x3, hg, dww, gru, out)
  const float* wsrc[16] = {cw1[0],cwd[0],cw2[0],cdn[0], cw1[1],cwd[1],cw2[1],cdn[1],
                           cw1[2],cwd[2],cw2[2],cdn[2], hgw, dww, gruw, outw};
  int Os[16] = {128,128,64,128, 256,256,128,256, 512,512,256,512, 8192,4096,8192,2048};
  int Ks[16] = {64,15,128,64, 128,15,256,128, 256,15,512,256, 512,3,1024,1024};
  int wbfOff[16], ivOff[16];
  {
    int wo = 0, io = 0;
    for (int i = 0; i < 16; i++){ wbfOff[i] = wo; ivOff[i] = io; wo += Os[i]*Ks[i]; io += Os[i]; }
  }
  // rownorm
  {
    NormArgs na;
    int rows = 0;
    for (int i = 0; i < 16; i++){ na.e[i].w = wsrc[i]; na.e[i].O = Os[i]; na.e[i].K = Ks[i]; na.e[i].off = ivOff[i]; rows += Os[i]; }
    rownorm_kernel<<<rows, 64, 0, stream>>>(na, INVW);
  }
  // wcast
  {
    WcArgs wa; int base = 0;
    for (int i = 0; i < 16; i++){
      wa.e[i].src = wsrc[i]; wa.e[i].dstOff = wbfOff[i]; wa.e[i].K = Ks[i];
      wa.e[i].invwOff = ivOff[i]; wa.e[i].base = base; base += Os[i]*Ks[i];
    }
    wa.total = base;
    wcast_kernel<<<(base+255)/256, 256, 0, stream>>>(wa, INVW, WBF);
  }
  projstats_kernel<<<1, 64, 0, stream>>>(pw, pb, S);

  // ---- conv blocks ----
  int Cin_[3]  = {64,128,256};
  int Cmid_[3] = {128,256,512};
  int F_[3]    = {128,32,8};
  int s_[3]    = {4,4,8};
  const float* Xin[3] = {nullptr, IN1, IN2};
  float* Xout[3] = {IN1, IN2, SEQ};
  int iW1[3]={0,4,8}, iWd[3]={1,5,9}, iW2[3]={2,6,10}, iDn[3]={3,7,11};

  for (int b = 0; b < 3; b++){
    int Cin = Cin_[b], Cmid = Cmid_[b], F = F_[b], s = s_[b];
    // pick chunk count: smallest nc with chunk buffers fitting arena
    int nc = 16;
    for (int c = 1; c <= 16; c <<= 1){
      long Lc = 2048/c;
      long bytes = 2L*(2L*Cmid*F*(Lc+8) + 2L*Cmid*F*Lc + 2L*Cin*F*Lc);
      if (bytes <= arenaBytes){ nc = c; break; }
    }
    int Lc = 2048/nc;
    unsigned short* R1 = (unsigned short*)ARENA;
    unsigned short* R2 = R1 + 2L*Cmid*F*(Lc+8);
    unsigned short* Hb = R2 + 2L*Cmid*F*Lc;
    unsigned short* XB = (unsigned short*)XBZC;

    if (b == 0){
      invn_audio_kernel<<<(2*128*2048/4+255)/256, 256, 0, stream>>>(audio, S, INVN);
    } else {
      int positions = 2*F*2048;
      invn_reduce_kernel<8><<<positions/32, 256, 0, stream>>>(Xin[b], INVN, Cin, F);
      long total4 = (long)2*Cin*F*2048/4;
      applynorm_kernel<true><<<(int)((total4+255)/256), 256, 0, stream>>>(Xin[b], INVN, XB, Cin, F, total4);
    }

    for (int ci = 0; ci < nc; ci++){
      int l0 = ci*Lc;
      // conv1: Cin -> Cmid on window [l0-4, l0+Lc+4) -> R1 bf16
      GemmArgs ga{};
      ga.A = WBF + wbfOff[iW1[b]];
      ga.Bh = XB; ga.invn = INVN; ga.audio = audio; ga.pw = pw; ga.pb = pb;
      ga.CoutH = R1; ga.N = Cmid; ga.K = Cin; ga.Fdim = F; ga.Lw = Lc+8; ga.lq0 = l0-4;
      ga.BLw = 2048; ga.Bl0 = 0; ga.CLw = Lc+8; ga.Cl0 = l0-4; ga.Nsto = Cmid; ga.Fsrc = F; ga.pool_s = 1;
      int M1 = 2*F*(Lc+8);
      dim3 g1((M1+127)/128, (Cmid+127)/128);
      if (b == 0) mgemm_kernel<2,1><<<g1,256,0,stream>>>(ga);
      else        mgemm_kernel<0,1><<<g1,256,0,stream>>>(ga);
      // depthwise 5x3 + silu -> R2 bf16
      DwArgs da{R1, WBF + wbfOff[iWd[b]], R2, Cmid, F, Lc, l0};
      int tdw = 2*Cmid*F*(Lc/4);
      dw2d_kernel<<<(tdw+255)/256, 256, 0, stream>>>(da);
      // conv2 + mp_add -> Hb bf16
      GemmArgs gb{};
      gb.A = WBF + wbfOff[iW2[b]];
      gb.Bh = R2; gb.invn = INVN; gb.audio = audio; gb.pw = pw; gb.pb = pb; gb.auxX = Xin[b];
      gb.CoutH = Hb; gb.N = Cin; gb.K = Cmid; gb.Fdim = F; gb.Lw = Lc; gb.lq0 = l0;
      gb.BLw = Lc; gb.Bl0 = l0; gb.CLw = Lc; gb.Cl0 = l0; gb.Nsto = Cin; gb.Fsrc = F; gb.pool_s = 1;
      int M2 = 2*F*Lc;
      dim3 g2((M2+127)/128, (Cin+127)/128);
      if (b == 0) mgemm_kernel<0,3><<<g2,256,0,stream>>>(gb);
      else        mgemm_kernel<0,2><<<g2,256,0,stream>>>(gb);
      // avgpool_freq + dn conv -> Xout fp32 (full-L layout)
      GemmArgs gc{};
      gc.A = WBF + wbfOff[iDn[b]];
      gc.Bh = Hb; gc.Cout = Xout[b];
      gc.N = Cmid; gc.K = Cin; gc.Fdim = F/s; gc.Lw = Lc; gc.lq0 = l0;
      gc.BLw = Lc; gc.Bl0 = l0; gc.CLw = 2048; gc.Cl0 = 0; gc.Nsto = Cmid; gc.Fsrc = F; gc.pool_s = s;
      int M3 = 2*(F/s)*Lc;
      dim3 g3((M3+127)/128, (Cmid+127)/128);
      mgemm_kernel<1,0><<<g3,256,0,stream>>>(gc);
    }
  }

  // ---- seq blocks (bf16 scratch lives in IN1, ZC in XBZC) ----
  unsigned short* XS = (unsigned short*)IN1;
  unsigned short* HS = XS + 2097152;
  unsigned short* G  = HS + 4194304;
  unsigned short* H2 = G  + 4194304;
  unsigned short* SC = H2 + 4194304;
  float* ZC = (float*)XBZC;

  for (int i = 0; i < 4; i++){
    invn_reduce_kernel<16><<<4096/16, 256, 0, stream>>>(SEQ, INVN, 512, 1);
    applynorm_kernel<false><<<(2*512*2048/4)/256, 256, 0, stream>>>(SEQ, INVN, XS, 512, 1, (long)2*512*2048/4);
    // hg conv (both halves): n<1024 -> silu -> HS, else raw -> G
    GemmArgs gh{};
    gh.A = WBF + wbfOff[12] + (long)i*2048*512;
    gh.Bh = XS;
    gh.CoutH = HS; gh.Cout2H = G;
    gh.N = 2048; gh.K = 512; gh.Fdim = 1; gh.Lw = 2048; gh.lq0 = 0;
    gh.BLw = 2048; gh.Bl0 = 0; gh.CLw = 2048; gh.Cl0 = 0; gh.Nsto = 1024; gh.Fsrc = 1; gh.pool_s = 1;
    mgemm_kernel<0,4><<<dim3(32,16),256,0,stream>>>(gh);
    // depthwise 3-tap + silu
    dwseq_kernel<<<(2*1024*512)/256, 256, 0, stream>>>(HS, WBF + wbfOff[13] + i*1024*3, H2);
    // gru conv 1024 -> 2048 (z|c) -> ZC fp32
    GemmArgs gz{};
    gz.A = WBF + wbfOff[14] + (long)i*2048*1024;
    gz.Bh = H2; gz.Cout = ZC; gz.N = 2048; gz.K = 1024; gz.Fdim = 1; gz.Lw = 2048; gz.lq0 = 0;
    gz.BLw = 2048; gz.Bl0 = 0; gz.CLw = 2048; gz.Cl0 = 0; gz.Nsto = 2048; gz.Fsrc = 1; gz.pool_s = 1;
    mgemm_kernel<0,0><<<dim3(32,16),256,0,stream>>>(gz);
    // scan + gate -> SC bf16
    scan_kernel<<<2048,256,0,stream>>>(ZC, G, SC);
    // out conv + mp_add -> SEQ (i<3) or mp_add+silu -> d_out (i==3)
    GemmArgs go{};
    go.A = WBF + wbfOff[15] + (long)i*512*1024;
    go.Bh = SC; go.auxX = SEQ; go.invn = INVN;
    go.N = 512; go.K = 1024; go.Fdim = 1; go.Lw = 2048; go.lq0 = 0;
    go.BLw = 2048; go.Bl0 = 0; go.CLw = 2048; go.Cl0 = 0; go.Nsto = 512; go.Fsrc = 1; go.pool_s = 1;
    if (i < 3){ go.Cout = SEQ; mgemm_kernel<0,5><<<dim3(32,4),256,0,stream>>>(go); }
    else      { go.Cout = out; mgemm_kernel<0,6><<<dim3(32,4),256,0,stream>>>(go); }
  }

  (void)in_sizes; (void)n_in; (void)out_size;
}

// Round 5
// 1739.311 us; speedup vs baseline: 4.6503x; 1.0876x over previous
//
#include <hip/hip_runtime.h>
#include <math.h>

#define GAIN 1.6778523489932886f     // 1/0.596
#define MPS  1.3130643285972254f     // 1/sqrt(0.7^2+0.3^2)

typedef __attribute__((ext_vector_type(8))) short short8;
typedef __attribute__((ext_vector_type(4))) short short4v;
typedef __attribute__((ext_vector_type(4))) float float4v;

__device__ __forceinline__ float silu_g(float x){
  float s = 1.0f/(1.0f + __expf(-x));
  return x*s*GAIN;
}
__device__ __forceinline__ short f2bf(float f){
  unsigned u = __builtin_bit_cast(unsigned, f);
  u += 0x7fffu + ((u >> 16) & 1u);
  return (short)(u >> 16);
}
__device__ __forceinline__ float bf2f(unsigned short h){
  return __builtin_bit_cast(float, ((unsigned)h) << 16);
}

// ---------------- weight row-norm reciprocals ----------------
struct NormEnt { const float* w; int O, K, off; };
struct NormArgs { NormEnt e[16]; };

__global__ __launch_bounds__(64) void rownorm_kernel(NormArgs na, float* invw){
  int row = blockIdx.x;
  int base = 0; int i;
  for (i = 0; i < 16; i++){
    if (row < base + na.e[i].O) break;
    base += na.e[i].O;
  }
  if (i >= 16) return;
  int r = row - base; int K = na.e[i].K;
  const float* w = na.e[i].w + (long)r*K;
  float s = 0.f;
  for (int k = threadIdx.x; k < K; k += 64){ float v = w[k]; s += v*v; }
  for (int off = 32; off; off >>= 1) s += __shfl_down(s, off);
  if (threadIdx.x == 0) invw[na.e[i].off + r] = rsqrtf(s + 1e-8f);
}

// ---------------- weight cast: bf16(w * invw[row]) ----------------
struct WcEnt { const float* src; int dstOff, K, invwOff, base; };
struct WcArgs { WcEnt e[16]; int total; };

__global__ __launch_bounds__(256) void wcast_kernel(WcArgs a, const float* __restrict__ invw,
                                                    unsigned short* __restrict__ wbf){
  int gid = blockIdx.x*256 + threadIdx.x;
  if (gid >= a.total) return;
  int i = 0;
  #pragma unroll
  for (int t = 1; t < 16; t++) if (gid >= a.e[t].base) i = t;
  int e = gid - a.e[i].base;
  int row = e / a.e[i].K;
  wbf[a.e[i].dstOff + e] = (unsigned short)f2bf(a.e[i].src[e] * invw[a.e[i].invwOff + row]);
}

// ---------------- audio projection stats (one wave) ----------------
__global__ __launch_bounds__(64) void projstats_kernel(const float* __restrict__ pw, const float* __restrict__ pb,
                                                       float* __restrict__ S){
  int t = threadIdx.x;
  float p = pw[t], q = pb[t];
  float s1 = p*p, s2 = p*q, s3 = q*q;
  for (int off = 32; off; off >>= 1){
    s1 += __shfl_down(s1, off); s2 += __shfl_down(s2, off); s3 += __shfl_down(s3, off);
  }
  if (t == 0){ S[0] = s1; S[1] = s2; S[2] = s3; }
}

// ---------------- b0 inverse pixel-norm (closed form, element-wise 4-wide) ----------------
__global__ __launch_bounds__(256) void invn_audio_kernel(const float* __restrict__ audio, const float* __restrict__ S,
                                                         float* __restrict__ invn){
  long i = blockIdx.x*256 + threadIdx.x;
  if (i >= (2L*128*2048)/4) return;
  long e = i*4;
  float S1 = S[0], S2 = S[1], S3 = S[2];
  float4v a = *(const float4v*)&audio[e];
  float4v o;
  #pragma unroll
  for (int j = 0; j < 4; j++) o[j] = rsqrtf((a[j]*a[j]*S1 + 2.f*a[j]*S2 + S3)/64.f + 1e-4f);
  *(float4v*)&invn[e] = o;
}

// ---------------- pixel-norm reduce ----------------
template<int G>
__global__ __launch_bounds__(256) void invn_reduce_kernel(const float* __restrict__ X, float* __restrict__ invn,
                                                          int C, int F){
  constexpr int L = 256/G;
  int t = threadIdx.x; int cs = t / L; int li = t % L;
  long pos = (long)blockIdx.x*L + li;
  int bf = (int)(pos >> 11); int l = (int)(pos & 2047);
  int b = bf / F; int f = bf - b*F;
  const float* base = X + ((long)b*C*F + f)*2048 + l;
  long stride = (long)F*2048;
  float s = 0.f;
  for (int c = cs; c < C; c += G){ float v = base[(long)c*stride]; s += v*v; }
  __shared__ float red[256];
  red[t] = s; __syncthreads();
  #pragma unroll
  for (int off = G/2; off > 0; off >>= 1){
    if (cs < off) red[t] += red[t + off*L];
    __syncthreads();
  }
  if (cs == 0) invn[pos] = rsqrtf(red[li]/(float)C + 1e-4f);
}

// ---------------- pixel-norm apply ----------------
template<bool SILU>
__global__ __launch_bounds__(256) void applynorm_kernel(const float* __restrict__ X, const float* __restrict__ invn,
                                                        unsigned short* __restrict__ XB, int C, int F, long total4){
  long i = blockIdx.x*256 + threadIdx.x;
  if (i >= total4) return;
  long e = i*4;
  int l = (int)(e & 2047); long r = e >> 11;      // r = (b*C + c)*F + f
  int f = (int)(r % F); long bc = r / F; int b = (int)(bc / C);
  float4v x = *(const float4v*)&X[e];
  float4v iv = *(const float4v*)&invn[((long)b*F + f)*2048 + l];
  short4v o;
  #pragma unroll
  for (int j = 0; j < 4; j++){
    float v = x[j]*iv[j];
    o[j] = f2bf(SILU ? silu_g(v) : v);
  }
  *(short4v*)&XB[e] = o;
}

// ---------------- bf16 MFMA fused GEMM (128x128 tile, register-prefetched K-loop) ----------------
// BMODE: 0 = bf16 copy (windowed/zero-padded), 1 = freq-pool mean of bf16, 2 = audio closed-form (b0 conv1)
// EMODE: 0 f32 store, 1 bf16 store, 2 mp_add auxX->bf16, 3 mp_add audio->bf16,
//        4 split n<Nsto: silu->CoutH else raw->Cout2H
struct GemmArgs {
  const unsigned short* A;       // pre-normalized bf16 weights, row-major K
  const unsigned short* Bh;      // bf16 B source
  const float* invn; const float* audio;
  const float* pw; const float* pb; const float* auxX;
  float* Cout; unsigned short* CoutH; unsigned short* Cout2H;
  int N, K, Fdim, Lw, lq0, BLw, Bl0, CLw, Cl0, Nsto, Fsrc, pool_s;
};

template<int BMODE, int EMODE>
__global__ __launch_bounds__(256,2) void mgemm_kernel(GemmArgs g){
  __shared__ __align__(16) unsigned short Asm[128*40];
  __shared__ __align__(16) unsigned short Bsm[128*40];
  const int t = threadIdx.x;
  const int lane = t & 63;
  const int wave = t >> 6;
  const int wc = wave >> 1, wsd = wave & 1;
  const int q = lane >> 4, r16 = lane & 15;
  const int s0 = blockIdx.x * 128;
  const int n0 = blockIdx.y * 128;
  const int FL = g.Fdim * g.Lw;

  // A staging mapping
  const int ar = t >> 1, ah = t & 1;
  const int an = n0 + ar;
  const bool aval = an < g.N;
  const unsigned short* Aptr = g.A + (long)an*g.K + ah*16;

  // B staging mapping: (k-group kg 0..7 of 4k, m-group mg 0..31 of 4m)
  const int kg = t & 7, mg = t >> 3;
  const int mb = s0 + mg*4;
  int bcol = mb / FL; int rr = mb - bcol*FL;
  int fcol = (g.Fdim > 1) ? (rr / g.Lw) : 0;
  int labs = g.lq0 + (rr - fcol*g.Lw);
  const bool cv = (bcol < 2);
  bool lv[4];
  #pragma unroll
  for (int j = 0; j < 4; j++) lv[j] = cv && (labs + j >= 0) && (labs + j < 2048);
  const bool vec4 = cv && (labs >= 0) && (labs + 3 < 2048);
  const unsigned short* bbase = g.Bh;
  if (cv) bbase = g.Bh + ((long)(bcol*g.K)*g.Fsrc + fcol*g.pool_s)*g.BLw + (labs - g.Bl0);
  const long kstep = (long)g.Fsrc * g.BLw;
  const float pinv = 1.f/(float)g.pool_s;

  float invn4[4] = {0,0,0,0}, aud4[4] = {0,0,0,0};
  if (BMODE == 2){
    #pragma unroll
    for (int j = 0; j < 4; j++) if (lv[j]){
      invn4[j] = g.invn[(bcol*g.Fdim + fcol)*2048 + labs + j];
      aud4[j]  = g.audio[(bcol*128 + fcol)*2048 + labs + j];
    }
  }

  float4v acc[4][4];
  #pragma unroll
  for (int i = 0; i < 4; i++)
    #pragma unroll
    for (int j = 0; j < 4; j++) acc[i][j] = (float4v){0.f,0.f,0.f,0.f};

  // prefetch registers
  short8 pa0 = {0,0,0,0,0,0,0,0}, pa1 = {0,0,0,0,0,0,0,0};
  short4v praw[4];
  #pragma unroll
  for (int i = 0; i < 4; i++) praw[i] = (short4v){0,0,0,0};

  auto ldA = [&](int kb){
    if (aval){
      pa0 = *(const short8*)(Aptr + kb);
      pa1 = *(const short8*)(Aptr + kb + 8);
    }
  };
  auto ldB = [&](int kb){
    #pragma unroll
    for (int i = 0; i < 4; i++){
      const int k = kb + kg*4 + i;
      const unsigned short* bp = bbase + (long)k*kstep;
      if (vec4) praw[i] = *(const short4v*)bp;
      else {
        short4v u = {0,0,0,0};
        #pragma unroll
        for (int j = 0; j < 4; j++) if (lv[j]) u[j] = (short)bp[j];
        praw[i] = u;
      }
    }
  };

  ldA(0);
  if (BMODE == 0) ldB(0);

  for (int k0 = 0; k0 < g.K; k0 += 32){
    // consume prefetched A
    short8 sa0 = pa0, sa1 = pa1;
    // produce packed B for this tile
    short4v bpk[4];
    if (BMODE == 0){
      #pragma unroll
      for (int j = 0; j < 4; j++){
        short4v p;
        #pragma unroll
        for (int i = 0; i < 4; i++) p[i] = praw[i][j];
        bpk[j] = p;
      }
    } else if (BMODE == 1){
      float sacc[4][4];
      #pragma unroll
      for (int i = 0; i < 4; i++){
        const int k = k0 + kg*4 + i;
        float s0v=0,s1v=0,s2v=0,s3v=0;
        for (int p = 0; p < g.pool_s; p++){
          const unsigned short* bp = bbase + (long)k*kstep + (long)p*g.BLw;
          if (vec4){ short4v u = *(const short4v*)bp;
            s0v += bf2f((unsigned short)u[0]); s1v += bf2f((unsigned short)u[1]);
            s2v += bf2f((unsigned short)u[2]); s3v += bf2f((unsigned short)u[3]); }
          else {
            if (lv[0]) s0v += bf2f(bp[0]); if (lv[1]) s1v += bf2f(bp[1]);
            if (lv[2]) s2v += bf2f(bp[2]); if (lv[3]) s3v += bf2f(bp[3]);
          }
        }
        sacc[i][0]=s0v*pinv; sacc[i][1]=s1v*pinv; sacc[i][2]=s2v*pinv; sacc[i][3]=s3v*pinv;
      }
      #pragma unroll
      for (int j = 0; j < 4; j++){
        short4v p;
        #pragma unroll
        for (int i = 0; i < 4; i++) p[i] = f2bf(sacc[i][j]);
        bpk[j] = p;
      }
    } else { // BMODE == 2
      float tv[4][4];
      #pragma unroll
      for (int i = 0; i < 4; i++){
        const int k = k0 + kg*4 + i;
        const float pwk = g.pw[k], pbk = g.pb[k];
        #pragma unroll
        for (int j = 0; j < 4; j++) tv[i][j] = lv[j] ? silu_g((aud4[j]*pwk + pbk)*invn4[j]) : 0.f;
      }
      #pragma unroll
      for (int j = 0; j < 4; j++){
        short4v p;
        #pragma unroll
        for (int i = 0; i < 4; i++) p[i] = f2bf(tv[i][j]);
        bpk[j] = p;
      }
    }
    // prefetch next tile (loads fly over LDS store + MFMA phase)
    if (k0 + 32 < g.K){
      ldA(k0 + 32);
      if (BMODE == 0) ldB(k0 + 32);
    }

    __syncthreads();
    *(short8*)&Asm[ar*40 + ah*16]     = sa0;
    *(short8*)&Asm[ar*40 + ah*16 + 8] = sa1;
    #pragma unroll
    for (int j = 0; j < 4; j++)
      *(short4v*)&Bsm[(mg*4 + j)*40 + kg*4] = bpk[j];
    __syncthreads();

    short8 afr[4], bfr[4];
    #pragma unroll
    for (int i = 0; i < 4; i++) afr[i] = *(const short8*)&Asm[(wc*64 + i*16 + r16)*40 + q*8];
    #pragma unroll
    for (int j = 0; j < 4; j++) bfr[j] = *(const short8*)&Bsm[(wsd*64 + j*16 + r16)*40 + q*8];
    #pragma unroll
    for (int i = 0; i < 4; i++)
      #pragma unroll
      for (int j = 0; j < 4; j++)
        acc[i][j] = __builtin_amdgcn_mfma_f32_16x16x32_bf16(afr[i], bfr[j], acc[i][j], 0, 0, 0);
  }

  // ---- epilogue ----
  #pragma unroll
  for (int j = 0; j < 4; j++){
    int sg = s0 + wsd*64 + j*16 + r16;
    int b2 = sg / FL; int r2 = sg - b2*FL;
    int f2 = (g.Fdim > 1) ? (r2 / g.Lw) : 0;
    int l2 = g.lq0 + (r2 - f2*g.Lw);
    if (b2 >= 2 || l2 < 0 || l2 >= 2048) continue;
    float invn_p = 0.f, aud_p = 0.f;
    if (EMODE==2 || EMODE==3) invn_p = g.invn[(b2*g.Fdim + f2)*2048 + l2];
    if (EMODE==3) aud_p = g.audio[(b2*128 + f2)*2048 + l2];
    #pragma unroll
    for (int i = 0; i < 4; i++){
      #pragma unroll
      for (int rg = 0; rg < 4; rg++){
        int n = n0 + wc*64 + i*16 + q*4 + rg;
        if (n >= g.N) continue;
        float v = acc[i][j][rg];
        long oidx = ((long)(b2*g.Nsto + n)*g.Fdim + f2)*g.CLw + (l2 - g.Cl0);
        if (EMODE == 0){
          g.Cout[oidx] = v;
        } else if (EMODE == 1){
          g.CoutH[oidx] = (unsigned short)f2bf(v);
        } else if (EMODE == 2){
          float xn = g.auxX[((long)(b2*g.N + n)*g.Fdim + f2)*2048 + l2] * invn_p;
          g.CoutH[oidx] = (unsigned short)f2bf((xn*0.7f + v*0.3f)*MPS);
        } else if (EMODE == 3){
          float xn = (aud_p*g.pw[n] + g.pb[n])*invn_p;
          g.CoutH[oidx] = (unsigned short)f2bf((xn*0.7f + v*0.3f)*MPS);
        } else if (EMODE == 4){
          if (n < g.Nsto) g.CoutH[(long)(b2*g.Nsto + n)*g.CLw + l2] = (unsigned short)f2bf(silu_g(v));
          else            g.Cout2H[(long)(b2*g.Nsto + (n - g.Nsto))*g.CLw + l2] = (unsigned short)f2bf(v);
        }
      }
    }
  }
}

// ---------------- seq out GEMM: 64x64 tile, Fdim=1, full-range M/N, prefetched ----------------
// EMODE 5: mp_add -> f32 Cout ; EMODE 6: mp_add + silu -> f32 Cout
template<int EMODE>
__global__ __launch_bounds__(256,4) void seqout_kernel(const unsigned short* __restrict__ A,
                                                       const unsigned short* __restrict__ Bh,
                                                       const float* __restrict__ invn,
                                                       const float* __restrict__ auxX,
                                                       float* __restrict__ Cout, int K){
  __shared__ __align__(16) unsigned short Asm[64*40];
  __shared__ __align__(16) unsigned short Bsm[64*40];
  const int t = threadIdx.x;
  const int lane = t & 63;
  const int wave = t >> 6;
  const int wc = wave >> 1, wsd = wave & 1;
  const int q = lane >> 4, r16 = lane & 15;
  const int s0 = blockIdx.x * 64;
  const int n0 = blockIdx.y * 64;

  // A staging: row ar (0..63), chunk ah (0..3) of 8 shorts
  const int ar = t >> 2, ah = t & 3;
  const unsigned short* Aptr = A + (long)(n0 + ar)*K + ah*8;
  // B staging (t<128): kg = t&7 (4k), mg = t>>3 (0..15) (4m)
  const int kg = t & 7, mg = t >> 3;
  const bool bstage = (mg < 16);
  const int mb = s0 + (mg & 15)*4;
  const int bcol = mb >> 11, lb = mb & 2047;
  const unsigned short* bbase = Bh + ((long)bcol*K)*2048 + lb;

  float4v acc[2][2];
  #pragma unroll
  for (int i = 0; i < 2; i++)
    #pragma unroll
    for (int j = 0; j < 2; j++) acc[i][j] = (float4v){0.f,0.f,0.f,0.f};

  short8 pa = {0,0,0,0,0,0,0,0};
  short4v praw[4];
  #pragma unroll
  for (int i = 0; i < 4; i++) praw[i] = (short4v){0,0,0,0};

  auto ldA = [&](int kb){ pa = *(const short8*)(Aptr + kb); };
  auto ldB = [&](int kb){
    if (bstage){
      #pragma unroll
      for (int i = 0; i < 4; i++)
        praw[i] = *(const short4v*)(bbase + (long)(kb + kg*4 + i)*2048);
    }
  };
  ldA(0); ldB(0);

  for (int k0 = 0; k0 < K; k0 += 32){
    short8 sa = pa;
    short4v bpk[4];
    #pragma unroll
    for (int j = 0; j < 4; j++){
      short4v p;
      #pragma unroll
      for (int i = 0; i < 4; i++) p[i] = praw[i][j];
      bpk[j] = p;
    }
    if (k0 + 32 < K){ ldA(k0 + 32); ldB(k0 + 32); }

    __syncthreads();
    *(short8*)&Asm[ar*40 + ah*8] = sa;
    if (bstage){
      #pragma unroll
      for (int j = 0; j < 4; j++)
        *(short4v*)&Bsm[((mg & 15)*4 + j)*40 + kg*4] = bpk[j];
    }
    __syncthreads();

    short8 afr[2], bfr[2];
    #pragma unroll
    for (int i = 0; i < 2; i++) afr[i] = *(const short8*)&Asm[(wc*32 + i*16 + r16)*40 + q*8];
    #pragma unroll
    for (int j = 0; j < 2; j++) bfr[j] = *(const short8*)&Bsm[(wsd*32 + j*16 + r16)*40 + q*8];
    #pragma unroll
    for (int i = 0; i < 2; i++)
      #pragma unroll
      for (int j = 0; j < 2; j++)
        acc[i][j] = __builtin_amdgcn_mfma_f32_16x16x32_bf16(afr[i], bfr[j], acc[i][j], 0, 0, 0);
  }

  #pragma unroll
  for (int j = 0; j < 2; j++){
    int sg = s0 + wsd*32 + j*16 + r16;
    int b2 = sg >> 11, l2 = sg & 2047;
    float invn_p = invn[b2*2048 + l2];
    #pragma unroll
    for (int i = 0; i < 2; i++){
      #pragma unroll
      for (int rg = 0; rg < 4; rg++){
        int n = n0 + wc*32 + i*16 + q*4 + rg;
        float v = acc[i][j][rg];
        float xn = auxX[((long)b2*512 + n)*2048 + l2] * invn_p;
        float r = (xn*0.7f + v*0.3f)*MPS;
        if (EMODE == 6) r = silu_g(r);
        Cout[((long)b2*512 + n)*2048 + l2] = r;
      }
    }
  }
}

// ---------------- depthwise 5x3 conv (+ silu), bf16 in/out ----------------
struct DwArgs { const unsigned short* R1; const unsigned short* wd; unsigned short* R2; int C, F, Lc, l0; };
__global__ __launch_bounds__(256) void dw2d_kernel(DwArgs a){
  int idx = blockIdx.x*256 + threadIdx.x;
  int Lq = a.Lc >> 2;
  int total = 2*a.C*a.F*Lq;
  if (idx >= total) return;
  int lq = idx % Lq; int r = idx / Lq;
  int f = r % a.F; r /= a.F;
  int c = r % a.C; int b = r / a.C;
  int labs = a.l0 + lq*4;
  const unsigned short* w = a.wd + c*15;
  int Lw = a.Lc + 8;
  const unsigned short* rowbase = a.R1 + (long)((b*a.C + c)*a.F)*Lw + (labs - (a.l0 - 4));
  float acc0=0,acc1=0,acc2=0,acc3=0;
  #pragma unroll
  for (int df = -2; df <= 2; df++){
    int ff = f + df; if (ff < 0 || ff >= a.F) continue;
    const unsigned short* p = rowbase + (long)ff*Lw;
    float w0 = bf2f(w[(df+2)*3+0]), w1 = bf2f(w[(df+2)*3+1]), w2 = bf2f(w[(df+2)*3+2]);
    short4v u = *(const short4v*)p;
    float xm = (labs > 0) ? bf2f(p[-1]) : 0.f;
    float x0 = bf2f((unsigned short)u[0]), x1 = bf2f((unsigned short)u[1]);
    float x2 = bf2f((unsigned short)u[2]), x3 = bf2f((unsigned short)u[3]);
    float x4 = (labs + 4 < 2048) ? bf2f(p[4]) : 0.f;
    acc0 += w0*xm + w1*x0 + w2*x1;
    acc1 += w0*x0 + w1*x1 + w2*x2;
    acc2 += w0*x1 + w1*x2 + w2*x3;
    acc3 += w0*x2 + w1*x3 + w2*x4;
  }
  short4v o = { f2bf(silu_g(acc0)), f2bf(silu_g(acc1)), f2bf(silu_g(acc2)), f2bf(silu_g(acc3)) };
  *(short4v*)&a.R2[((long)((b*a.C + c)*a.F + f))*a.Lc + (labs - a.l0)] = o;
}

// ---------------- seq depthwise 3-tap (+ silu), bf16 in/out ----------------
__global__ __launch_bounds__(256) void dwseq_kernel(const unsigned short* __restrict__ HS, const unsigned short* __restrict__ w,
                                                    unsigned short* __restrict__ H2){
  int idx = blockIdx.x*256 + threadIdx.x;
  if (idx >= 2*1024*512) return;
  int e = idx*4;
  int tt = e & 2047; int bc = e >> 11; int c = bc & 1023;
  const unsigned short* base = HS + (long)bc*2048 + tt;
  float w0 = bf2f(w[c*3+0]), w1 = bf2f(w[c*3+1]), w2 = bf2f(w[c*3+2]);
  short4v u = *(const short4v*)base;
  float xm = (tt > 0) ? bf2f(base[-1]) : 0.f;
  float x0 = bf2f((unsigned short)u[0]), x1 = bf2f((unsigned short)u[1]);
  float x2 = bf2f((unsigned short)u[2]), x3 = bf2f((unsigned short)u[3]);
  float x4 = (tt < 2044) ? bf2f(base[4]) : 0.f;
  short4v o = { f2bf(silu_g(w0*xm + w1*x0 + w2*x1)),
                f2bf(silu_g(w0*x0 + w1*x1 + w2*x2)),
                f2bf(silu_g(w0*x1 + w1*x2 + w2*x3)),
                f2bf(silu_g(w0*x2 + w1*x3 + w2*x4)) };
  *(short4v*)&H2[(long)bc*2048 + tt] = o;
}

// ---------------- minGRU scan + gate (bf16 z/c) ----------------
__global__ __launch_bounds__(256) void scan_kernel(const unsigned short* __restrict__ ZC, const unsigned short* __restrict__ G,
                                                   unsigned short* __restrict__ SC){
  int bc = blockIdx.x;            // 0..2047 = b*1024+c
  int b = bc >> 10, c = bc & 1023;
  const unsigned short* zrow = ZC + ((long)(b*2048 + c))*2048;
  const unsigned short* crow = ZC + ((long)(b*2048 + 1024 + c))*2048;
  const unsigned short* grow = G + (long)bc*2048;
  unsigned short* orow = SC + (long)bc*2048;
  int tid = threadIdx.x;
  int t0 = tid*8;
  short8 zv = *(const short8*)&zrow[t0];
  short8 cv = *(const short8*)&crow[t0];
  float av[8], bv[8];
  float A = 1.f, Bv = 0.f;
  #pragma unroll
  for (int j = 0; j < 8; j++){
    float z = bf2f((unsigned short)zv[j]); float cval = bf2f((unsigned short)cv[j]);
    float zs = 1.f/(1.f + __expf(-z));
    float a = 1.f - zs; float bb = zs*cval;
    av[j] = a; bv[j] = bb;
    Bv = a*Bv + bb;
    A = a*A;
  }
  __shared__ float sA[256], sB[256];
  sA[tid] = A; sB[tid] = Bv;
  __syncthreads();
  for (int off = 1; off < 256; off <<= 1){
    float pA = 1.f, pB = 0.f;
    if (tid >= off){ pA = sA[tid-off]; pB = sB[tid-off]; }
    __syncthreads();
    float nA = A*pA; float nB = A*pB + Bv;
    A = nA; Bv = nB;
    sA[tid] = A; sB[tid] = Bv;
    __syncthreads();
  }
  float h = (tid > 0) ? sB[tid-1] : 0.f;
  short8 gv = *(const short8*)&grow[t0];
  short8 ov;
  #pragma unroll
  for (int j = 0; j < 8; j++){
    h = av[j]*h + bv[j];
    ov[j] = f2bf(h * silu_g(bf2f((unsigned short)gv[j])));
  }
  *(short8*)&orow[t0] = ov;
}

extern "C" void kernel_launch(void* const* d_in, const int* in_sizes, int n_in,
                              void* d_out, int out_size, void* d_ws, size_t ws_size,
                              hipStream_t stream) {
  const float* audio = (const float*)d_in[0];
  const float* pw = (const float*)d_in[1];
  const float* pb = (const float*)d_in[2];
  const float* cw1[3] = {(const float*)d_in[3], (const float*)d_in[7], (const float*)d_in[11]};
  const float* cwd[3] = {(const float*)d_in[4], (const float*)d_in[8], (const float*)d_in[12]};
  const float* cw2[3] = {(const float*)d_in[5], (const float*)d_in[9], (const float*)d_in[13]};
  const float* cdn[3] = {(const float*)d_in[6], (const float*)d_in[10], (const float*)d_in[14]};
  const float* hgw  = (const float*)d_in[15];
  const float* dww  = (const float*)d_in[16];
  const float* gruw = (const float*)d_in[17];
  const float* outw = (const float*)d_in[18];
  float* out = (float*)d_out;

  // ---- workspace layout (bytes) ----
  char* P = (char*)d_ws;
  float*          INVW = (float*)P;                     P += 131072;     // 25664 used + S at [32000]
  unsigned short* WBF  = (unsigned short*)P;            P += 30443776;   // 15,221,888 bf16
  float*          INVN = (float*)P;                     P += 2097152;
  char*           XBZC = P;                             P += 33554432;   // XB (conv b1/b2) then ZC bf16 (seq)
  float*          IN1  = (float*)P;                     P += 67108864;   // also seq bf16 scratch later
  float*          IN2  = (float*)P;                     P += 33554432;
  float*          SEQ  = (float*)P;                     P += 8388608;
  char*           ARENA = P;
  long arenaBytes = (long)ws_size - (long)(P - (char*)d_ws);
  float* S = INVW + 32000;

  // weight table (order: cw1/cwd/cw2/cdn x3, hg, dww, gru, out)
  const float* wsrc[16] = {cw1[0],cwd[0],cw2[0],cdn[0], cw1[1],cwd[1],cw2[1],cdn[1],
                           cw1[2],cwd[2],cw2[2],cdn[2], hgw, dww, gruw, outw};
  int Os[16] = {128,128,64,128, 256,256,128,256, 512,512,256,512, 8192,4096,8192,2048};
  int Ks[16] = {64,15,128,64, 128,15,256,128, 256,15,512,256, 512,3,1024,1024};
  int wbfOff[16], ivOff[16];
  {
    int wo = 0, io = 0;
    for (int i = 0; i < 16; i++){ wbfOff[i] = wo; ivOff[i] = io; wo += Os[i]*Ks[i]; io += Os[i]; }
  }
  // rownorm
  {
    NormArgs na;
    int rows = 0;
    for (int i = 0; i < 16; i++){ na.e[i].w = wsrc[i]; na.e[i].O = Os[i]; na.e[i].K = Ks[i]; na.e[i].off = ivOff[i]; rows += Os[i]; }
    rownorm_kernel<<<rows, 64, 0, stream>>>(na, INVW);
  }
  // wcast
  {
    WcArgs wa; int base = 0;
    for (int i = 0; i < 16; i++){
      wa.e[i].src = wsrc[i]; wa.e[i].dstOff = wbfOff[i]; wa.e[i].K = Ks[i];
      wa.e[i].invwOff = ivOff[i]; wa.e[i].base = base; base += Os[i]*Ks[i];
    }
    wa.total = base;
    wcast_kernel<<<(base+255)/256, 256, 0, stream>>>(wa, INVW, WBF);
  }
  projstats_kernel<<<1, 64, 0, stream>>>(pw, pb, S);

  // ---- conv blocks ----
  int Cin_[3]  = {64,128,256};
  int Cmid_[3] = {128,256,512};
  int F_[3]    = {128,32,8};
  int s_[3]    = {4,4,8};
  const float* Xin[3] = {nullptr, IN1, IN2};
  float* Xout[3] = {IN1, IN2, SEQ};
  int iW1[3]={0,4,8}, iWd[3]={1,5,9}, iW2[3]={2,6,10}, iDn[3]={3,7,11};

  for (int b = 0; b < 3; b++){
    int Cin = Cin_[b], Cmid = Cmid_[b], F = F_[b], s = s_[b];
    int nc = 16;
    for (int c = 1; c <= 16; c <<= 1){
      long Lc = 2048/c;
      long bytes = 2L*(2L*Cmid*F*(Lc+8) + 2L*Cmid*F*Lc + 2L*Cin*F*Lc);
      if (bytes <= arenaBytes){ nc = c; break; }
    }
    int Lc = 2048/nc;
    unsigned short* R1 = (unsigned short*)ARENA;
    unsigned short* R2 = R1 + 2L*Cmid*F*(Lc+8);
    unsigned short* Hb = R2 + 2L*Cmid*F*Lc;
    unsigned short* XB = (unsigned short*)XBZC;

    if (b == 0){
      invn_audio_kernel<<<(2*128*2048/4+255)/256, 256, 0, stream>>>(audio, S, INVN);
    } else {
      int positions = 2*F*2048;
      invn_reduce_kernel<8><<<positions/32, 256, 0, stream>>>(Xin[b], INVN, Cin, F);
      long total4 = (long)2*Cin*F*2048/4;
      applynorm_kernel<true><<<(int)((total4+255)/256), 256, 0, stream>>>(Xin[b], INVN, XB, Cin, F, total4);
    }

    for (int ci = 0; ci < nc; ci++){
      int l0 = ci*Lc;
      // conv1: Cin -> Cmid on window [l0-4, l0+Lc+4) -> R1 bf16
      GemmArgs ga{};
      ga.A = WBF + wbfOff[iW1[b]];
      ga.Bh = XB; ga.invn = INVN; ga.audio = audio; ga.pw = pw; ga.pb = pb;
      ga.CoutH = R1; ga.N = Cmid; ga.K = Cin; ga.Fdim = F; ga.Lw = Lc+8; ga.lq0 = l0-4;
      ga.BLw = 2048; ga.Bl0 = 0; ga.CLw = Lc+8; ga.Cl0 = l0-4; ga.Nsto = Cmid; ga.Fsrc = F; ga.pool_s = 1;
      int M1 = 2*F*(Lc+8);
      dim3 g1((M1+127)/128, (Cmid+127)/128);
      if (b == 0) mgemm_kernel<2,1><<<g1,256,0,stream>>>(ga);
      else        mgemm_kernel<0,1><<<g1,256,0,stream>>>(ga);
      // depthwise 5x3 + silu -> R2 bf16
      DwArgs da{R1, WBF + wbfOff[iWd[b]], R2, Cmid, F, Lc, l0};
      int tdw = 2*Cmid*F*(Lc/4);
      dw2d_kernel<<<(tdw+255)/256, 256, 0, stream>>>(da);
      // conv2 + mp_add -> Hb bf16
      GemmArgs gb{};
      gb.A = WBF + wbfOff[iW2[b]];
      gb.Bh = R2; gb.invn = INVN; gb.audio = audio; gb.pw = pw; gb.pb = pb; gb.auxX = Xin[b];
      gb.CoutH = Hb; gb.N = Cin; gb.K = Cmid; gb.Fdim = F; gb.Lw = Lc; gb.lq0 = l0;
      gb.BLw = Lc; gb.Bl0 = l0; gb.CLw = Lc; gb.Cl0 = l0; gb.Nsto = Cin; gb.Fsrc = F; gb.pool_s = 1;
      int M2 = 2*F*Lc;
      dim3 g2((M2+127)/128, (Cin+127)/128);
      if (b == 0) mgemm_kernel<0,3><<<g2,256,0,stream>>>(gb);
      else        mgemm_kernel<0,2><<<g2,256,0,stream>>>(gb);
      // avgpool_freq + dn conv -> Xout fp32 (full-L layout)
      GemmArgs gc{};
      gc.A = WBF + wbfOff[iDn[b]];
      gc.Bh = Hb; gc.Cout = Xout[b];
      gc.N = Cmid; gc.K = Cin; gc.Fdim = F/s; gc.Lw = Lc; gc.lq0 = l0;
      gc.BLw = Lc; gc.Bl0 = l0; gc.CLw = 2048; gc.Cl0 = 0; gc.Nsto = Cmid; gc.Fsrc = F; gc.pool_s = s;
      int M3 = 2*(F/s)*Lc;
      dim3 g3((M3+127)/128, (Cmid+127)/128);
      mgemm_kernel<1,0><<<g3,256,0,stream>>>(gc);
    }
  }

  // ---- seq blocks (bf16 scratch lives in IN1, ZC bf16 in XBZC) ----
  unsigned short* XS = (unsigned short*)IN1;
  unsigned short* HS = XS + 2097152;
  unsigned short* G  = HS + 4194304;
  unsigned short* H2 = G  + 4194304;
  unsigned short* SC = H2 + 4194304;
  unsigned short* ZCh = (unsigned short*)XBZC;

  for (int i = 0; i < 4; i++){
    invn_reduce_kernel<16><<<4096/16, 256, 0, stream>>>(SEQ, INVN, 512, 1);
    applynorm_kernel<false><<<(2*512*2048/4)/256, 256, 0, stream>>>(SEQ, INVN, XS, 512, 1, (long)2*512*2048/4);
    // hg conv (both halves): n<1024 -> silu -> HS, else raw -> G
    GemmArgs gh{};
    gh.A = WBF + wbfOff[12] + (long)i*2048*512;
    gh.Bh = XS;
    gh.CoutH = HS; gh.Cout2H = G;
    gh.N = 2048; gh.K = 512; gh.Fdim = 1; gh.Lw = 2048; gh.lq0 = 0;
    gh.BLw = 2048; gh.Bl0 = 0; gh.CLw = 2048; gh.Cl0 = 0; gh.Nsto = 1024; gh.Fsrc = 1; gh.pool_s = 1;
    mgemm_kernel<0,4><<<dim3(32,16),256,0,stream>>>(gh);
    // depthwise 3-tap + silu
    dwseq_kernel<<<(2*1024*512)/256, 256, 0, stream>>>(HS, WBF + wbfOff[13] + i*1024*3, H2);
    // gru conv 1024 -> 2048 (z|c) -> ZCh bf16
    GemmArgs gz{};
    gz.A = WBF + wbfOff[14] + (long)i*2048*1024;
    gz.Bh = H2; gz.CoutH = ZCh; gz.N = 2048; gz.K = 1024; gz.Fdim = 1; gz.Lw = 2048; gz.lq0 = 0;
    gz.BLw = 2048; gz.Bl0 = 0; gz.CLw = 2048; gz.Cl0 = 0; gz.Nsto = 2048; gz.Fsrc = 1; gz.pool_s = 1;
    mgemm_kernel<0,1><<<dim3(32,16),256,0,stream>>>(gz);
    // scan + gate -> SC bf16
    scan_kernel<<<2048,256,0,stream>>>(ZCh, G, SC);
    // out conv + mp_add -> SEQ (i<3) or mp_add+silu -> d_out (i==3), 64x64 tile (512 blocks)
    const unsigned short* oA = WBF + wbfOff[15] + (long)i*512*1024;
    if (i < 3) seqout_kernel<5><<<dim3(64,8),256,0,stream>>>(oA, SC, INVN, SEQ, SEQ, 1024);
    else       seqout_kernel<6><<<dim3(64,8),256,0,stream>>>(oA, SC, INVN, SEQ, out, 1024);
  }

  (void)in_sizes; (void)n_in; (void)out_size;
}

// Round 6
// 1570.467 us; speedup vs baseline: 5.1503x; 1.1075x over previous
//
#include <hip/hip_runtime.h>
#include <math.h>

#define GAIN 1.6778523489932886f     // 1/0.596
#define MPS  1.3130643285972254f     // 1/sqrt(0.7^2+0.3^2)

typedef __attribute__((ext_vector_type(8))) short short8;
typedef __attribute__((ext_vector_type(4))) short short4v;
typedef __attribute__((ext_vector_type(4))) float float4v;

__device__ __forceinline__ float silu_g(float x){
  float s = 1.0f/(1.0f + __expf(-x));
  return x*s*GAIN;
}
__device__ __forceinline__ short f2bf(float f){
  unsigned u = __builtin_bit_cast(unsigned, f);
  u += 0x7fffu + ((u >> 16) & 1u);
  return (short)(u >> 16);
}
__device__ __forceinline__ float bf2f(unsigned short h){
  return __builtin_bit_cast(float, ((unsigned)h) << 16);
}

// ---------------- weight row-norm reciprocals ----------------
struct NormEnt { const float* w; int O, K, off; };
struct NormArgs { NormEnt e[16]; };

__global__ __launch_bounds__(64) void rownorm_kernel(NormArgs na, float* invw){
  int row = blockIdx.x;
  int base = 0; int i;
  for (i = 0; i < 16; i++){
    if (row < base + na.e[i].O) break;
    base += na.e[i].O;
  }
  if (i >= 16) return;
  int r = row - base; int K = na.e[i].K;
  const float* w = na.e[i].w + (long)r*K;
  float s = 0.f;
  for (int k = threadIdx.x; k < K; k += 64){ float v = w[k]; s += v*v; }
  for (int off = 32; off; off >>= 1) s += __shfl_down(s, off);
  if (threadIdx.x == 0) invw[na.e[i].off + r] = rsqrtf(s + 1e-8f);
}

// ---------------- weight cast: bf16(w * invw[row]) ----------------
struct WcEnt { const float* src; int dstOff, K, invwOff, base; };
struct WcArgs { WcEnt e[16]; int total; };

__global__ __launch_bounds__(256) void wcast_kernel(WcArgs a, const float* __restrict__ invw,
                                                    unsigned short* __restrict__ wbf){
  int gid = blockIdx.x*256 + threadIdx.x;
  if (gid >= a.total) return;
  int i = 0;
  #pragma unroll
  for (int t = 1; t < 16; t++) if (gid >= a.e[t].base) i = t;
  int e = gid - a.e[i].base;
  int row = e / a.e[i].K;
  wbf[a.e[i].dstOff + e] = (unsigned short)f2bf(a.e[i].src[e] * invw[a.e[i].invwOff + row]);
}

// ---------------- audio projection stats (one wave) ----------------
__global__ __launch_bounds__(64) void projstats_kernel(const float* __restrict__ pw, const float* __restrict__ pb,
                                                       float* __restrict__ S){
  int t = threadIdx.x;
  float p = pw[t], q = pb[t];
  float s1 = p*p, s2 = p*q, s3 = q*q;
  for (int off = 32; off; off >>= 1){
    s1 += __shfl_down(s1, off); s2 += __shfl_down(s2, off); s3 += __shfl_down(s3, off);
  }
  if (t == 0){ S[0] = s1; S[1] = s2; S[2] = s3; }
}

// ---------------- b0 inverse pixel-norm (closed form, element-wise 4-wide) ----------------
__global__ __launch_bounds__(256) void invn_audio_kernel(const float* __restrict__ audio, const float* __restrict__ S,
                                                         float* __restrict__ invn){
  long i = blockIdx.x*256 + threadIdx.x;
  if (i >= (2L*128*2048)/4) return;
  long e = i*4;
  float S1 = S[0], S2 = S[1], S3 = S[2];
  float4v a = *(const float4v*)&audio[e];
  float4v o;
  #pragma unroll
  for (int j = 0; j < 4; j++) o[j] = rsqrtf((a[j]*a[j]*S1 + 2.f*a[j]*S2 + S3)/64.f + 1e-4f);
  *(float4v*)&invn[e] = o;
}

// ---------------- pixel-norm reduce (fp32 or bf16 source) ----------------
template<int G, bool BF>
__global__ __launch_bounds__(256) void invn_reduce_kernel(const void* __restrict__ Xv, float* __restrict__ invn,
                                                          int C, int F){
  constexpr int L = 256/G;
  int t = threadIdx.x; int cs = t / L; int li = t % L;
  long pos = (long)blockIdx.x*L + li;
  int bf = (int)(pos >> 11); int l = (int)(pos & 2047);
  int b = bf / F; int f = bf - b*F;
  long base = ((long)b*C*F + f)*2048 + l;
  long stride = (long)F*2048;
  float s = 0.f;
  if (BF){
    const unsigned short* X = (const unsigned short*)Xv;
    for (int c = cs; c < C; c += G){ float v = bf2f(X[base + (long)c*stride]); s += v*v; }
  } else {
    const float* X = (const float*)Xv;
    for (int c = cs; c < C; c += G){ float v = X[base + (long)c*stride]; s += v*v; }
  }
  __shared__ float red[256];
  red[t] = s; __syncthreads();
  #pragma unroll
  for (int off = G/2; off > 0; off >>= 1){
    if (cs < off) red[t] += red[t + off*L];
    __syncthreads();
  }
  if (cs == 0) invn[pos] = rsqrtf(red[li]/(float)C + 1e-4f);
}

// ---------------- pixel-norm apply (fp32 or bf16 source) ----------------
template<bool SILU, bool BF>
__global__ __launch_bounds__(256) void applynorm_kernel(const void* __restrict__ Xv, const float* __restrict__ invn,
                                                        unsigned short* __restrict__ XB, int C, int F, long total4){
  long i = blockIdx.x*256 + threadIdx.x;
  if (i >= total4) return;
  long e = i*4;
  int l = (int)(e & 2047); long r = e >> 11;      // r = (b*C + c)*F + f
  int f = (int)(r % F); long bc = r / F; int b = (int)(bc / C);
  float4v x;
  if (BF){
    short4v u = *(const short4v*)((const unsigned short*)Xv + e);
    x = (float4v){ bf2f((unsigned short)u[0]), bf2f((unsigned short)u[1]),
                   bf2f((unsigned short)u[2]), bf2f((unsigned short)u[3]) };
  } else {
    x = *(const float4v*)((const float*)Xv + e);
  }
  float4v iv = *(const float4v*)&invn[((long)b*F + f)*2048 + l];
  short4v o;
  #pragma unroll
  for (int j = 0; j < 4; j++){
    float v = x[j]*iv[j];
    o[j] = f2bf(SILU ? silu_g(v) : v);
  }
  *(short4v*)&XB[e] = o;
}

// ---------------- freq-pool: P[b,k,f2,l] = mean_p Hb[b,k,f2*s+p,l], bf16 ----------------
__global__ __launch_bounds__(256) void poolf_kernel(const unsigned short* __restrict__ Hb,
                                                    unsigned short* __restrict__ P,
                                                    int F2, int s, int Lc, long total4){
  long i = blockIdx.x*256 + threadIdx.x;
  if (i >= total4) return;
  long e = i*4;
  int li = (int)(e % Lc); long r0 = e / Lc;
  int f2 = (int)(r0 % F2); long r = r0 / F2;        // r = b*Kc + k
  const unsigned short* src = Hb + ((long)r*F2*s + (long)f2*s)*Lc + li;
  float a0=0,a1=0,a2=0,a3=0;
  for (int p = 0; p < s; p++){
    short4v u = *(const short4v*)(src + (long)p*Lc);
    a0 += bf2f((unsigned short)u[0]); a1 += bf2f((unsigned short)u[1]);
    a2 += bf2f((unsigned short)u[2]); a3 += bf2f((unsigned short)u[3]);
  }
  float inv = 1.f/(float)s;
  short4v o = { f2bf(a0*inv), f2bf(a1*inv), f2bf(a2*inv), f2bf(a3*inv) };
  *(short4v*)&P[((long)r*F2 + f2)*Lc + li] = o;
}

// ---------------- bf16 MFMA fused GEMM (128x128 tile, register-prefetched K-loop) ----------------
// BMODE: 0 = bf16 copy (windowed/zero-padded), 2 = audio closed-form (b0 conv1)
// EMODE: 1 bf16 store, 2 mp_add auxXH(bf16)->bf16, 3 mp_add audio-proj->bf16,
//        4 split n<Nsto: silu->CoutH else raw->Cout2H
struct GemmArgs {
  const unsigned short* A;       // pre-normalized bf16 weights, row-major K
  const unsigned short* Bh;      // bf16 B source
  const float* invn; const float* audio;
  const float* pw; const float* pb;
  const unsigned short* auxXH;
  unsigned short* CoutH; unsigned short* Cout2H;
  int N, K, Fdim, Lw, lq0, BLw, Bl0, CLw, Cl0, Nsto, Fsrc;
};

template<int BMODE, int EMODE>
__global__ __launch_bounds__(256,2) void mgemm_kernel(GemmArgs g){
  __shared__ __align__(16) unsigned short Asm[128*40];
  __shared__ __align__(16) unsigned short Bsm[128*40];
  const int t = threadIdx.x;
  const int lane = t & 63;
  const int wave = t >> 6;
  const int wc = wave >> 1, wsd = wave & 1;
  const int q = lane >> 4, r16 = lane & 15;
  const int s0 = blockIdx.x * 128;
  const int n0 = blockIdx.y * 128;
  const int FL = g.Fdim * g.Lw;

  // A staging mapping
  const int ar = t >> 1, ah = t & 1;
  const int an = n0 + ar;
  const bool aval = an < g.N;
  const unsigned short* Aptr = g.A + (long)an*g.K + ah*16;

  // B staging mapping: (k-group kg 0..7 of 4k, m-group mg 0..31 of 4m)
  const int kg = t & 7, mg = t >> 3;
  const int mb = s0 + mg*4;
  int bcol = mb / FL; int rr = mb - bcol*FL;
  int fcol = (g.Fdim > 1) ? (rr / g.Lw) : 0;
  int labs = g.lq0 + (rr - fcol*g.Lw);
  const bool cv = (bcol < 2);
  bool lv[4];
  #pragma unroll
  for (int j = 0; j < 4; j++) lv[j] = cv && (labs + j >= 0) && (labs + j < 2048);
  const bool vec4 = cv && (labs >= 0) && (labs + 3 < 2048);
  const unsigned short* bbase = g.Bh;
  if (cv) bbase = g.Bh + ((long)(bcol*g.K)*g.Fsrc + fcol)*g.BLw + (labs - g.Bl0);
  const long kstep = (long)g.Fsrc * g.BLw;

  float invn4[4] = {0,0,0,0}, aud4[4] = {0,0,0,0};
  if (BMODE == 2){
    #pragma unroll
    for (int j = 0; j < 4; j++) if (lv[j]){
      invn4[j] = g.invn[(bcol*g.Fdim + fcol)*2048 + labs + j];
      aud4[j]  = g.audio[(bcol*128 + fcol)*2048 + labs + j];
    }
  }

  float4v acc[4][4];
  #pragma unroll
  for (int i = 0; i < 4; i++)
    #pragma unroll
    for (int j = 0; j < 4; j++) acc[i][j] = (float4v){0.f,0.f,0.f,0.f};

  // prefetch registers
  short8 pa0 = {0,0,0,0,0,0,0,0}, pa1 = {0,0,0,0,0,0,0,0};
  short4v praw[4];
  #pragma unroll
  for (int i = 0; i < 4; i++) praw[i] = (short4v){0,0,0,0};

  auto ldA = [&](int kb){
    if (aval){
      pa0 = *(const short8*)(Aptr + kb);
      pa1 = *(const short8*)(Aptr + kb + 8);
    }
  };
  auto ldB = [&](int kb){
    #pragma unroll
    for (int i = 0; i < 4; i++){
      const int k = kb + kg*4 + i;
      const unsigned short* bp = bbase + (long)k*kstep;
      if (vec4) praw[i] = *(const short4v*)bp;
      else {
        short4v u = {0,0,0,0};
        #pragma unroll
        for (int j = 0; j < 4; j++) if (lv[j]) u[j] = (short)bp[j];
        praw[i] = u;
      }
    }
  };

  ldA(0);
  if (BMODE == 0) ldB(0);

  for (int k0 = 0; k0 < g.K; k0 += 32){
    short8 sa0 = pa0, sa1 = pa1;
    short4v bpk[4];
    if (BMODE == 0){
      #pragma unroll
      for (int j = 0; j < 4; j++){
        short4v p;
        #pragma unroll
        for (int i = 0; i < 4; i++) p[i] = praw[i][j];
        bpk[j] = p;
      }
    } else { // BMODE == 2
      float tv[4][4];
      #pragma unroll
      for (int i = 0; i < 4; i++){
        const int k = k0 + kg*4 + i;
        const float pwk = g.pw[k], pbk = g.pb[k];
        #pragma unroll
        for (int j = 0; j < 4; j++) tv[i][j] = lv[j] ? silu_g((aud4[j]*pwk + pbk)*invn4[j]) : 0.f;
      }
      #pragma unroll
      for (int j = 0; j < 4; j++){
        short4v p;
        #pragma unroll
        for (int i = 0; i < 4; i++) p[i] = f2bf(tv[i][j]);
        bpk[j] = p;
      }
    }
    if (k0 + 32 < g.K){
      ldA(k0 + 32);
      if (BMODE == 0) ldB(k0 + 32);
    }

    __syncthreads();
    *(short8*)&Asm[ar*40 + ah*16]     = sa0;
    *(short8*)&Asm[ar*40 + ah*16 + 8] = sa1;
    #pragma unroll
    for (int j = 0; j < 4; j++)
      *(short4v*)&Bsm[(mg*4 + j)*40 + kg*4] = bpk[j];
    __syncthreads();

    short8 afr[4], bfr[4];
    #pragma unroll
    for (int i = 0; i < 4; i++) afr[i] = *(const short8*)&Asm[(wc*64 + i*16 + r16)*40 + q*8];
    #pragma unroll
    for (int j = 0; j < 4; j++) bfr[j] = *(const short8*)&Bsm[(wsd*64 + j*16 + r16)*40 + q*8];
    #pragma unroll
    for (int i = 0; i < 4; i++)
      #pragma unroll
      for (int j = 0; j < 4; j++)
        acc[i][j] = __builtin_amdgcn_mfma_f32_16x16x32_bf16(afr[i], bfr[j], acc[i][j], 0, 0, 0);
  }

  // ---- epilogue ----
  #pragma unroll
  for (int j = 0; j < 4; j++){
    int sg = s0 + wsd*64 + j*16 + r16;
    int b2 = sg / FL; int r2 = sg - b2*FL;
    int f2 = (g.Fdim > 1) ? (r2 / g.Lw) : 0;
    int l2 = g.lq0 + (r2 - f2*g.Lw);
    if (b2 >= 2 || l2 < 0 || l2 >= 2048) continue;
    float invn_p = 0.f, aud_p = 0.f;
    if (EMODE==2 || EMODE==3) invn_p = g.invn[(b2*g.Fdim + f2)*2048 + l2];
    if (EMODE==3) aud_p = g.audio[(b2*128 + f2)*2048 + l2];
    #pragma unroll
    for (int i = 0; i < 4; i++){
      #pragma unroll
      for (int rg = 0; rg < 4; rg++){
        int n = n0 + wc*64 + i*16 + q*4 + rg;
        if (n >= g.N) continue;
        float v = acc[i][j][rg];
        long oidx = ((long)(b2*g.Nsto + n)*g.Fdim + f2)*g.CLw + (l2 - g.Cl0);
        if (EMODE == 1){
          g.CoutH[oidx] = (unsigned short)f2bf(v);
        } else if (EMODE == 2){
          float xn = bf2f(g.auxXH[((long)(b2*g.N + n)*g.Fdim + f2)*2048 + l2]) * invn_p;
          g.CoutH[oidx] = (unsigned short)f2bf((xn*0.7f + v*0.3f)*MPS);
        } else if (EMODE == 3){
          float xn = (aud_p*g.pw[n] + g.pb[n])*invn_p;
          g.CoutH[oidx] = (unsigned short)f2bf((xn*0.7f + v*0.3f)*MPS);
        } else if (EMODE == 4){
          if (n < g.Nsto) g.CoutH[(long)(b2*g.Nsto + n)*g.CLw + l2] = (unsigned short)f2bf(silu_g(v));
          else            g.Cout2H[(long)(b2*g.Nsto + (n - g.Nsto))*g.CLw + l2] = (unsigned short)f2bf(v);
        }
      }
    }
  }
}

// ---------------- downsample conv GEMM: 64x64 tile on pooled P, prefetched ----------------
// EMODE 0: f32 store full-L ; EMODE 1: bf16 store full-L
struct DnArgs {
  const unsigned short* A; const unsigned short* P;
  float* Cout; unsigned short* CoutH;
  int N, K, F2, Lc, l0;
};

template<int EMODE>
__global__ __launch_bounds__(256,4) void mgemm64_kernel(DnArgs g){
  __shared__ __align__(16) unsigned short Asm[64*40];
  __shared__ __align__(16) unsigned short Bsm[64*40];
  const int t = threadIdx.x;
  const int lane = t & 63;
  const int wave = t >> 6;
  const int wc = wave >> 1, wsd = wave & 1;
  const int q = lane >> 4, r16 = lane & 15;
  const int s0 = blockIdx.x * 64;
  const int n0 = blockIdx.y * 64;
  const int FL = g.F2 * g.Lc;

  // A staging: row ar (0..63), chunk ah (0..3) of 8 shorts
  const int ar = t >> 2, ah = t & 3;
  const unsigned short* Aptr = g.A + (long)(n0 + ar)*g.K + ah*8;
  // B staging (mg<16): kg = t&7 (4k), mg (4m)
  const int kg = t & 7, mg = t >> 3;
  const bool bstage = (mg < 16);
  const int mb = s0 + (mg & 15)*4;
  const int bcol = mb / FL; const int rr = mb - bcol*FL;
  const int fcol = rr / g.Lc; const int li = rr - fcol*g.Lc;
  const unsigned short* bbase = g.P + ((long)(bcol*g.K)*g.F2 + fcol)*g.Lc + li;
  const long kstep = (long)g.F2 * g.Lc;

  float4v acc[2][2];
  #pragma unroll
  for (int i = 0; i < 2; i++)
    #pragma unroll
    for (int j = 0; j < 2; j++) acc[i][j] = (float4v){0.f,0.f,0.f,0.f};

  short8 pa = {0,0,0,0,0,0,0,0};
  short4v praw[4];
  #pragma unroll
  for (int i = 0; i < 4; i++) praw[i] = (short4v){0,0,0,0};

  auto ldA = [&](int kb){ pa = *(const short8*)(Aptr + kb); };
  auto ldB = [&](int kb){
    if (bstage){
      #pragma unroll
      for (int i = 0; i < 4; i++)
        praw[i] = *(const short4v*)(bbase + (long)(kb + kg*4 + i)*kstep);
    }
  };
  ldA(0); ldB(0);

  for (int k0 = 0; k0 < g.K; k0 += 32){
    short8 sa = pa;
    short4v bpk[4];
    #pragma unroll
    for (int j = 0; j < 4; j++){
      short4v p;
      #pragma unroll
      for (int i = 0; i < 4; i++) p[i] = praw[i][j];
      bpk[j] = p;
    }
    if (k0 + 32 < g.K){ ldA(k0 + 32); ldB(k0 + 32); }

    __syncthreads();
    *(short8*)&Asm[ar*40 + ah*8] = sa;
    if (bstage){
      #pragma unroll
      for (int j = 0; j < 4; j++)
        *(short4v*)&Bsm[((mg & 15)*4 + j)*40 + kg*4] = bpk[j];
    }
    __syncthreads();

    short8 afr[2], bfr[2];
    #pragma unroll
    for (int i = 0; i < 2; i++) afr[i] = *(const short8*)&Asm[(wc*32 + i*16 + r16)*40 + q*8];
    #pragma unroll
    for (int j = 0; j < 2; j++) bfr[j] = *(const short8*)&Bsm[(wsd*32 + j*16 + r16)*40 + q*8];
    #pragma unroll
    for (int i = 0; i < 2; i++)
      #pragma unroll
      for (int j = 0; j < 2; j++)
        acc[i][j] = __builtin_amdgcn_mfma_f32_16x16x32_bf16(afr[i], bfr[j], acc[i][j], 0, 0, 0);
  }

  #pragma unroll
  for (int j = 0; j < 2; j++){
    int sg = s0 + wsd*32 + j*16 + r16;
    int b2 = sg / FL; int r2 = sg - b2*FL;
    int f2 = r2 / g.Lc; int l2 = g.l0 + (r2 - f2*g.Lc);
    #pragma unroll
    for (int i = 0; i < 2; i++){
      #pragma unroll
      for (int rg = 0; rg < 4; rg++){
        int n = n0 + wc*32 + i*16 + q*4 + rg;
        float v = acc[i][j][rg];
        long oidx = ((long)(b2*g.N + n)*g.F2 + f2)*2048 + l2;
        if (EMODE == 0) g.Cout[oidx] = v;
        else            g.CoutH[oidx] = (unsigned short)f2bf(v);
      }
    }
  }
}

// ---------------- seq out GEMM: 64x64 tile, Fdim=1, prefetched ----------------
// EMODE 5: mp_add -> f32 Cout ; EMODE 6: mp_add + silu -> f32 Cout
template<int EMODE>
__global__ __launch_bounds__(256,4) void seqout_kernel(const unsigned short* __restrict__ A,
                                                       const unsigned short* __restrict__ Bh,
                                                       const float* __restrict__ invn,
                                                       const float* __restrict__ auxX,
                                                       float* __restrict__ Cout, int K){
  __shared__ __align__(16) unsigned short Asm[64*40];
  __shared__ __align__(16) unsigned short Bsm[64*40];
  const int t = threadIdx.x;
  const int lane = t & 63;
  const int wave = t >> 6;
  const int wc = wave >> 1, wsd = wave & 1;
  const int q = lane >> 4, r16 = lane & 15;
  const int s0 = blockIdx.x * 64;
  const int n0 = blockIdx.y * 64;

  const int ar = t >> 2, ah = t & 3;
  const unsigned short* Aptr = A + (long)(n0 + ar)*K + ah*8;
  const int kg = t & 7, mg = t >> 3;
  const bool bstage = (mg < 16);
  const int mb = s0 + (mg & 15)*4;
  const int bcol = mb >> 11, lb = mb & 2047;
  const unsigned short* bbase = Bh + ((long)bcol*K)*2048 + lb;

  float4v acc[2][2];
  #pragma unroll
  for (int i = 0; i < 2; i++)
    #pragma unroll
    for (int j = 0; j < 2; j++) acc[i][j] = (float4v){0.f,0.f,0.f,0.f};

  short8 pa = {0,0,0,0,0,0,0,0};
  short4v praw[4];
  #pragma unroll
  for (int i = 0; i < 4; i++) praw[i] = (short4v){0,0,0,0};

  auto ldA = [&](int kb){ pa = *(const short8*)(Aptr + kb); };
  auto ldB = [&](int kb){
    if (bstage){
      #pragma unroll
      for (int i = 0; i < 4; i++)
        praw[i] = *(const short4v*)(bbase + (long)(kb + kg*4 + i)*2048);
    }
  };
  ldA(0); ldB(0);

  for (int k0 = 0; k0 < K; k0 += 32){
    short8 sa = pa;
    short4v bpk[4];
    #pragma unroll
    for (int j = 0; j < 4; j++){
      short4v p;
      #pragma unroll
      for (int i = 0; i < 4; i++) p[i] = praw[i][j];
      bpk[j] = p;
    }
    if (k0 + 32 < K){ ldA(k0 + 32); ldB(k0 + 32); }

    __syncthreads();
    *(short8*)&Asm[ar*40 + ah*8] = sa;
    if (bstage){
      #pragma unroll
      for (int j = 0; j < 4; j++)
        *(short4v*)&Bsm[((mg & 15)*4 + j)*40 + kg*4] = bpk[j];
    }
    __syncthreads();

    short8 afr[2], bfr[2];
    #pragma unroll
    for (int i = 0; i < 2; i++) afr[i] = *(const short8*)&Asm[(wc*32 + i*16 + r16)*40 + q*8];
    #pragma unroll
    for (int j = 0; j < 2; j++) bfr[j] = *(const short8*)&Bsm[(wsd*32 + j*16 + r16)*40 + q*8];
    #pragma unroll
    for (int i = 0; i < 2; i++)
      #pragma unroll
      for (int j = 0; j < 2; j++)
        acc[i][j] = __builtin_amdgcn_mfma_f32_16x16x32_bf16(afr[i], bfr[j], acc[i][j], 0, 0, 0);
  }

  #pragma unroll
  for (int j = 0; j < 2; j++){
    int sg = s0 + wsd*32 + j*16 + r16;
    int b2 = sg >> 11, l2 = sg & 2047;
    float invn_p = invn[b2*2048 + l2];
    #pragma unroll
    for (int i = 0; i < 2; i++){
      #pragma unroll
      for (int rg = 0; rg < 4; rg++){
        int n = n0 + wc*32 + i*16 + q*4 + rg;
        float v = acc[i][j][rg];
        float xn = auxX[((long)b2*512 + n)*2048 + l2] * invn_p;
        float r = (xn*0.7f + v*0.3f)*MPS;
        if (EMODE == 6) r = silu_g(r);
        Cout[((long)b2*512 + n)*2048 + l2] = r;
      }
    }
  }
}

// ---------------- depthwise 5x3 conv (+ silu), bf16 in/out ----------------
struct DwArgs { const unsigned short* R1; const unsigned short* wd; unsigned short* R2; int C, F, Lc, l0; };
__global__ __launch_bounds__(256) void dw2d_kernel(DwArgs a){
  int idx = blockIdx.x*256 + threadIdx.x;
  int Lq = a.Lc >> 2;
  int total = 2*a.C*a.F*Lq;
  if (idx >= total) return;
  int lq = idx % Lq; int r = idx / Lq;
  int f = r % a.F; r /= a.F;
  int c = r % a.C; int b = r / a.C;
  int labs = a.l0 + lq*4;
  const unsigned short* w = a.wd + c*15;
  int Lw = a.Lc + 8;
  const unsigned short* rowbase = a.R1 + (long)((b*a.C + c)*a.F)*Lw + (labs - (a.l0 - 4));
  float acc0=0,acc1=0,acc2=0,acc3=0;
  #pragma unroll
  for (int df = -2; df <= 2; df++){
    int ff = f + df; if (ff < 0 || ff >= a.F) continue;
    const unsigned short* p = rowbase + (long)ff*Lw;
    float w0 = bf2f(w[(df+2)*3+0]), w1 = bf2f(w[(df+2)*3+1]), w2 = bf2f(w[(df+2)*3+2]);
    short4v u = *(const short4v*)p;
    float xm = (labs > 0) ? bf2f(p[-1]) : 0.f;
    float x0 = bf2f((unsigned short)u[0]), x1 = bf2f((unsigned short)u[1]);
    float x2 = bf2f((unsigned short)u[2]), x3 = bf2f((unsigned short)u[3]);
    float x4 = (labs + 4 < 2048) ? bf2f(p[4]) : 0.f;
    acc0 += w0*xm + w1*x0 + w2*x1;
    acc1 += w0*x0 + w1*x1 + w2*x2;
    acc2 += w0*x1 + w1*x2 + w2*x3;
    acc3 += w0*x2 + w1*x3 + w2*x4;
  }
  short4v o = { f2bf(silu_g(acc0)), f2bf(silu_g(acc1)), f2bf(silu_g(acc2)), f2bf(silu_g(acc3)) };
  *(short4v*)&a.R2[((long)((b*a.C + c)*a.F + f))*a.Lc + (labs - a.l0)] = o;
}

// ---------------- seq depthwise 3-tap (+ silu), bf16 in/out ----------------
__global__ __launch_bounds__(256) void dwseq_kernel(const unsigned short* __restrict__ HS, const unsigned short* __restrict__ w,
                                                    unsigned short* __restrict__ H2){
  int idx = blockIdx.x*256 + threadIdx.x;
  if (idx >= 2*1024*512) return;
  int e = idx*4;
  int tt = e & 2047; int bc = e >> 11; int c = bc & 1023;
  const unsigned short* base = HS + (long)bc*2048 + tt;
  float w0 = bf2f(w[c*3+0]), w1 = bf2f(w[c*3+1]), w2 = bf2f(w[c*3+2]);
  short4v u = *(const short4v*)base;
  float xm = (tt > 0) ? bf2f(base[-1]) : 0.f;
  float x0 = bf2f((unsigned short)u[0]), x1 = bf2f((unsigned short)u[1]);
  float x2 = bf2f((unsigned short)u[2]), x3 = bf2f((unsigned short)u[3]);
  float x4 = (tt < 2044) ? bf2f(base[4]) : 0.f;
  short4v o = { f2bf(silu_g(w0*xm + w1*x0 + w2*x1)),
                f2bf(silu_g(w0*x0 + w1*x1 + w2*x2)),
                f2bf(silu_g(w0*x1 + w1*x2 + w2*x3)),
                f2bf(silu_g(w0*x2 + w1*x3 + w2*x4)) };
  *(short4v*)&H2[(long)bc*2048 + tt] = o;
}

// ---------------- minGRU scan + gate (bf16 z/c) ----------------
__global__ __launch_bounds__(256) void scan_kernel(const unsigned short* __restrict__ ZC, const unsigned short* __restrict__ G,
                                                   unsigned short* __restrict__ SC){
  int bc = blockIdx.x;            // 0..2047 = b*1024+c
  int b = bc >> 10, c = bc & 1023;
  const unsigned short* zrow = ZC + ((long)(b*2048 + c))*2048;
  const unsigned short* crow = ZC + ((long)(b*2048 + 1024 + c))*2048;
  const unsigned short* grow = G + (long)bc*2048;
  unsigned short* orow = SC + (long)bc*2048;
  int tid = threadIdx.x;
  int t0 = tid*8;
  short8 zv = *(const short8*)&zrow[t0];
  short8 cv = *(const short8*)&crow[t0];
  float av[8], bv[8];
  float A = 1.f, Bv = 0.f;
  #pragma unroll
  for (int j = 0; j < 8; j++){
    float z = bf2f((unsigned short)zv[j]); float cval = bf2f((unsigned short)cv[j]);
    float zs = 1.f/(1.f + __expf(-z));
    float a = 1.f - zs; float bb = zs*cval;
    av[j] = a; bv[j] = bb;
    Bv = a*Bv + bb;
    A = a*A;
  }
  __shared__ float sA[256], sB[256];
  sA[tid] = A; sB[tid] = Bv;
  __syncthreads();
  for (int off = 1; off < 256; off <<= 1){
    float pA = 1.f, pB = 0.f;
    if (tid >= off){ pA = sA[tid-off]; pB = sB[tid-off]; }
    __syncthreads();
    float nA = A*pA; float nB = A*pB + Bv;
    A = nA; Bv = nB;
    sA[tid] = A; sB[tid] = Bv;
    __syncthreads();
  }
  float h = (tid > 0) ? sB[tid-1] : 0.f;
  short8 gv = *(const short8*)&grow[t0];
  short8 ov;
  #pragma unroll
  for (int j = 0; j < 8; j++){
    h = av[j]*h + bv[j];
    ov[j] = f2bf(h * silu_g(bf2f((unsigned short)gv[j])));
  }
  *(short8*)&orow[t0] = ov;
}

extern "C" void kernel_launch(void* const* d_in, const int* in_sizes, int n_in,
                              void* d_out, int out_size, void* d_ws, size_t ws_size,
                              hipStream_t stream) {
  const float* audio = (const float*)d_in[0];
  const float* pw = (const float*)d_in[1];
  const float* pb = (const float*)d_in[2];
  const float* cw1[3] = {(const float*)d_in[3], (const float*)d_in[7], (const float*)d_in[11]};
  const float* cwd[3] = {(const float*)d_in[4], (const float*)d_in[8], (const float*)d_in[12]};
  const float* cw2[3] = {(const float*)d_in[5], (const float*)d_in[9], (const float*)d_in[13]};
  const float* cdn[3] = {(const float*)d_in[6], (const float*)d_in[10], (const float*)d_in[14]};
  const float* hgw  = (const float*)d_in[15];
  const float* dww  = (const float*)d_in[16];
  const float* gruw = (const float*)d_in[17];
  const float* outw = (const float*)d_in[18];
  float* out = (float*)d_out;

  // ---- workspace layout (bytes) ----
  char* P0 = (char*)d_ws;
  float*          INVW = (float*)P0;                    P0 += 131072;     // 25664 used + S at [32000]
  unsigned short* WBF  = (unsigned short*)P0;           P0 += 30443776;   // 15,221,888 bf16
  float*          INVN = (float*)P0;                    P0 += 2097152;
  char*           XBZC = P0;                            P0 += 33554432;   // XB (conv b1/b2) / ZC bf16 (seq)
  unsigned short* IN1h = (unsigned short*)P0;           P0 += 33554432;   // b0 out bf16; seq scratch later
  unsigned short* IN2h = (unsigned short*)P0;           P0 += 16777216;   // b1 out bf16
  float*          SEQ  = (float*)P0;                    P0 += 8388608;    // b2 out fp32
  char*           ARENA = P0;
  long arenaBytes = (long)ws_size - (long)(P0 - (char*)d_ws);
  float* S = INVW + 32000;

  // weight table (order: cw1/cwd/cw2/cdn x3, hg, dww, gru, out)
  const float* wsrc[16] = {cw1[0],cwd[0],cw2[0],cdn[0], cw1[1],cwd[1],cw2[1],cdn[1],
                           cw1[2],cwd[2],cw2[2],cdn[2], hgw, dww, gruw, outw};
  int Os[16] = {128,128,64,128, 256,256,128,256, 512,512,256,512, 8192,4096,8192,2048};
  int Ks[16] = {64,15,128,64, 128,15,256,128, 256,15,512,256, 512,3,1024,1024};
  int wbfOff[16], ivOff[16];
  {
    int wo = 0, io = 0;
    for (int i = 0; i < 16; i++){ wbfOff[i] = wo; ivOff[i] = io; wo += Os[i]*Ks[i]; io += Os[i]; }
  }
  {
    NormArgs na;
    int rows = 0;
    for (int i = 0; i < 16; i++){ na.e[i].w = wsrc[i]; na.e[i].O = Os[i]; na.e[i].K = Ks[i]; na.e[i].off = ivOff[i]; rows += Os[i]; }
    rownorm_kernel<<<rows, 64, 0, stream>>>(na, INVW);
  }
  {
    WcArgs wa; int base = 0;
    for (int i = 0; i < 16; i++){
      wa.e[i].src = wsrc[i]; wa.e[i].dstOff = wbfOff[i]; wa.e[i].K = Ks[i];
      wa.e[i].invwOff = ivOff[i]; wa.e[i].base = base; base += Os[i]*Ks[i];
    }
    wa.total = base;
    wcast_kernel<<<(base+255)/256, 256, 0, stream>>>(wa, INVW, WBF);
  }
  projstats_kernel<<<1, 64, 0, stream>>>(pw, pb, S);

  // ---- conv blocks ----
  int Cin_[3]  = {64,128,256};
  int Cmid_[3] = {128,256,512};
  int F_[3]    = {128,32,8};
  int s_[3]    = {4,4,8};
  const unsigned short* XinH[3] = {nullptr, IN1h, IN2h};
  unsigned short* XoutH[3] = {IN1h, IN2h, nullptr};
  int iW1[3]={0,4,8}, iWd[3]={1,5,9}, iW2[3]={2,6,10}, iDn[3]={3,7,11};

  for (int b = 0; b < 3; b++){
    int Cin = Cin_[b], Cmid = Cmid_[b], F = F_[b], s = s_[b];
    int F2 = F/s;
    // pick chunk count: smallest nc with chunk buffers (R1,R2,Hb,P) fitting arena
    int nc = 16;
    for (int c = 1; c <= 16; c <<= 1){
      long Lc = 2048/c;
      long bytes = 2L*(2L*Cmid*F*(Lc+8) + 2L*Cmid*F*Lc + 2L*Cin*F*Lc + 2L*Cin*F2*Lc);
      if (bytes <= arenaBytes){ nc = c; break; }
    }
    int Lc = 2048/nc;
    unsigned short* R1 = (unsigned short*)ARENA;
    unsigned short* R2 = R1 + 2L*Cmid*F*(Lc+8);
    unsigned short* Hb = R2 + 2L*Cmid*F*Lc;
    unsigned short* Pb = Hb + 2L*Cin*F*Lc;
    unsigned short* XB = (unsigned short*)XBZC;

    if (b == 0){
      invn_audio_kernel<<<(2*128*2048/4+255)/256, 256, 0, stream>>>(audio, S, INVN);
    } else {
      int positions = 2*F*2048;
      invn_reduce_kernel<8,true><<<positions/32, 256, 0, stream>>>(XinH[b], INVN, Cin, F);
      long total4 = (long)2*Cin*F*2048/4;
      applynorm_kernel<true,true><<<(int)((total4+255)/256), 256, 0, stream>>>(XinH[b], INVN, XB, Cin, F, total4);
    }

    for (int ci = 0; ci < nc; ci++){
      int l0 = ci*Lc;
      // conv1: Cin -> Cmid on window [l0-4, l0+Lc+4) -> R1 bf16
      GemmArgs ga{};
      ga.A = WBF + wbfOff[iW1[b]];
      ga.Bh = XB; ga.invn = INVN; ga.audio = audio; ga.pw = pw; ga.pb = pb;
      ga.CoutH = R1; ga.N = Cmid; ga.K = Cin; ga.Fdim = F; ga.Lw = Lc+8; ga.lq0 = l0-4;
      ga.BLw = 2048; ga.Bl0 = 0; ga.CLw = Lc+8; ga.Cl0 = l0-4; ga.Nsto = Cmid; ga.Fsrc = F;
      int M1 = 2*F*(Lc+8);
      dim3 g1((M1+127)/128, (Cmid+127)/128);
      if (b == 0) mgemm_kernel<2,1><<<g1,256,0,stream>>>(ga);
      else        mgemm_kernel<0,1><<<g1,256,0,stream>>>(ga);
      // depthwise 5x3 + silu -> R2 bf16
      DwArgs da{R1, WBF + wbfOff[iWd[b]], R2, Cmid, F, Lc, l0};
      int tdw = 2*Cmid*F*(Lc/4);
      dw2d_kernel<<<(tdw+255)/256, 256, 0, stream>>>(da);
      // conv2 + mp_add -> Hb bf16
      GemmArgs gb{};
      gb.A = WBF + wbfOff[iW2[b]];
      gb.Bh = R2; gb.invn = INVN; gb.audio = audio; gb.pw = pw; gb.pb = pb; gb.auxXH = XinH[b];
      gb.CoutH = Hb; gb.N = Cin; gb.K = Cmid; gb.Fdim = F; gb.Lw = Lc; gb.lq0 = l0;
      gb.BLw = Lc; gb.Bl0 = l0; gb.CLw = Lc; gb.Cl0 = l0; gb.Nsto = Cin; gb.Fsrc = F;
      int M2 = 2*F*Lc;
      dim3 g2((M2+127)/128, (Cin+127)/128);
      if (b == 0) mgemm_kernel<0,3><<<g2,256,0,stream>>>(gb);
      else        mgemm_kernel<0,2><<<g2,256,0,stream>>>(gb);
      // freq-pool Hb -> Pb (bf16)
      long tp4 = (2L*Cin*F2*Lc)/4;
      poolf_kernel<<<(int)((tp4+255)/256), 256, 0, stream>>>(Hb, Pb, F2, s, Lc, tp4);
      // dn conv on pooled P -> Xout (bf16 full-L for b0/b1; fp32 SEQ for b2)
      DnArgs dn{};
      dn.A = WBF + wbfOff[iDn[b]]; dn.P = Pb;
      dn.Cout = SEQ; dn.CoutH = XoutH[b];
      dn.N = Cmid; dn.K = Cin; dn.F2 = F2; dn.Lc = Lc; dn.l0 = l0;
      dim3 gdn((2*F2*Lc)/64, Cmid/64);
      if (b == 2) mgemm64_kernel<0><<<gdn,256,0,stream>>>(dn);
      else        mgemm64_kernel<1><<<gdn,256,0,stream>>>(dn);
    }
  }

  // ---- seq blocks (bf16 scratch spans IN1h+IN2h; ZC bf16 in XBZC) ----
  unsigned short* XS = IN1h;
  unsigned short* HS = XS + 2097152;
  unsigned short* G  = HS + 4194304;
  unsigned short* H2 = G  + 4194304;
  unsigned short* SC = H2 + 4194304;
  unsigned short* ZCh = (unsigned short*)XBZC;

  for (int i = 0; i < 4; i++){
    invn_reduce_kernel<16,false><<<4096/16, 256, 0, stream>>>(SEQ, INVN, 512, 1);
    applynorm_kernel<false,false><<<(2*512*2048/4)/256, 256, 0, stream>>>(SEQ, INVN, XS, 512, 1, (long)2*512*2048/4);
    // hg conv (both halves): n<1024 -> silu -> HS, else raw -> G
    GemmArgs gh{};
    gh.A = WBF + wbfOff[12] + (long)i*2048*512;
    gh.Bh = XS;
    gh.CoutH = HS; gh.Cout2H = G;
    gh.N = 2048; gh.K = 512; gh.Fdim = 1; gh.Lw = 2048; gh.lq0 = 0;
    gh.BLw = 2048; gh.Bl0 = 0; gh.CLw = 2048; gh.Cl0 = 0; gh.Nsto = 1024; gh.Fsrc = 1;
    mgemm_kernel<0,4><<<dim3(32,16),256,0,stream>>>(gh);
    // depthwise 3-tap + silu
    dwseq_kernel<<<(2*1024*512)/256, 256, 0, stream>>>(HS, WBF + wbfOff[13] + i*1024*3, H2);
    // gru conv 1024 -> 2048 (z|c) -> ZCh bf16
    GemmArgs gz{};
    gz.A = WBF + wbfOff[14] + (long)i*2048*1024;
    gz.Bh = H2; gz.CoutH = ZCh; gz.N = 2048; gz.K = 1024; gz.Fdim = 1; gz.Lw = 2048; gz.lq0 = 0;
    gz.BLw = 2048; gz.Bl0 = 0; gz.CLw = 2048; gz.Cl0 = 0; gz.Nsto = 2048; gz.Fsrc = 1;
    mgemm_kernel<0,1><<<dim3(32,16),256,0,stream>>>(gz);
    // scan + gate -> SC bf16
    scan_kernel<<<2048,256,0,stream>>>(ZCh, G, SC);
    // out conv + mp_add -> SEQ (i<3) or mp_add+silu -> d_out (i==3)
    const unsigned short* oA = WBF + wbfOff[15] + (long)i*512*1024;
    if (i < 3) seqout_kernel<5><<<dim3(64,8),256,0,stream>>>(oA, SC, INVN, SEQ, SEQ, 1024);
    else       seqout_kernel<6><<<dim3(64,8),256,0,stream>>>(oA, SC, INVN, SEQ, out, 1024);
  }

  (void)in_sizes; (void)n_in; (void)out_size;
}

// Round 7
// 1396.211 us; speedup vs baseline: 5.7931x; 1.1248x over previous
//
#include <hip/hip_runtime.h>
#include <math.h>

#define GAIN 1.6778523489932886f     // 1/0.596
#define MPS  1.3130643285972254f     // 1/sqrt(0.7^2+0.3^2)

typedef __attribute__((ext_vector_type(8))) short short8;
typedef __attribute__((ext_vector_type(4))) short short4v;
typedef __attribute__((ext_vector_type(4))) float float4v;

__device__ __forceinline__ float silu_g(float x){
  float s = 1.0f/(1.0f + __expf(-x));
  return x*s*GAIN;
}
__device__ __forceinline__ short f2bf(float f){
  unsigned u = __builtin_bit_cast(unsigned, f);
  u += 0x7fffu + ((u >> 16) & 1u);
  return (short)(u >> 16);
}
__device__ __forceinline__ float bf2f(unsigned short h){
  return __builtin_bit_cast(float, ((unsigned)h) << 16);
}

// ---------------- weight row-norm reciprocals ----------------
struct NormEnt { const float* w; int O, K, off; };
struct NormArgs { NormEnt e[16]; };

__global__ __launch_bounds__(64) void rownorm_kernel(NormArgs na, float* invw){
  int row = blockIdx.x;
  int base = 0; int i;
  for (i = 0; i < 16; i++){
    if (row < base + na.e[i].O) break;
    base += na.e[i].O;
  }
  if (i >= 16) return;
  int r = row - base; int K = na.e[i].K;
  const float* w = na.e[i].w + (long)r*K;
  float s = 0.f;
  for (int k = threadIdx.x; k < K; k += 64){ float v = w[k]; s += v*v; }
  for (int off = 32; off; off >>= 1) s += __shfl_down(s, off);
  if (threadIdx.x == 0) invw[na.e[i].off + r] = rsqrtf(s + 1e-8f);
}

// ---------------- weight cast: bf16(w * invw[row]) ----------------
struct WcEnt { const float* src; int dstOff, K, invwOff, base; };
struct WcArgs { WcEnt e[16]; int total; };

__global__ __launch_bounds__(256) void wcast_kernel(WcArgs a, const float* __restrict__ invw,
                                                    unsigned short* __restrict__ wbf){
  int gid = blockIdx.x*256 + threadIdx.x;
  if (gid >= a.total) return;
  int i = 0;
  #pragma unroll
  for (int t = 1; t < 16; t++) if (gid >= a.e[t].base) i = t;
  int e = gid - a.e[i].base;
  int row = e / a.e[i].K;
  wbf[a.e[i].dstOff + e] = (unsigned short)f2bf(a.e[i].src[e] * invw[a.e[i].invwOff + row]);
}

// ---------------- audio projection stats (one wave) ----------------
__global__ __launch_bounds__(64) void projstats_kernel(const float* __restrict__ pw, const float* __restrict__ pb,
                                                       float* __restrict__ S){
  int t = threadIdx.x;
  float p = pw[t], q = pb[t];
  float s1 = p*p, s2 = p*q, s3 = q*q;
  for (int off = 32; off; off >>= 1){
    s1 += __shfl_down(s1, off); s2 += __shfl_down(s2, off); s3 += __shfl_down(s3, off);
  }
  if (t == 0){ S[0] = s1; S[1] = s2; S[2] = s3; }
}

// ---------------- b0 inverse pixel-norm (closed form, element-wise 4-wide) ----------------
__global__ __launch_bounds__(256) void invn_audio_kernel(const float* __restrict__ audio, const float* __restrict__ S,
                                                         float* __restrict__ invn){
  long i = blockIdx.x*256 + threadIdx.x;
  if (i >= (2L*128*2048)/4) return;
  long e = i*4;
  float S1 = S[0], S2 = S[1], S3 = S[2];
  float4v a = *(const float4v*)&audio[e];
  float4v o;
  #pragma unroll
  for (int j = 0; j < 4; j++) o[j] = rsqrtf((a[j]*a[j]*S1 + 2.f*a[j]*S2 + S3)/64.f + 1e-4f);
  *(float4v*)&invn[e] = o;
}

// ---------------- pixel-norm reduce (fp32 or bf16 source) ----------------
template<int G, bool BF>
__global__ __launch_bounds__(256) void invn_reduce_kernel(const void* __restrict__ Xv, float* __restrict__ invn,
                                                          int C, int F){
  constexpr int L = 256/G;
  int t = threadIdx.x; int cs = t / L; int li = t % L;
  long pos = (long)blockIdx.x*L + li;
  int bf = (int)(pos >> 11); int l = (int)(pos & 2047);
  int b = bf / F; int f = bf - b*F;
  long base = ((long)b*C*F + f)*2048 + l;
  long stride = (long)F*2048;
  float s = 0.f;
  if (BF){
    const unsigned short* X = (const unsigned short*)Xv;
    for (int c = cs; c < C; c += G){ float v = bf2f(X[base + (long)c*stride]); s += v*v; }
  } else {
    const float* X = (const float*)Xv;
    for (int c = cs; c < C; c += G){ float v = X[base + (long)c*stride]; s += v*v; }
  }
  __shared__ float red[256];
  red[t] = s; __syncthreads();
  #pragma unroll
  for (int off = G/2; off > 0; off >>= 1){
    if (cs < off) red[t] += red[t + off*L];
    __syncthreads();
  }
  if (cs == 0) invn[pos] = rsqrtf(red[li]/(float)C + 1e-4f);
}

// ---------------- pixel-norm apply (fp32 or bf16 source) ----------------
template<bool SILU, bool BF>
__global__ __launch_bounds__(256) void applynorm_kernel(const void* __restrict__ Xv, const float* __restrict__ invn,
                                                        unsigned short* __restrict__ XB, int C, int F, long total4){
  long i = blockIdx.x*256 + threadIdx.x;
  if (i >= total4) return;
  long e = i*4;
  int l = (int)(e & 2047); long r = e >> 11;      // r = (b*C + c)*F + f
  int f = (int)(r % F); long bc = r / F; int b = (int)(bc / C);
  float4v x;
  if (BF){
    short4v u = *(const short4v*)((const unsigned short*)Xv + e);
    x = (float4v){ bf2f((unsigned short)u[0]), bf2f((unsigned short)u[1]),
                   bf2f((unsigned short)u[2]), bf2f((unsigned short)u[3]) };
  } else {
    x = *(const float4v*)((const float*)Xv + e);
  }
  float4v iv = *(const float4v*)&invn[((long)b*F + f)*2048 + l];
  short4v o;
  #pragma unroll
  for (int j = 0; j < 4; j++){
    float v = x[j]*iv[j];
    o[j] = f2bf(SILU ? silu_g(v) : v);
  }
  *(short4v*)&XB[e] = o;
}

// ---------------- freq-pool: P[b,k,f2,l] = mean_p Hb[b,k,f2*s+p,l], bf16 ----------------
__global__ __launch_bounds__(256) void poolf_kernel(const unsigned short* __restrict__ Hb,
                                                    unsigned short* __restrict__ P,
                                                    int F2, int s, int Lc, long total4){
  long i = blockIdx.x*256 + threadIdx.x;
  if (i >= total4) return;
  long e = i*4;
  int li = (int)(e % Lc); long r0 = e / Lc;
  int f2 = (int)(r0 % F2); long r = r0 / F2;        // r = b*Kc + k
  const unsigned short* src = Hb + ((long)r*F2*s + (long)f2*s)*Lc + li;
  float a0=0,a1=0,a2=0,a3=0;
  for (int p = 0; p < s; p++){
    short4v u = *(const short4v*)(src + (long)p*Lc);
    a0 += bf2f((unsigned short)u[0]); a1 += bf2f((unsigned short)u[1]);
    a2 += bf2f((unsigned short)u[2]); a3 += bf2f((unsigned short)u[3]);
  }
  float inv = 1.f/(float)s;
  short4v o = { f2bf(a0*inv), f2bf(a1*inv), f2bf(a2*inv), f2bf(a3*inv) };
  *(short4v*)&P[((long)r*F2 + f2)*Lc + li] = o;
}

// ---------------- bf16 MFMA fused GEMM (128x128 tile, register-prefetched K-loop) ----------------
// BMODE: 0 = bf16 copy (windowed/zero-padded), 2 = audio closed-form (b0 conv1)
// EMODE: 1 bf16 store, 2 mp_add auxXH(bf16)->bf16, 3 mp_add audio-proj->bf16,
//        4 split n<Nsto: silu->CoutH else raw->Cout2H
struct GemmArgs {
  const unsigned short* A;       // pre-normalized bf16 weights, row-major K
  const unsigned short* Bh;      // bf16 B source
  const float* invn; const float* audio;
  const float* pw; const float* pb;
  const unsigned short* auxXH;
  unsigned short* CoutH; unsigned short* Cout2H;
  int N, K, Fdim, Lw, lq0, BLw, Bl0, CLw, Cl0, Nsto, Fsrc;
};

template<int BMODE, int EMODE>
__global__ __launch_bounds__(256,2) void mgemm_kernel(GemmArgs g){
  __shared__ __align__(16) unsigned short Asm[128*40];
  __shared__ __align__(16) unsigned short Bsm[128*40];
  const int t = threadIdx.x;
  const int lane = t & 63;
  const int wave = t >> 6;
  const int wc = wave >> 1, wsd = wave & 1;
  const int q = lane >> 4, r16 = lane & 15;
  const int s0 = blockIdx.x * 128;
  const int n0 = blockIdx.y * 128;
  const int FL = g.Fdim * g.Lw;

  // A staging mapping
  const int ar = t >> 1, ah = t & 1;
  const int an = n0 + ar;
  const bool aval = an < g.N;
  const unsigned short* Aptr = g.A + (long)an*g.K + ah*16;

  // B staging mapping: (k-group kg 0..7 of 4k, m-group mg 0..31 of 4m)
  const int kg = t & 7, mg = t >> 3;
  const int mb = s0 + mg*4;
  int bcol = mb / FL; int rr = mb - bcol*FL;
  int fcol = (g.Fdim > 1) ? (rr / g.Lw) : 0;
  int labs = g.lq0 + (rr - fcol*g.Lw);
  const bool cv = (bcol < 2);
  bool lv[4];
  #pragma unroll
  for (int j = 0; j < 4; j++) lv[j] = cv && (labs + j >= 0) && (labs + j < 2048);
  const bool vec4 = cv && (labs >= 0) && (labs + 3 < 2048);
  const unsigned short* bbase = g.Bh;
  if (cv) bbase = g.Bh + ((long)(bcol*g.K)*g.Fsrc + fcol)*g.BLw + (labs - g.Bl0);
  const long kstep = (long)g.Fsrc * g.BLw;

  float invn4[4] = {0,0,0,0}, aud4[4] = {0,0,0,0};
  if (BMODE == 2){
    #pragma unroll
    for (int j = 0; j < 4; j++) if (lv[j]){
      invn4[j] = g.invn[(bcol*g.Fdim + fcol)*2048 + labs + j];
      aud4[j]  = g.audio[(bcol*128 + fcol)*2048 + labs + j];
    }
  }

  float4v acc[4][4];
  #pragma unroll
  for (int i = 0; i < 4; i++)
    #pragma unroll
    for (int j = 0; j < 4; j++) acc[i][j] = (float4v){0.f,0.f,0.f,0.f};

  // prefetch registers
  short8 pa0 = {0,0,0,0,0,0,0,0}, pa1 = {0,0,0,0,0,0,0,0};
  short4v praw[4];
  #pragma unroll
  for (int i = 0; i < 4; i++) praw[i] = (short4v){0,0,0,0};

  auto ldA = [&](int kb){
    if (aval){
      pa0 = *(const short8*)(Aptr + kb);
      pa1 = *(const short8*)(Aptr + kb + 8);
    }
  };
  auto ldB = [&](int kb){
    #pragma unroll
    for (int i = 0; i < 4; i++){
      const int k = kb + kg*4 + i;
      const unsigned short* bp = bbase + (long)k*kstep;
      if (vec4) praw[i] = *(const short4v*)bp;
      else {
        short4v u = {0,0,0,0};
        #pragma unroll
        for (int j = 0; j < 4; j++) if (lv[j]) u[j] = (short)bp[j];
        praw[i] = u;
      }
    }
  };

  ldA(0);
  if (BMODE == 0) ldB(0);

  for (int k0 = 0; k0 < g.K; k0 += 32){
    short8 sa0 = pa0, sa1 = pa1;
    short4v bpk[4];
    if (BMODE == 0){
      #pragma unroll
      for (int j = 0; j < 4; j++){
        short4v p;
        #pragma unroll
        for (int i = 0; i < 4; i++) p[i] = praw[i][j];
        bpk[j] = p;
      }
    } else { // BMODE == 2
      float tv[4][4];
      #pragma unroll
      for (int i = 0; i < 4; i++){
        const int k = k0 + kg*4 + i;
        const float pwk = g.pw[k], pbk = g.pb[k];
        #pragma unroll
        for (int j = 0; j < 4; j++) tv[i][j] = lv[j] ? silu_g((aud4[j]*pwk + pbk)*invn4[j]) : 0.f;
      }
      #pragma unroll
      for (int j = 0; j < 4; j++){
        short4v p;
        #pragma unroll
        for (int i = 0; i < 4; i++) p[i] = f2bf(tv[i][j]);
        bpk[j] = p;
      }
    }
    if (k0 + 32 < g.K){
      ldA(k0 + 32);
      if (BMODE == 0) ldB(k0 + 32);
    }

    __syncthreads();
    *(short8*)&Asm[ar*40 + ah*16]     = sa0;
    *(short8*)&Asm[ar*40 + ah*16 + 8] = sa1;
    #pragma unroll
    for (int j = 0; j < 4; j++)
      *(short4v*)&Bsm[(mg*4 + j)*40 + kg*4] = bpk[j];
    __syncthreads();

    short8 afr[4], bfr[4];
    #pragma unroll
    for (int i = 0; i < 4; i++) afr[i] = *(const short8*)&Asm[(wc*64 + i*16 + r16)*40 + q*8];
    #pragma unroll
    for (int j = 0; j < 4; j++) bfr[j] = *(const short8*)&Bsm[(wsd*64 + j*16 + r16)*40 + q*8];
    #pragma unroll
    for (int i = 0; i < 4; i++)
      #pragma unroll
      for (int j = 0; j < 4; j++)
        acc[i][j] = __builtin_amdgcn_mfma_f32_16x16x32_bf16(afr[i], bfr[j], acc[i][j], 0, 0, 0);
  }

  // ---- epilogue ----
  #pragma unroll
  for (int j = 0; j < 4; j++){
    int sg = s0 + wsd*64 + j*16 + r16;
    int b2 = sg / FL; int r2 = sg - b2*FL;
    int f2 = (g.Fdim > 1) ? (r2 / g.Lw) : 0;
    int l2 = g.lq0 + (r2 - f2*g.Lw);
    if (b2 >= 2 || l2 < 0 || l2 >= 2048) continue;
    float invn_p = 0.f, aud_p = 0.f;
    if (EMODE==2 || EMODE==3) invn_p = g.invn[(b2*g.Fdim + f2)*2048 + l2];
    if (EMODE==3) aud_p = g.audio[(b2*128 + f2)*2048 + l2];
    #pragma unroll
    for (int i = 0; i < 4; i++){
      #pragma unroll
      for (int rg = 0; rg < 4; rg++){
        int n = n0 + wc*64 + i*16 + q*4 + rg;
        if (n >= g.N) continue;
        float v = acc[i][j][rg];
        long oidx = ((long)(b2*g.Nsto + n)*g.Fdim + f2)*g.CLw + (l2 - g.Cl0);
        if (EMODE == 1){
          g.CoutH[oidx] = (unsigned short)f2bf(v);
        } else if (EMODE == 2){
          float xn = bf2f(g.auxXH[((long)(b2*g.N + n)*g.Fdim + f2)*2048 + l2]) * invn_p;
          g.CoutH[oidx] = (unsigned short)f2bf((xn*0.7f + v*0.3f)*MPS);
        } else if (EMODE == 3){
          float xn = (aud_p*g.pw[n] + g.pb[n])*invn_p;
          g.CoutH[oidx] = (unsigned short)f2bf((xn*0.7f + v*0.3f)*MPS);
        } else if (EMODE == 4){
          if (n < g.Nsto) g.CoutH[(long)(b2*g.Nsto + n)*g.CLw + l2] = (unsigned short)f2bf(silu_g(v));
          else            g.Cout2H[(long)(b2*g.Nsto + (n - g.Nsto))*g.CLw + l2] = (unsigned short)f2bf(v);
        }
      }
    }
  }
}

// ---------------- downsample conv GEMM: 64x64 tile on pooled P, prefetched ----------------
// EMODE 0: f32 store full-L ; EMODE 1: bf16 store full-L
struct DnArgs {
  const unsigned short* A; const unsigned short* P;
  float* Cout; unsigned short* CoutH;
  int N, K, F2, Lc, l0;
};

template<int EMODE>
__global__ __launch_bounds__(256,4) void mgemm64_kernel(DnArgs g){
  __shared__ __align__(16) unsigned short Asm[64*40];
  __shared__ __align__(16) unsigned short Bsm[64*40];
  const int t = threadIdx.x;
  const int lane = t & 63;
  const int wave = t >> 6;
  const int wc = wave >> 1, wsd = wave & 1;
  const int q = lane >> 4, r16 = lane & 15;
  const int s0 = blockIdx.x * 64;
  const int n0 = blockIdx.y * 64;
  const int FL = g.F2 * g.Lc;

  const int ar = t >> 2, ah = t & 3;
  const unsigned short* Aptr = g.A + (long)(n0 + ar)*g.K + ah*8;
  const int kg = t & 7, mg = t >> 3;
  const bool bstage = (mg < 16);
  const int mb = s0 + (mg & 15)*4;
  const int bcol = mb / FL; const int rr = mb - bcol*FL;
  const int fcol = rr / g.Lc; const int li = rr - fcol*g.Lc;
  const unsigned short* bbase = g.P + ((long)(bcol*g.K)*g.F2 + fcol)*g.Lc + li;
  const long kstep = (long)g.F2 * g.Lc;

  float4v acc[2][2];
  #pragma unroll
  for (int i = 0; i < 2; i++)
    #pragma unroll
    for (int j = 0; j < 2; j++) acc[i][j] = (float4v){0.f,0.f,0.f,0.f};

  short8 pa = {0,0,0,0,0,0,0,0};
  short4v praw[4];
  #pragma unroll
  for (int i = 0; i < 4; i++) praw[i] = (short4v){0,0,0,0};

  auto ldA = [&](int kb){ pa = *(const short8*)(Aptr + kb); };
  auto ldB = [&](int kb){
    if (bstage){
      #pragma unroll
      for (int i = 0; i < 4; i++)
        praw[i] = *(const short4v*)(bbase + (long)(kb + kg*4 + i)*kstep);
    }
  };
  ldA(0); ldB(0);

  for (int k0 = 0; k0 < g.K; k0 += 32){
    short8 sa = pa;
    short4v bpk[4];
    #pragma unroll
    for (int j = 0; j < 4; j++){
      short4v p;
      #pragma unroll
      for (int i = 0; i < 4; i++) p[i] = praw[i][j];
      bpk[j] = p;
    }
    if (k0 + 32 < g.K){ ldA(k0 + 32); ldB(k0 + 32); }

    __syncthreads();
    *(short8*)&Asm[ar*40 + ah*8] = sa;
    if (bstage){
      #pragma unroll
      for (int j = 0; j < 4; j++)
        *(short4v*)&Bsm[((mg & 15)*4 + j)*40 + kg*4] = bpk[j];
    }
    __syncthreads();

    short8 afr[2], bfr[2];
    #pragma unroll
    for (int i = 0; i < 2; i++) afr[i] = *(const short8*)&Asm[(wc*32 + i*16 + r16)*40 + q*8];
    #pragma unroll
    for (int j = 0; j < 2; j++) bfr[j] = *(const short8*)&Bsm[(wsd*32 + j*16 + r16)*40 + q*8];
    #pragma unroll
    for (int i = 0; i < 2; i++)
      #pragma unroll
      for (int j = 0; j < 2; j++)
        acc[i][j] = __builtin_amdgcn_mfma_f32_16x16x32_bf16(afr[i], bfr[j], acc[i][j], 0, 0, 0);
  }

  #pragma unroll
  for (int j = 0; j < 2; j++){
    int sg = s0 + wsd*32 + j*16 + r16;
    int b2 = sg / FL; int r2 = sg - b2*FL;
    int f2 = r2 / g.Lc; int l2 = g.l0 + (r2 - f2*g.Lc);
    #pragma unroll
    for (int i = 0; i < 2; i++){
      #pragma unroll
      for (int rg = 0; rg < 4; rg++){
        int n = n0 + wc*32 + i*16 + q*4 + rg;
        float v = acc[i][j][rg];
        long oidx = ((long)(b2*g.N + n)*g.F2 + f2)*2048 + l2;
        if (EMODE == 0) g.Cout[oidx] = v;
        else            g.CoutH[oidx] = (unsigned short)f2bf(v);
      }
    }
  }
}

// ---------------- seq out GEMM: 64x64 tile, Fdim=1, prefetched ----------------
// EMODE 5: mp_add -> f32 Cout ; EMODE 6: mp_add + silu -> f32 Cout
template<int EMODE>
__global__ __launch_bounds__(256,4) void seqout_kernel(const unsigned short* __restrict__ A,
                                                       const unsigned short* __restrict__ Bh,
                                                       const float* __restrict__ invn,
                                                       const float* __restrict__ auxX,
                                                       float* __restrict__ Cout, int K){
  __shared__ __align__(16) unsigned short Asm[64*40];
  __shared__ __align__(16) unsigned short Bsm[64*40];
  const int t = threadIdx.x;
  const int lane = t & 63;
  const int wave = t >> 6;
  const int wc = wave >> 1, wsd = wave & 1;
  const int q = lane >> 4, r16 = lane & 15;
  const int s0 = blockIdx.x * 64;
  const int n0 = blockIdx.y * 64;

  const int ar = t >> 2, ah = t & 3;
  const unsigned short* Aptr = A + (long)(n0 + ar)*K + ah*8;
  const int kg = t & 7, mg = t >> 3;
  const bool bstage = (mg < 16);
  const int mb = s0 + (mg & 15)*4;
  const int bcol = mb >> 11, lb = mb & 2047;
  const unsigned short* bbase = Bh + ((long)bcol*K)*2048 + lb;

  float4v acc[2][2];
  #pragma unroll
  for (int i = 0; i < 2; i++)
    #pragma unroll
    for (int j = 0; j < 2; j++) acc[i][j] = (float4v){0.f,0.f,0.f,0.f};

  short8 pa = {0,0,0,0,0,0,0,0};
  short4v praw[4];
  #pragma unroll
  for (int i = 0; i < 4; i++) praw[i] = (short4v){0,0,0,0};

  auto ldA = [&](int kb){ pa = *(const short8*)(Aptr + kb); };
  auto ldB = [&](int kb){
    if (bstage){
      #pragma unroll
      for (int i = 0; i < 4; i++)
        praw[i] = *(const short4v*)(bbase + (long)(kb + kg*4 + i)*2048);
    }
  };
  ldA(0); ldB(0);

  for (int k0 = 0; k0 < K; k0 += 32){
    short8 sa = pa;
    short4v bpk[4];
    #pragma unroll
    for (int j = 0; j < 4; j++){
      short4v p;
      #pragma unroll
      for (int i = 0; i < 4; i++) p[i] = praw[i][j];
      bpk[j] = p;
    }
    if (k0 + 32 < K){ ldA(k0 + 32); ldB(k0 + 32); }

    __syncthreads();
    *(short8*)&Asm[ar*40 + ah*8] = sa;
    if (bstage){
      #pragma unroll
      for (int j = 0; j < 4; j++)
        *(short4v*)&Bsm[((mg & 15)*4 + j)*40 + kg*4] = bpk[j];
    }
    __syncthreads();

    short8 afr[2], bfr[2];
    #pragma unroll
    for (int i = 0; i < 2; i++) afr[i] = *(const short8*)&Asm[(wc*32 + i*16 + r16)*40 + q*8];
    #pragma unroll
    for (int j = 0; j < 2; j++) bfr[j] = *(const short8*)&Bsm[(wsd*32 + j*16 + r16)*40 + q*8];
    #pragma unroll
    for (int i = 0; i < 2; i++)
      #pragma unroll
      for (int j = 0; j < 2; j++)
        acc[i][j] = __builtin_amdgcn_mfma_f32_16x16x32_bf16(afr[i], bfr[j], acc[i][j], 0, 0, 0);
  }

  #pragma unroll
  for (int j = 0; j < 2; j++){
    int sg = s0 + wsd*32 + j*16 + r16;
    int b2 = sg >> 11, l2 = sg & 2047;
    float invn_p = invn[b2*2048 + l2];
    #pragma unroll
    for (int i = 0; i < 2; i++){
      #pragma unroll
      for (int rg = 0; rg < 4; rg++){
        int n = n0 + wc*32 + i*16 + q*4 + rg;
        float v = acc[i][j][rg];
        float xn = auxX[((long)b2*512 + n)*2048 + l2] * invn_p;
        float r = (xn*0.7f + v*0.3f)*MPS;
        if (EMODE == 6) r = silu_g(r);
        Cout[((long)b2*512 + n)*2048 + l2] = r;
      }
    }
  }
}

// ---------------- depthwise 5x3 conv (+ silu), bf16 in/out ----------------
// 4 f-rows x 8 l per thread; each input row loaded once, feeds up to 3 f-accumulators
struct DwArgs { const unsigned short* R1; const unsigned short* wd; unsigned short* R2; int C, F, Lc, l0; };
__global__ __launch_bounds__(256) void dw2d_kernel(DwArgs a){
  int idx = blockIdx.x*256 + threadIdx.x;
  int Lq = a.Lc >> 3;
  int Fq = a.F >> 2;
  int total = 2*a.C*Fq*Lq;
  if (idx >= total) return;
  int lq = idx % Lq; int r = idx / Lq;
  int fq = r % Fq; r /= Fq;
  int c = r % a.C; int b = r / a.C;
  int f0 = fq*4;
  int labs = a.l0 + lq*8;
  int Lw = a.Lc + 8;
  // base points at l-position labs of row f=0 (R1 window starts at l0-4)
  const unsigned short* base = a.R1 + (long)((b*a.C + c)*a.F)*Lw + (labs - (a.l0 - 4));
  const unsigned short* w = a.wd + c*15;
  float W[5][3];
  #pragma unroll
  for (int tp = 0; tp < 5; tp++)
    #pragma unroll
    for (int j = 0; j < 3; j++) W[tp][j] = bf2f(w[tp*3 + j]);

  const bool llo = (labs > 0);
  const bool lhi = (labs + 8 < 2048);
  float acc[4][8];
  #pragma unroll
  for (int t = 0; t < 4; t++)
    #pragma unroll
    for (int j = 0; j < 8; j++) acc[t][j] = 0.f;

  #pragma unroll
  for (int r8 = 0; r8 < 8; r8++){
    int rrow = f0 - 2 + r8;
    if (rrow < 0 || rrow >= a.F) continue;
    const unsigned short* p = base + (long)rrow*Lw;
    short4v u0 = *(const short4v*)p;
    short4v u1 = *(const short4v*)(p + 4);
    float x[10];
    x[0] = llo ? bf2f(p[-1]) : 0.f;
    x[1] = bf2f((unsigned short)u0[0]); x[2] = bf2f((unsigned short)u0[1]);
    x[3] = bf2f((unsigned short)u0[2]); x[4] = bf2f((unsigned short)u0[3]);
    x[5] = bf2f((unsigned short)u1[0]); x[6] = bf2f((unsigned short)u1[1]);
    x[7] = bf2f((unsigned short)u1[2]); x[8] = bf2f((unsigned short)u1[3]);
    x[9] = lhi ? bf2f(p[8]) : 0.f;
    #pragma unroll
    for (int t = 0; t < 4; t++){
      const int df = r8 - 2 - t;          // compile-time per (r8,t)
      if (df < -2 || df > 2) continue;
      float w0 = W[df+2][0], w1 = W[df+2][1], w2 = W[df+2][2];
      #pragma unroll
      for (int j = 0; j < 8; j++)
        acc[t][j] += w0*x[j] + w1*x[j+1] + w2*x[j+2];
    }
  }

  unsigned short* ob = a.R2 + ((long)((b*a.C + c)*a.F + f0))*a.Lc + (labs - a.l0);
  #pragma unroll
  for (int t = 0; t < 4; t++){
    short8 o;
    #pragma unroll
    for (int j = 0; j < 8; j++) o[j] = f2bf(silu_g(acc[t][j]));
    *(short8*)(ob + (long)t*a.Lc) = o;
  }
}

// ---------------- seq depthwise 3-tap (+ silu), bf16 in/out ----------------
__global__ __launch_bounds__(256) void dwseq_kernel(const unsigned short* __restrict__ HS, const unsigned short* __restrict__ w,
                                                    unsigned short* __restrict__ H2){
  int idx = blockIdx.x*256 + threadIdx.x;
  if (idx >= 2*1024*512) return;
  int e = idx*4;
  int tt = e & 2047; int bc = e >> 11; int c = bc & 1023;
  const unsigned short* base = HS + (long)bc*2048 + tt;
  float w0 = bf2f(w[c*3+0]), w1 = bf2f(w[c*3+1]), w2 = bf2f(w[c*3+2]);
  short4v u = *(const short4v*)base;
  float xm = (tt > 0) ? bf2f(base[-1]) : 0.f;
  float x0 = bf2f((unsigned short)u[0]), x1 = bf2f((unsigned short)u[1]);
  float x2 = bf2f((unsigned short)u[2]), x3 = bf2f((unsigned short)u[3]);
  float x4 = (tt < 2044) ? bf2f(base[4]) : 0.f;
  short4v o = { f2bf(silu_g(w0*xm + w1*x0 + w2*x1)),
                f2bf(silu_g(w0*x0 + w1*x1 + w2*x2)),
                f2bf(silu_g(w0*x1 + w1*x2 + w2*x3)),
                f2bf(silu_g(w0*x2 + w1*x3 + w2*x4)) };
  *(short4v*)&H2[(long)bc*2048 + tt] = o;
}

// ---------------- minGRU scan + gate (bf16 z/c) ----------------
__global__ __launch_bounds__(256) void scan_kernel(const unsigned short* __restrict__ ZC, const unsigned short* __restrict__ G,
                                                   unsigned short* __restrict__ SC){
  int bc = blockIdx.x;            // 0..2047 = b*1024+c
  int b = bc >> 10, c = bc & 1023;
  const unsigned short* zrow = ZC + ((long)(b*2048 + c))*2048;
  const unsigned short* crow = ZC + ((long)(b*2048 + 1024 + c))*2048;
  const unsigned short* grow = G + (long)bc*2048;
  unsigned short* orow = SC + (long)bc*2048;
  int tid = threadIdx.x;
  int t0 = tid*8;
  short8 zv = *(const short8*)&zrow[t0];
  short8 cv = *(const short8*)&crow[t0];
  float av[8], bv[8];
  float A = 1.f, Bv = 0.f;
  #pragma unroll
  for (int j = 0; j < 8; j++){
    float z = bf2f((unsigned short)zv[j]); float cval = bf2f((unsigned short)cv[j]);
    float zs = 1.f/(1.f + __expf(-z));
    float a = 1.f - zs; float bb = zs*cval;
    av[j] = a; bv[j] = bb;
    Bv = a*Bv + bb;
    A = a*A;
  }
  __shared__ float sA[256], sB[256];
  sA[tid] = A; sB[tid] = Bv;
  __syncthreads();
  for (int off = 1; off < 256; off <<= 1){
    float pA = 1.f, pB = 0.f;
    if (tid >= off){ pA = sA[tid-off]; pB = sB[tid-off]; }
    __syncthreads();
    float nA = A*pA; float nB = A*pB + Bv;
    A = nA; Bv = nB;
    sA[tid] = A; sB[tid] = Bv;
    __syncthreads();
  }
  float h = (tid > 0) ? sB[tid-1] : 0.f;
  short8 gv = *(const short8*)&grow[t0];
  short8 ov;
  #pragma unroll
  for (int j = 0; j < 8; j++){
    h = av[j]*h + bv[j];
    ov[j] = f2bf(h * silu_g(bf2f((unsigned short)gv[j])));
  }
  *(short8*)&orow[t0] = ov;
}

extern "C" void kernel_launch(void* const* d_in, const int* in_sizes, int n_in,
                              void* d_out, int out_size, void* d_ws, size_t ws_size,
                              hipStream_t stream) {
  const float* audio = (const float*)d_in[0];
  const float* pw = (const float*)d_in[1];
  const float* pb = (const float*)d_in[2];
  const float* cw1[3] = {(const float*)d_in[3], (const float*)d_in[7], (const float*)d_in[11]};
  const float* cwd[3] = {(const float*)d_in[4], (const float*)d_in[8], (const float*)d_in[12]};
  const float* cw2[3] = {(const float*)d_in[5], (const float*)d_in[9], (const float*)d_in[13]};
  const float* cdn[3] = {(const float*)d_in[6], (const float*)d_in[10], (const float*)d_in[14]};
  const float* hgw  = (const float*)d_in[15];
  const float* dww  = (const float*)d_in[16];
  const float* gruw = (const float*)d_in[17];
  const float* outw = (const float*)d_in[18];
  float* out = (float*)d_out;

  // ---- workspace layout (bytes) ----
  char* P0 = (char*)d_ws;
  float*          INVW = (float*)P0;                    P0 += 131072;     // 25664 used + S at [32000]
  unsigned short* WBF  = (unsigned short*)P0;           P0 += 30443776;   // 15,221,888 bf16
  float*          INVN = (float*)P0;                    P0 += 2097152;
  char*           XBZC = P0;                            P0 += 33554432;   // XB (conv b1/b2) / ZC bf16 (seq)
  unsigned short* IN1h = (unsigned short*)P0;           P0 += 33554432;   // b0 out bf16; seq scratch later
  unsigned short* IN2h = (unsigned short*)P0;           P0 += 16777216;   // b1 out bf16
  float*          SEQ  = (float*)P0;                    P0 += 8388608;    // b2 out fp32
  char*           ARENA = P0;
  long arenaBytes = (long)ws_size - (long)(P0 - (char*)d_ws);
  float* S = INVW + 32000;

  // weight table (order: cw1/cwd/cw2/cdn x3, hg, dww, gru, out)
  const float* wsrc[16] = {cw1[0],cwd[0],cw2[0],cdn[0], cw1[1],cwd[1],cw2[1],cdn[1],
                           cw1[2],cwd[2],cw2[2],cdn[2], hgw, dww, gruw, outw};
  int Os[16] = {128,128,64,128, 256,256,128,256, 512,512,256,512, 8192,4096,8192,2048};
  int Ks[16] = {64,15,128,64, 128,15,256,128, 256,15,512,256, 512,3,1024,1024};
  int wbfOff[16], ivOff[16];
  {
    int wo = 0, io = 0;
    for (int i = 0; i < 16; i++){ wbfOff[i] = wo; ivOff[i] = io; wo += Os[i]*Ks[i]; io += Os[i]; }
  }
  {
    NormArgs na;
    int rows = 0;
    for (int i = 0; i < 16; i++){ na.e[i].w = wsrc[i]; na.e[i].O = Os[i]; na.e[i].K = Ks[i]; na.e[i].off = ivOff[i]; rows += Os[i]; }
    rownorm_kernel<<<rows, 64, 0, stream>>>(na, INVW);
  }
  {
    WcArgs wa; int base = 0;
    for (int i = 0; i < 16; i++){
      wa.e[i].src = wsrc[i]; wa.e[i].dstOff = wbfOff[i]; wa.e[i].K = Ks[i];
      wa.e[i].invwOff = ivOff[i]; wa.e[i].base = base; base += Os[i]*Ks[i];
    }
    wa.total = base;
    wcast_kernel<<<(base+255)/256, 256, 0, stream>>>(wa, INVW, WBF);
  }
  projstats_kernel<<<1, 64, 0, stream>>>(pw, pb, S);

  // ---- conv blocks ----
  int Cin_[3]  = {64,128,256};
  int Cmid_[3] = {128,256,512};
  int F_[3]    = {128,32,8};
  int s_[3]    = {4,4,8};
  const unsigned short* XinH[3] = {nullptr, IN1h, IN2h};
  unsigned short* XoutH[3] = {IN1h, IN2h, nullptr};
  int iW1[3]={0,4,8}, iWd[3]={1,5,9}, iW2[3]={2,6,10}, iDn[3]={3,7,11};

  for (int b = 0; b < 3; b++){
    int Cin = Cin_[b], Cmid = Cmid_[b], F = F_[b], s = s_[b];
    int F2 = F/s;
    int nc = 16;
    for (int c = 1; c <= 16; c <<= 1){
      long Lc = 2048/c;
      long bytes = 2L*(2L*Cmid*F*(Lc+8) + 2L*Cmid*F*Lc + 2L*Cin*F*Lc + 2L*Cin*F2*Lc);
      if (bytes <= arenaBytes){ nc = c; break; }
    }
    int Lc = 2048/nc;
    unsigned short* R1 = (unsigned short*)ARENA;
    unsigned short* R2 = R1 + 2L*Cmid*F*(Lc+8);
    unsigned short* Hb = R2 + 2L*Cmid*F*Lc;
    unsigned short* Pb = Hb + 2L*Cin*F*Lc;
    unsigned short* XB = (unsigned short*)XBZC;

    if (b == 0){
      invn_audio_kernel<<<(2*128*2048/4+255)/256, 256, 0, stream>>>(audio, S, INVN);
    } else {
      int positions = 2*F*2048;
      invn_reduce_kernel<8,true><<<positions/32, 256, 0, stream>>>(XinH[b], INVN, Cin, F);
      long total4 = (long)2*Cin*F*2048/4;
      applynorm_kernel<true,true><<<(int)((total4+255)/256), 256, 0, stream>>>(XinH[b], INVN, XB, Cin, F, total4);
    }

    for (int ci = 0; ci < nc; ci++){
      int l0 = ci*Lc;
      // conv1: Cin -> Cmid on window [l0-4, l0+Lc+4) -> R1 bf16
      GemmArgs ga{};
      ga.A = WBF + wbfOff[iW1[b]];
      ga.Bh = XB; ga.invn = INVN; ga.audio = audio; ga.pw = pw; ga.pb = pb;
      ga.CoutH = R1; ga.N = Cmid; ga.K = Cin; ga.Fdim = F; ga.Lw = Lc+8; ga.lq0 = l0-4;
      ga.BLw = 2048; ga.Bl0 = 0; ga.CLw = Lc+8; ga.Cl0 = l0-4; ga.Nsto = Cmid; ga.Fsrc = F;
      int M1 = 2*F*(Lc+8);
      dim3 g1((M1+127)/128, (Cmid+127)/128);
      if (b == 0) mgemm_kernel<2,1><<<g1,256,0,stream>>>(ga);
      else        mgemm_kernel<0,1><<<g1,256,0,stream>>>(ga);
      // depthwise 5x3 + silu -> R2 bf16 (4f x 8l per thread)
      DwArgs da{R1, WBF + wbfOff[iWd[b]], R2, Cmid, F, Lc, l0};
      int tdw = 2*Cmid*(F/4)*(Lc/8);
      dw2d_kernel<<<(tdw+255)/256, 256, 0, stream>>>(da);
      // conv2 + mp_add -> Hb bf16
      GemmArgs gb{};
      gb.A = WBF + wbfOff[iW2[b]];
      gb.Bh = R2; gb.invn = INVN; gb.audio = audio; gb.pw = pw; gb.pb = pb; gb.auxXH = XinH[b];
      gb.CoutH = Hb; gb.N = Cin; gb.K = Cmid; gb.Fdim = F; gb.Lw = Lc; gb.lq0 = l0;
      gb.BLw = Lc; gb.Bl0 = l0; gb.CLw = Lc; gb.Cl0 = l0; gb.Nsto = Cin; gb.Fsrc = F;
      int M2 = 2*F*Lc;
      dim3 g2((M2+127)/128, (Cin+127)/128);
      if (b == 0) mgemm_kernel<0,3><<<g2,256,0,stream>>>(gb);
      else        mgemm_kernel<0,2><<<g2,256,0,stream>>>(gb);
      // freq-pool Hb -> Pb (bf16)
      long tp4 = (2L*Cin*F2*Lc)/4;
      poolf_kernel<<<(int)((tp4+255)/256), 256, 0, stream>>>(Hb, Pb, F2, s, Lc, tp4);
      // dn conv on pooled P -> Xout (bf16 full-L for b0/b1; fp32 SEQ for b2)
      DnArgs dn{};
      dn.A = WBF + wbfOff[iDn[b]]; dn.P = Pb;
      dn.Cout = SEQ; dn.CoutH = XoutH[b];
      dn.N = Cmid; dn.K = Cin; dn.F2 = F2; dn.Lc = Lc; dn.l0 = l0;
      dim3 gdn((2*F2*Lc)/64, Cmid/64);
      if (b == 2) mgemm64_kernel<0><<<gdn,256,0,stream>>>(dn);
      else        mgemm64_kernel<1><<<gdn,256,0,stream>>>(dn);
    }
  }

  // ---- seq blocks (bf16 scratch spans IN1h+IN2h; ZC bf16 in XBZC) ----
  unsigned short* XS = IN1h;
  unsigned short* HS = XS + 2097152;
  unsigned short* G  = HS + 4194304;
  unsigned short* H2 = G  + 4194304;
  unsigned short* SC = H2 + 4194304;
  unsigned short* ZCh = (unsigned short*)XBZC;

  for (int i = 0; i < 4; i++){
    invn_reduce_kernel<16,false><<<4096/16, 256, 0, stream>>>(SEQ, INVN, 512, 1);
    applynorm_kernel<false,false><<<(2*512*2048/4)/256, 256, 0, stream>>>(SEQ, INVN, XS, 512, 1, (long)2*512*2048/4);
    // hg conv (both halves): n<1024 -> silu -> HS, else raw -> G
    GemmArgs gh{};
    gh.A = WBF + wbfOff[12] + (long)i*2048*512;
    gh.Bh = XS;
    gh.CoutH = HS; gh.Cout2H = G;
    gh.N = 2048; gh.K = 512; gh.Fdim = 1; gh.Lw = 2048; gh.lq0 = 0;
    gh.BLw = 2048; gh.Bl0 = 0; gh.CLw = 2048; gh.Cl0 = 0; gh.Nsto = 1024; gh.Fsrc = 1;
    mgemm_kernel<0,4><<<dim3(32,16),256,0,stream>>>(gh);
    // depthwise 3-tap + silu
    dwseq_kernel<<<(2*1024*512)/256, 256, 0, stream>>>(HS, WBF + wbfOff[13] + i*1024*3, H2);
    // gru conv 1024 -> 2048 (z|c) -> ZCh bf16
    GemmArgs gz{};
    gz.A = WBF + wbfOff[14] + (long)i*2048*1024;
    gz.Bh = H2; gz.CoutH = ZCh; gz.N = 2048; gz.K = 1024; gz.Fdim = 1; gz.Lw = 2048; gz.lq0 = 0;
    gz.BLw = 2048; gz.Bl0 = 0; gz.CLw = 2048; gz.Cl0 = 0; gz.Nsto = 2048; gz.Fsrc = 1;
    mgemm_kernel<0,1><<<dim3(32,16),256,0,stream>>>(gz);
    // scan + gate -> SC bf16
    scan_kernel<<<2048,256,0,stream>>>(ZCh, G, SC);
    // out conv + mp_add -> SEQ (i<3) or mp_add+silu -> d_out (i==3)
    const unsigned short* oA = WBF + wbfOff[15] + (long)i*512*1024;
    if (i < 3) seqout_kernel<5><<<dim3(64,8),256,0,stream>>>(oA, SC, INVN, SEQ, SEQ, 1024);
    else       seqout_kernel<6><<<dim3(64,8),256,0,stream>>>(oA, SC, INVN, SEQ, out, 1024);
  }

  (void)in_sizes; (void)n_in; (void)out_size;
}